// Round 1
// baseline (1656.075 us; speedup 1.0000x reference)
//
#include <hip/hip_runtime.h>
#include <math.h>

#define S 128
#define R 256
#define DMODEL 256
#define DP 128
#define H 8
#define CDIM 32
#define HC 256
#define DFF 1024
#define NROWS (S*R)     // 32768
#define NPAIR (R*R)     // 65536
#define LN_EPS 1e-5f

// ---------------- LayerNorm over 256 elems, one row per wave ----------------
// tmode==0: row m reads in[m], writes out[m]
// tmode==1: m enumerates (r,s); reads in[s*R + r] (node1 [s,r,d]), writes out[m] ([r,s,d])
__global__ __launch_bounds__(256) void ln256_kernel(
    const float* __restrict__ in, float* __restrict__ out,
    const float* __restrict__ gamma, const float* __restrict__ beta,
    int tmode)
{
  int wid = threadIdx.x >> 6, lane = threadIdx.x & 63;
  int m = blockIdx.x * 4 + wid;
  int inrow = m;
  if (tmode) { int r = m >> 7, s = m & 127; inrow = s * R + r; }
  float4 x = *(const float4*)(in + (size_t)inrow * DMODEL + lane * 4);
  float sum = x.x + x.y + x.z + x.w;
  float sq  = x.x*x.x + x.y*x.y + x.z*x.z + x.w*x.w;
  #pragma unroll
  for (int off = 32; off; off >>= 1) {
    sum += __shfl_xor(sum, off);
    sq  += __shfl_xor(sq, off);
  }
  float mean = sum * (1.0f/256.0f);
  float var  = sq  * (1.0f/256.0f) - mean*mean;
  float rstd = rsqrtf(var + LN_EPS);
  float4 g = *(const float4*)(gamma + lane*4);
  float4 b = *(const float4*)(beta  + lane*4);
  float4 o;
  o.x = (x.x-mean)*rstd*g.x + b.x;
  o.y = (x.y-mean)*rstd*g.y + b.y;
  o.z = (x.z-mean)*rstd*g.z + b.z;
  o.w = (x.w-mean)*rstd*g.w + b.w;
  *(float4*)(out + (size_t)m * DMODEL + lane*4) = o;
}

// ------------- pair LN (over 128) + bias projection: b[h,q,k] -------------
// one (q,k) pair per wave; bias layout [H][R*R]
__global__ __launch_bounds__(256) void pair_bias_kernel(
    const float* __restrict__ pair, const float* __restrict__ gamma,
    const float* __restrict__ beta, const float* __restrict__ bw,
    float* __restrict__ bias)
{
  int wid = threadIdx.x >> 6, lane = threadIdx.x & 63;
  int p = blockIdx.x * 4 + wid;        // 0..65535
  float2 x = *(const float2*)(pair + (size_t)p * DP + lane*2);
  float sum = x.x + x.y, sq = x.x*x.x + x.y*x.y;
  #pragma unroll
  for (int off = 32; off; off >>= 1) {
    sum += __shfl_xor(sum, off);
    sq  += __shfl_xor(sq, off);
  }
  float mean = sum * (1.0f/128.0f);
  float rstd = rsqrtf(sq*(1.0f/128.0f) - mean*mean + LN_EPS);
  float z0 = (x.x-mean)*rstd*gamma[lane*2]   + beta[lane*2];
  float z1 = (x.y-mean)*rstd*gamma[lane*2+1] + beta[lane*2+1];
  float a0 = z0*bw[0*DP+lane*2] + z1*bw[0*DP+lane*2+1];
  float a1 = z0*bw[1*DP+lane*2] + z1*bw[1*DP+lane*2+1];
  float a2 = z0*bw[2*DP+lane*2] + z1*bw[2*DP+lane*2+1];
  float a3 = z0*bw[3*DP+lane*2] + z1*bw[3*DP+lane*2+1];
  float a4 = z0*bw[4*DP+lane*2] + z1*bw[4*DP+lane*2+1];
  float a5 = z0*bw[5*DP+lane*2] + z1*bw[5*DP+lane*2+1];
  float a6 = z0*bw[6*DP+lane*2] + z1*bw[6*DP+lane*2+1];
  float a7 = z0*bw[7*DP+lane*2] + z1*bw[7*DP+lane*2+1];
  #pragma unroll
  for (int off = 32; off; off >>= 1) {
    a0 += __shfl_xor(a0, off); a1 += __shfl_xor(a1, off);
    a2 += __shfl_xor(a2, off); a3 += __shfl_xor(a3, off);
    a4 += __shfl_xor(a4, off); a5 += __shfl_xor(a5, off);
    a6 += __shfl_xor(a6, off); a7 += __shfl_xor(a7, off);
  }
  float v = a0;
  v = (lane==1)?a1:v; v = (lane==2)?a2:v; v = (lane==3)?a3:v;
  v = (lane==4)?a4:v; v = (lane==5)?a5:v; v = (lane==6)?a6:v; v = (lane==7)?a7:v;
  if (lane < 8) bias[(size_t)lane*NPAIR + p] = v;
}

// ---------------- generic f32 NT GEMM: C[M,N] = A[M,K] * W[N,K]^T ----------------
// mode 0: none    1: *scale    2: sigmoid(x+bias[n])    3: relu(x+bias[n])
// mode 4: x + res[m,n] + bias[n]
// mode 5: transposed residual+write: m=(r,s); idx=(s*R+r)*N+n; out=x+res[idx]+bias[n]
__global__ __launch_bounds__(256) void gemm_nt_kernel(
    const float* __restrict__ A, const float* __restrict__ W,
    float* __restrict__ Cout, int M, int N, int K,
    int mode, const float* __restrict__ bias, const float* __restrict__ res,
    float scale)
{
  __shared__ float As[16][64];
  __shared__ float Bs[16][64];
  int t = threadIdx.x;
  int bn = blockIdx.x * 64, bm = blockIdx.y * 64;
  int tx = t & 15, ty = t >> 4;
  int lm = t >> 2, lk = (t & 3) << 2;
  const float* Ap = A + (size_t)(bm + lm) * K + lk;
  const float* Wp = W + (size_t)(bn + lm) * K + lk;
  float acc[4][4] = {};
  for (int k0 = 0; k0 < K; k0 += 16) {
    float4 av = *(const float4*)(Ap + k0);
    float4 wv = *(const float4*)(Wp + k0);
    __syncthreads();
    As[lk+0][lm]=av.x; As[lk+1][lm]=av.y; As[lk+2][lm]=av.z; As[lk+3][lm]=av.w;
    Bs[lk+0][lm]=wv.x; Bs[lk+1][lm]=wv.y; Bs[lk+2][lm]=wv.z; Bs[lk+3][lm]=wv.w;
    __syncthreads();
    #pragma unroll
    for (int k = 0; k < 16; ++k) {
      float4 a = *(const float4*)&As[k][ty<<2];
      float4 b = *(const float4*)&Bs[k][tx<<2];
      acc[0][0] = fmaf(a.x,b.x,acc[0][0]); acc[0][1] = fmaf(a.x,b.y,acc[0][1]);
      acc[0][2] = fmaf(a.x,b.z,acc[0][2]); acc[0][3] = fmaf(a.x,b.w,acc[0][3]);
      acc[1][0] = fmaf(a.y,b.x,acc[1][0]); acc[1][1] = fmaf(a.y,b.y,acc[1][1]);
      acc[1][2] = fmaf(a.y,b.z,acc[1][2]); acc[1][3] = fmaf(a.y,b.w,acc[1][3]);
      acc[2][0] = fmaf(a.z,b.x,acc[2][0]); acc[2][1] = fmaf(a.z,b.y,acc[2][1]);
      acc[2][2] = fmaf(a.z,b.z,acc[2][2]); acc[2][3] = fmaf(a.z,b.w,acc[2][3]);
      acc[3][0] = fmaf(a.w,b.x,acc[3][0]); acc[3][1] = fmaf(a.w,b.y,acc[3][1]);
      acc[3][2] = fmaf(a.w,b.z,acc[3][2]); acc[3][3] = fmaf(a.w,b.w,acc[3][3]);
    }
  }
  int n0 = bn + (tx<<2);
  #pragma unroll
  for (int i = 0; i < 4; ++i) {
    int m = bm + (ty<<2) + i;
    float4 c = make_float4(acc[i][0],acc[i][1],acc[i][2],acc[i][3]);
    if (mode == 1) {
      c.x*=scale; c.y*=scale; c.z*=scale; c.w*=scale;
    } else if (mode == 2) {
      c.x = 1.0f/(1.0f+__expf(-(c.x+bias[n0+0])));
      c.y = 1.0f/(1.0f+__expf(-(c.y+bias[n0+1])));
      c.z = 1.0f/(1.0f+__expf(-(c.z+bias[n0+2])));
      c.w = 1.0f/(1.0f+__expf(-(c.w+bias[n0+3])));
    } else if (mode == 3) {
      c.x = fmaxf(c.x+bias[n0+0],0.0f); c.y = fmaxf(c.y+bias[n0+1],0.0f);
      c.z = fmaxf(c.z+bias[n0+2],0.0f); c.w = fmaxf(c.w+bias[n0+3],0.0f);
    } else if (mode == 4) {
      float4 rv = *(const float4*)(res + (size_t)m*N + n0);
      float4 bv = *(const float4*)(bias + n0);
      c.x += rv.x + bv.x; c.y += rv.y + bv.y;
      c.z += rv.z + bv.z; c.w += rv.w + bv.w;
    } else if (mode == 5) {
      int rr = m >> 7, ss = m & 127;
      size_t idx = ((size_t)ss * R + rr) * N + n0;
      float4 rv = *(const float4*)(res + idx);
      float4 bv = *(const float4*)(bias + n0);
      c.x += rv.x + bv.x; c.y += rv.y + bv.y;
      c.z += rv.z + bv.z; c.w += rv.w + bv.w;
      *(float4*)(Cout + idx) = c;
      continue;
    }
    *(float4*)(Cout + (size_t)m*N + n0) = c;
  }
}

// ---------------- row attention: one block per (h, s), thread = query r ----------------
__global__ __launch_bounds__(256) void row_attn_kernel(
    const float* __restrict__ q, const float* __restrict__ k,
    const float* __restrict__ v, const float* __restrict__ gate,
    const float* __restrict__ bias, const float* __restrict__ mask,
    float* __restrict__ og)
{
  int h = blockIdx.x;   // 0..7
  int s = blockIdx.y;   // 0..127
  __shared__ float ks[R][CDIM];
  __shared__ float vs[R][CDIM];
  __shared__ float lmadd[R];
  int t = threadIdx.x;
  size_t baseK = (size_t)s * (R*HC) + h * CDIM;   // + kr*HC + c
  for (int i = t; i < R*CDIM; i += 256) {
    int kr = i >> 5, c = i & 31;
    ks[kr][c] = k[baseK + (size_t)kr*HC + c];
    vs[kr][c] = v[baseK + (size_t)kr*HC + c];
  }
  lmadd[t] = 1e9f * (mask[s*R + t] - 1.0f);
  __syncthreads();

  float qv[CDIM];
  const float* qp = q + baseK + (size_t)t*HC;
  #pragma unroll
  for (int c0 = 0; c0 < CDIM; c0 += 4) {
    float4 tmp = *(const float4*)(qp + c0);
    qv[c0]=tmp.x; qv[c0+1]=tmp.y; qv[c0+2]=tmp.z; qv[c0+3]=tmp.w;
  }
  const float* bp = bias + (size_t)h*NPAIR + (size_t)t*R;
  float mmax = -INFINITY, l = 0.0f;
  float o[CDIM] = {};
  for (int kr = 0; kr < R; ++kr) {
    float logit = lmadd[kr] + bp[kr];
    #pragma unroll
    for (int c = 0; c < CDIM; ++c) logit = fmaf(qv[c], ks[kr][c], logit);
    if (logit <= mmax) {
      float p = __expf(logit - mmax);
      l += p;
      #pragma unroll
      for (int c = 0; c < CDIM; ++c) o[c] = fmaf(p, vs[kr][c], o[c]);
    } else {
      float sc = __expf(mmax - logit);
      mmax = logit;
      l = l*sc + 1.0f;
      #pragma unroll
      for (int c = 0; c < CDIM; ++c) o[c] = fmaf(o[c], sc, vs[kr][c]);
    }
  }
  float inv = 1.0f / l;
  const float* gp = gate + baseK + (size_t)t*HC;
  float* op = og + baseK + (size_t)t*HC;
  #pragma unroll
  for (int c0 = 0; c0 < CDIM; c0 += 4) {
    float4 g4 = *(const float4*)(gp + c0);
    float4 ov;
    ov.x = o[c0+0]*inv*g4.x; ov.y = o[c0+1]*inv*g4.y;
    ov.z = o[c0+2]*inv*g4.z; ov.w = o[c0+3]*inv*g4.w;
    *(float4*)(op + c0) = ov;
  }
}

// ---------------- column attention: one block per (h, r), thread = query s ----------------
// q/k/v/gate and og in [r, s, e] layout; mask_t[r,s] = node_mask[s*R + r]
__global__ __launch_bounds__(128) void col_attn_kernel(
    const float* __restrict__ q, const float* __restrict__ k,
    const float* __restrict__ v, const float* __restrict__ gate,
    const float* __restrict__ mask, float* __restrict__ og)
{
  int h = blockIdx.x;   // 0..7
  int r = blockIdx.y;   // 0..255
  __shared__ float ks[S][CDIM];
  __shared__ float vs[S][CDIM];
  __shared__ float lmadd[S];
  int t = threadIdx.x;  // query s
  size_t baseK = (size_t)r * (S*HC) + h * CDIM;   // + skey*HC + c
  for (int i = t; i < S*CDIM; i += 128) {
    int kr = i >> 5, c = i & 31;
    ks[kr][c] = k[baseK + (size_t)kr*HC + c];
    vs[kr][c] = v[baseK + (size_t)kr*HC + c];
  }
  lmadd[t] = 1e9f * (mask[t*R + r] - 1.0f);
  __syncthreads();

  float qv[CDIM];
  const float* qp = q + baseK + (size_t)t*HC;
  #pragma unroll
  for (int c0 = 0; c0 < CDIM; c0 += 4) {
    float4 tmp = *(const float4*)(qp + c0);
    qv[c0]=tmp.x; qv[c0+1]=tmp.y; qv[c0+2]=tmp.z; qv[c0+3]=tmp.w;
  }
  float mmax = -INFINITY, l = 0.0f;
  float o[CDIM] = {};
  for (int kr = 0; kr < S; ++kr) {
    float logit = lmadd[kr];
    #pragma unroll
    for (int c = 0; c < CDIM; ++c) logit = fmaf(qv[c], ks[kr][c], logit);
    if (logit <= mmax) {
      float p = __expf(logit - mmax);
      l += p;
      #pragma unroll
      for (int c = 0; c < CDIM; ++c) o[c] = fmaf(p, vs[kr][c], o[c]);
    } else {
      float sc = __expf(mmax - logit);
      mmax = logit;
      l = l*sc + 1.0f;
      #pragma unroll
      for (int c = 0; c < CDIM; ++c) o[c] = fmaf(o[c], sc, vs[kr][c]);
    }
  }
  float inv = 1.0f / l;
  const float* gp = gate + baseK + (size_t)t*HC;
  float* op = og + baseK + (size_t)t*HC;
  #pragma unroll
  for (int c0 = 0; c0 < CDIM; c0 += 4) {
    float4 g4 = *(const float4*)(gp + c0);
    float4 ov;
    ov.x = o[c0+0]*inv*g4.x; ov.y = o[c0+1]*inv*g4.y;
    ov.z = o[c0+2]*inv*g4.z; ov.w = o[c0+3]*inv*g4.w;
    *(float4*)(op + c0) = ov;
  }
}

extern "C" void kernel_launch(void* const* d_in, const int* in_sizes, int n_in,
                              void* d_out, int out_size, void* d_ws, size_t ws_size,
                              hipStream_t stream)
{
  const float* node         = (const float*)d_in[0];
  const float* pair         = (const float*)d_in[1];
  const float* node_mask    = (const float*)d_in[2];
  const float* row_ln_m_g   = (const float*)d_in[3];
  const float* row_ln_m_b   = (const float*)d_in[4];
  const float* row_ln_z_g   = (const float*)d_in[5];
  const float* row_ln_z_b   = (const float*)d_in[6];
  const float* row_b_w      = (const float*)d_in[7];
  const float* row_wq       = (const float*)d_in[8];
  const float* row_wk       = (const float*)d_in[9];
  const float* row_wv       = (const float*)d_in[10];
  const float* row_wg       = (const float*)d_in[11];
  const float* row_bg       = (const float*)d_in[12];
  const float* row_wo       = (const float*)d_in[13];
  const float* row_out_bias = (const float*)d_in[14];
  const float* col_ln_g     = (const float*)d_in[15];
  const float* col_ln_b     = (const float*)d_in[16];
  const float* col_wq       = (const float*)d_in[17];
  const float* col_wk       = (const float*)d_in[18];
  const float* col_wv       = (const float*)d_in[19];
  const float* col_wg       = (const float*)d_in[20];
  const float* col_bg       = (const float*)d_in[21];
  const float* col_wo       = (const float*)d_in[22];
  const float* col_bo       = (const float*)d_in[23];
  const float* tr_ln_g      = (const float*)d_in[24];
  const float* tr_ln_b      = (const float*)d_in[25];
  const float* tr_w1        = (const float*)d_in[26];
  const float* tr_b1        = (const float*)d_in[27];
  const float* tr_w2        = (const float*)d_in[28];
  const float* tr_b2        = (const float*)d_in[29];

  float* out = (float*)d_out;
  char*  ws  = (char*)d_ws;
  // Workspace layout: A (32 MiB) | B0..B3 (4x32 MiB = t1 128 MiB) | Dbias (2 MiB)
  float* A     = (float*)(ws);
  float* B0    = (float*)(ws + (1ull<<25));
  float* B1    = B0 + (1ull<<23);
  float* B2    = B1 + (1ull<<23);
  float* B3    = B2 + (1ull<<23);
  float* Dbias = (float*)(ws + 5ull*(1ull<<25));

  const float qscale = 0.17677669529663687f;   // 1/sqrt(32)
  dim3 gproj(4, 512);     // N=256 tiles x M=32768 tiles

  // --- row attention ---
  ln256_kernel<<<8192, 256, 0, stream>>>(node, A, row_ln_m_g, row_ln_m_b, 0);
  pair_bias_kernel<<<16384, 256, 0, stream>>>(pair, row_ln_z_g, row_ln_z_b, row_b_w, Dbias);
  gemm_nt_kernel<<<gproj, 256, 0, stream>>>(A, row_wq, B0, NROWS, 256, 256, 1, nullptr, nullptr, qscale);
  gemm_nt_kernel<<<gproj, 256, 0, stream>>>(A, row_wk, B1, NROWS, 256, 256, 0, nullptr, nullptr, 0.f);
  gemm_nt_kernel<<<gproj, 256, 0, stream>>>(A, row_wv, B2, NROWS, 256, 256, 0, nullptr, nullptr, 0.f);
  gemm_nt_kernel<<<gproj, 256, 0, stream>>>(A, row_wg, B3, NROWS, 256, 256, 2, row_bg, nullptr, 0.f);
  row_attn_kernel<<<dim3(8,128), 256, 0, stream>>>(B0, B1, B2, B3, Dbias, node_mask, A);
  // node1 = node + attn + row_out_bias  -> d_out
  gemm_nt_kernel<<<gproj, 256, 0, stream>>>(A, row_wo, out, NROWS, 256, 256, 4, row_out_bias, node, 0.f);

  // --- column attention (work in [r,s,d] layout) ---
  ln256_kernel<<<8192, 256, 0, stream>>>(out, A, col_ln_g, col_ln_b, 1);
  gemm_nt_kernel<<<gproj, 256, 0, stream>>>(A, col_wq, B0, NROWS, 256, 256, 1, nullptr, nullptr, qscale);
  gemm_nt_kernel<<<gproj, 256, 0, stream>>>(A, col_wk, B1, NROWS, 256, 256, 0, nullptr, nullptr, 0.f);
  gemm_nt_kernel<<<gproj, 256, 0, stream>>>(A, col_wv, B2, NROWS, 256, 256, 0, nullptr, nullptr, 0.f);
  gemm_nt_kernel<<<gproj, 256, 0, stream>>>(A, col_wg, B3, NROWS, 256, 256, 2, col_bg, nullptr, 0.f);
  col_attn_kernel<<<dim3(8,256), 128, 0, stream>>>(B0, B1, B2, B3, node_mask, A);
  // node2 = node1 + attn_c^T + col_bo  -> d_out (in place, transposed epilogue)
  gemm_nt_kernel<<<gproj, 256, 0, stream>>>(A, col_wo, out, NROWS, 256, 256, 5, col_bo, out, 0.f);

  // --- transition ---
  ln256_kernel<<<8192, 256, 0, stream>>>(out, A, tr_ln_g, tr_ln_b, 0);
  gemm_nt_kernel<<<dim3(16,512), 256, 0, stream>>>(A, tr_w1, B0, NROWS, DFF, 256, 3, tr_b1, nullptr, 0.f);
  gemm_nt_kernel<<<gproj, 256, 0, stream>>>(B0, tr_w2, out, NROWS, 256, DFF, 4, tr_b2, out, 0.f);
}

// Round 2
// 805.841 us; speedup vs baseline: 2.0551x; 2.0551x over previous
//
#include <hip/hip_runtime.h>
#include <math.h>

#define S 128
#define R 256
#define DMODEL 256
#define H 8
#define CDIM 32
#define HC 256
#define DFF 1024
#define NROWS (S*R)     // 32768
#define NPAIR (R*R)     // 65536
#define LN_EPS 1e-5f

typedef unsigned short u16;
typedef __attribute__((ext_vector_type(8))) short bf16x8;
typedef __attribute__((ext_vector_type(4))) float f32x4;

__device__ __forceinline__ u16 f2bf(float x) {
  unsigned u = __float_as_uint(x);
  u = (u + 0x7fffu + ((u >> 16) & 1u)) >> 16;
  return (u16)u;
}

__device__ __forceinline__ void gload_lds16(const u16* g, u16* l) {
  __builtin_amdgcn_global_load_lds(
      (const __attribute__((address_space(1))) unsigned int*)g,
      (__attribute__((address_space(3))) unsigned int*)l, 16, 0, 0);
}

// dot of 8 bf16 (packed in uint4) with q8[0..7], accumulated
__device__ __forceinline__ float dot8(uint4 u, const float* q8, float acc) {
  acc = fmaf(__uint_as_float(u.x << 16),        q8[0], acc);
  acc = fmaf(__uint_as_float(u.x & 0xffff0000u), q8[1], acc);
  acc = fmaf(__uint_as_float(u.y << 16),        q8[2], acc);
  acc = fmaf(__uint_as_float(u.y & 0xffff0000u), q8[3], acc);
  acc = fmaf(__uint_as_float(u.z << 16),        q8[4], acc);
  acc = fmaf(__uint_as_float(u.z & 0xffff0000u), q8[5], acc);
  acc = fmaf(__uint_as_float(u.w << 16),        q8[6], acc);
  acc = fmaf(__uint_as_float(u.w & 0xffff0000u), q8[7], acc);
  return acc;
}

__device__ __forceinline__ void axpy8(uint4 u, float p, float* o8) {
  o8[0] = fmaf(__uint_as_float(u.x << 16),        p, o8[0]);
  o8[1] = fmaf(__uint_as_float(u.x & 0xffff0000u), p, o8[1]);
  o8[2] = fmaf(__uint_as_float(u.y << 16),        p, o8[2]);
  o8[3] = fmaf(__uint_as_float(u.y & 0xffff0000u), p, o8[3]);
  o8[4] = fmaf(__uint_as_float(u.z << 16),        p, o8[4]);
  o8[5] = fmaf(__uint_as_float(u.z & 0xffff0000u), p, o8[5]);
  o8[6] = fmaf(__uint_as_float(u.w << 16),        p, o8[6]);
  o8[7] = fmaf(__uint_as_float(u.w & 0xffff0000u), p, o8[7]);
}

__device__ __forceinline__ void unpack8(uint4 u, float* f) {
  f[0] = __uint_as_float(u.x << 16); f[1] = __uint_as_float(u.x & 0xffff0000u);
  f[2] = __uint_as_float(u.y << 16); f[3] = __uint_as_float(u.y & 0xffff0000u);
  f[4] = __uint_as_float(u.z << 16); f[5] = __uint_as_float(u.z & 0xffff0000u);
  f[6] = __uint_as_float(u.w << 16); f[7] = __uint_as_float(u.w & 0xffff0000u);
}

// ---------------- weight f32 -> bf16 conversion (12 segments, one launch) ----------------
struct CvtArgs {
  const float* src[12];
  int off[12];
  int n[12];
  float scale[12];
};

__global__ __launch_bounds__(256) void cvt_w_kernel(CvtArgs a, u16* __restrict__ dst) {
  int sg = blockIdx.y;
  int i = (blockIdx.x * 256 + threadIdx.x) * 4;
  if (i >= a.n[sg]) return;
  float4 v = *(const float4*)(a.src[sg] + i);
  float sc = a.scale[sg];
  ushort4 o;
  o.x = f2bf(v.x * sc); o.y = f2bf(v.y * sc);
  o.z = f2bf(v.z * sc); o.w = f2bf(v.w * sc);
  *(ushort4*)(dst + a.off[sg] + i) = o;
}

// ---------------- LayerNorm over 256, one row per wave, bf16 out ----------------
__global__ __launch_bounds__(256) void ln256_kernel(
    const float* __restrict__ in, u16* __restrict__ out,
    const float* __restrict__ gamma, const float* __restrict__ beta,
    int tmode)
{
  int wid = threadIdx.x >> 6, lane = threadIdx.x & 63;
  int m = blockIdx.x * 4 + wid;
  int inrow = m;
  if (tmode) { int r = m >> 7, s = m & 127; inrow = s * R + r; }
  float4 x = *(const float4*)(in + (size_t)inrow * DMODEL + lane * 4);
  float sum = x.x + x.y + x.z + x.w;
  float sq  = x.x*x.x + x.y*x.y + x.z*x.z + x.w*x.w;
  #pragma unroll
  for (int off = 32; off; off >>= 1) {
    sum += __shfl_xor(sum, off);
    sq  += __shfl_xor(sq, off);
  }
  float mean = sum * (1.0f/256.0f);
  float var  = sq  * (1.0f/256.0f) - mean*mean;
  float rstd = rsqrtf(var + LN_EPS);
  float4 g = *(const float4*)(gamma + lane*4);
  float4 b = *(const float4*)(beta  + lane*4);
  ushort4 o;
  o.x = f2bf((x.x-mean)*rstd*g.x + b.x);
  o.y = f2bf((x.y-mean)*rstd*g.y + b.y);
  o.z = f2bf((x.z-mean)*rstd*g.z + b.z);
  o.w = f2bf((x.w-mean)*rstd*g.w + b.w);
  *(ushort4*)(out + (size_t)m * DMODEL + lane*4) = o;
}

// ------------- pair LN (over 128) + bias projection -> bias[h][q][k] (f32) -------------
__global__ __launch_bounds__(256) void pair_bias_kernel(
    const float* __restrict__ pair, const float* __restrict__ gamma,
    const float* __restrict__ beta, const float* __restrict__ bw,
    float* __restrict__ bias)
{
  int wid = threadIdx.x >> 6, lane = threadIdx.x & 63;
  int p = blockIdx.x * 4 + wid;
  float2 x = *(const float2*)(pair + (size_t)p * 128 + lane*2);
  float sum = x.x + x.y, sq = x.x*x.x + x.y*x.y;
  #pragma unroll
  for (int off = 32; off; off >>= 1) {
    sum += __shfl_xor(sum, off);
    sq  += __shfl_xor(sq, off);
  }
  float mean = sum * (1.0f/128.0f);
  float rstd = rsqrtf(sq*(1.0f/128.0f) - mean*mean + LN_EPS);
  float z0 = (x.x-mean)*rstd*gamma[lane*2]   + beta[lane*2];
  float z1 = (x.y-mean)*rstd*gamma[lane*2+1] + beta[lane*2+1];
  float a0 = z0*bw[0*128+lane*2] + z1*bw[0*128+lane*2+1];
  float a1 = z0*bw[1*128+lane*2] + z1*bw[1*128+lane*2+1];
  float a2 = z0*bw[2*128+lane*2] + z1*bw[2*128+lane*2+1];
  float a3 = z0*bw[3*128+lane*2] + z1*bw[3*128+lane*2+1];
  float a4 = z0*bw[4*128+lane*2] + z1*bw[4*128+lane*2+1];
  float a5 = z0*bw[5*128+lane*2] + z1*bw[5*128+lane*2+1];
  float a6 = z0*bw[6*128+lane*2] + z1*bw[6*128+lane*2+1];
  float a7 = z0*bw[7*128+lane*2] + z1*bw[7*128+lane*2+1];
  #pragma unroll
  for (int off = 32; off; off >>= 1) {
    a0 += __shfl_xor(a0, off); a1 += __shfl_xor(a1, off);
    a2 += __shfl_xor(a2, off); a3 += __shfl_xor(a3, off);
    a4 += __shfl_xor(a4, off); a5 += __shfl_xor(a5, off);
    a6 += __shfl_xor(a6, off); a7 += __shfl_xor(a7, off);
  }
  float v = a0;
  v = (lane==1)?a1:v; v = (lane==2)?a2:v; v = (lane==3)?a3:v;
  v = (lane==4)?a4:v; v = (lane==5)?a5:v; v = (lane==6)?a6:v; v = (lane==7)?a7:v;
  if (lane < 8) bias[(size_t)lane*NPAIR + p] = v;
}

// ---------------- bf16 MFMA NT GEMM: C[M,N] = A[M,K] * W[N,K]^T ----------------
// modes: 1: bf16 out  2: bf16 sigmoid(x+bias[n])  3: bf16 relu(x+bias[n])
//        4: f32 out = x + res[m,n] + bias[n]
//        5: f32 transposed: idx=((m&127)*R + (m>>7))*N + n; out[idx]=x+res[idx]+bias[n]
__global__ __launch_bounds__(256) void gemm_mfma(
    const u16* __restrict__ A, const u16* __restrict__ W,
    void* __restrict__ Cout, int M, int N, int K,
    int mode, const float* __restrict__ bias, const float* __restrict__ res)
{
  __shared__ u16 As[128*32];
  __shared__ u16 Bs[128*32];
  int t = threadIdx.x;
  int lane = t & 63;
  int w = t >> 6;
  int wm = w >> 1, wn = w & 1;
  int bn = blockIdx.x * 128, bm = blockIdx.y * 128;

  int sr = t >> 2;            // 0..63 staging row
  int sc = (t & 3) * 8;       // staging col (elements)
  const u16* Ag = A + (size_t)(bm + sr) * K + sc;
  const u16* Wg = W + (size_t)(bn + sr) * K + sc;
  u16* Al = As + sr*32 + sc;
  u16* Bl = Bs + sr*32 + sc;

  f32x4 acc[4][4];
  #pragma unroll
  for (int m=0;m<4;++m)
    #pragma unroll
    for (int n=0;n<4;++n) acc[m][n] = (f32x4){0.f,0.f,0.f,0.f};

  const u16* ap = As + ((size_t)(wm*64 + (lane&15)))*32 + (lane>>4)*8;
  const u16* bp = Bs + ((size_t)(wn*64 + (lane&15)))*32 + (lane>>4)*8;

  for (int k0 = 0; k0 < K; k0 += 32) {
    gload_lds16(Ag + k0, Al);
    gload_lds16(Ag + (size_t)64*K + k0, Al + 64*32);
    gload_lds16(Wg + k0, Bl);
    gload_lds16(Wg + (size_t)64*K + k0, Bl + 64*32);
    __syncthreads();
    bf16x8 a[4], b[4];
    #pragma unroll
    for (int m=0;m<4;++m) a[m] = *(const bf16x8*)(ap + m*16*32);
    #pragma unroll
    for (int n=0;n<4;++n) b[n] = *(const bf16x8*)(bp + n*16*32);
    #pragma unroll
    for (int m=0;m<4;++m)
      #pragma unroll
      for (int n=0;n<4;++n)
        acc[m][n] = __builtin_amdgcn_mfma_f32_16x16x32_bf16(a[m], b[n], acc[m][n], 0, 0, 0);
    __syncthreads();
  }

  int lm = lane & 15;
  int row0 = bm + wm*64 + ((lane>>4)<<2);
  #pragma unroll
  for (int m=0;m<4;++m) {
    #pragma unroll
    for (int n=0;n<4;++n) {
      int col = bn + wn*64 + n*16 + lm;
      float bb = 0.f;
      if (mode >= 2) bb = bias[col];
      #pragma unroll
      for (int r=0;r<4;++r) {
        int row = row0 + m*16 + r;
        float val = acc[m][n][r];
        if (mode == 1) {
          ((u16*)Cout)[(size_t)row*N + col] = f2bf(val);
        } else if (mode == 2) {
          ((u16*)Cout)[(size_t)row*N + col] = f2bf(1.0f/(1.0f+__expf(-(val+bb))));
        } else if (mode == 3) {
          ((u16*)Cout)[(size_t)row*N + col] = f2bf(fmaxf(val+bb, 0.0f));
        } else if (mode == 4) {
          size_t i2 = (size_t)row*N + col;
          ((float*)Cout)[i2] = val + res[i2] + bb;
        } else {
          int rr = row >> 7, ss = row & 127;
          size_t i2 = ((size_t)ss*R + rr)*N + col;
          ((float*)Cout)[i2] = val + res[i2] + bb;
        }
      }
    }
  }
}

// ---------------- row attention: block=(h,s), thread = query r, bf16 in/out ----------------
__global__ __launch_bounds__(256) void row_attn_kernel(
    const u16* __restrict__ q, const u16* __restrict__ k,
    const u16* __restrict__ v, const u16* __restrict__ g,
    const float* __restrict__ bias, const float* __restrict__ mask,
    u16* __restrict__ og)
{
  int h = blockIdx.x, s = blockIdx.y;
  __shared__ u16 ks[R*CDIM];
  __shared__ u16 vs[R*CDIM];
  __shared__ float lmadd[R];
  int t = threadIdx.x;
  size_t base = (size_t)s*(R*HC) + (size_t)h*CDIM;
  for (int i = t; i < R*CDIM/8; i += 256) {
    int kr = i >> 2, c = (i & 3)*8;
    *(bf16x8*)(ks + kr*CDIM + c) = *(const bf16x8*)(k + base + (size_t)kr*HC + c);
    *(bf16x8*)(vs + kr*CDIM + c) = *(const bf16x8*)(v + base + (size_t)kr*HC + c);
  }
  lmadd[t] = 1e9f * (mask[s*R + t] - 1.0f);
  __syncthreads();

  float qf[CDIM];
  { const u16* qp = q + base + (size_t)t*HC;
    #pragma unroll
    for (int c0 = 0; c0 < CDIM; c0 += 8) unpack8(*(const uint4*)(qp + c0), qf + c0); }
  const float* bp = bias + (size_t)h*NPAIR + (size_t)t*R;

  float l = 0.0f;
  float o[CDIM] = {};
  for (int kr = 0; kr < R; ++kr) {
    const u16* kp = ks + kr*CDIM;
    float d0 = dot8(*(const uint4*)(kp +  0), qf +  0, 0.0f);
    float d1 = dot8(*(const uint4*)(kp +  8), qf +  8, 0.0f);
    float d2 = dot8(*(const uint4*)(kp + 16), qf + 16, 0.0f);
    float d3 = dot8(*(const uint4*)(kp + 24), qf + 24, 0.0f);
    float logit = lmadd[kr] + bp[kr] + ((d0 + d1) + (d2 + d3));
    float p = __expf(logit);
    l += p;
    const u16* vp = vs + kr*CDIM;
    axpy8(*(const uint4*)(vp +  0), p, o +  0);
    axpy8(*(const uint4*)(vp +  8), p, o +  8);
    axpy8(*(const uint4*)(vp + 16), p, o + 16);
    axpy8(*(const uint4*)(vp + 24), p, o + 24);
  }
  float inv = 1.0f / l;
  float gf[CDIM];
  { const u16* gp = g + base + (size_t)t*HC;
    #pragma unroll
    for (int c0 = 0; c0 < CDIM; c0 += 8) unpack8(*(const uint4*)(gp + c0), gf + c0); }
  u16* op = og + base + (size_t)t*HC;
  #pragma unroll
  for (int c0 = 0; c0 < CDIM; c0 += 4) {
    ushort4 w4;
    w4.x = f2bf(o[c0+0]*inv*gf[c0+0]);
    w4.y = f2bf(o[c0+1]*inv*gf[c0+1]);
    w4.z = f2bf(o[c0+2]*inv*gf[c0+2]);
    w4.w = f2bf(o[c0+3]*inv*gf[c0+3]);
    *(ushort4*)(op + c0) = w4;
  }
}

// ---------------- column attention: block=(h,r), thread = query s ----------------
__global__ __launch_bounds__(128) void col_attn_kernel(
    const u16* __restrict__ q, const u16* __restrict__ k,
    const u16* __restrict__ v, const u16* __restrict__ g,
    const float* __restrict__ mask, u16* __restrict__ og)
{
  int h = blockIdx.x, r = blockIdx.y;
  __shared__ u16 ks[S*CDIM];
  __shared__ u16 vs[S*CDIM];
  __shared__ float lmadd[S];
  int t = threadIdx.x;
  size_t base = (size_t)r*(S*HC) + (size_t)h*CDIM;
  for (int i = t; i < S*CDIM/8; i += 128) {
    int kr = i >> 2, c = (i & 3)*8;
    *(bf16x8*)(ks + kr*CDIM + c) = *(const bf16x8*)(k + base + (size_t)kr*HC + c);
    *(bf16x8*)(vs + kr*CDIM + c) = *(const bf16x8*)(v + base + (size_t)kr*HC + c);
  }
  lmadd[t] = 1e9f * (mask[t*R + r] - 1.0f);
  __syncthreads();

  float qf[CDIM];
  { const u16* qp = q + base + (size_t)t*HC;
    #pragma unroll
    for (int c0 = 0; c0 < CDIM; c0 += 8) unpack8(*(const uint4*)(qp + c0), qf + c0); }

  float l = 0.0f;
  float o[CDIM] = {};
  for (int kr = 0; kr < S; ++kr) {
    const u16* kp = ks + kr*CDIM;
    float d0 = dot8(*(const uint4*)(kp +  0), qf +  0, 0.0f);
    float d1 = dot8(*(const uint4*)(kp +  8), qf +  8, 0.0f);
    float d2 = dot8(*(const uint4*)(kp + 16), qf + 16, 0.0f);
    float d3 = dot8(*(const uint4*)(kp + 24), qf + 24, 0.0f);
    float logit = lmadd[kr] + ((d0 + d1) + (d2 + d3));
    float p = __expf(logit);
    l += p;
    const u16* vp = vs + kr*CDIM;
    axpy8(*(const uint4*)(vp +  0), p, o +  0);
    axpy8(*(const uint4*)(vp +  8), p, o +  8);
    axpy8(*(const uint4*)(vp + 16), p, o + 16);
    axpy8(*(const uint4*)(vp + 24), p, o + 24);
  }
  float inv = 1.0f / l;
  float gf[CDIM];
  { const u16* gp = g + base + (size_t)t*HC;
    #pragma unroll
    for (int c0 = 0; c0 < CDIM; c0 += 8) unpack8(*(const uint4*)(gp + c0), gf + c0); }
  u16* op = og + base + (size_t)t*HC;
  #pragma unroll
  for (int c0 = 0; c0 < CDIM; c0 += 4) {
    ushort4 w4;
    w4.x = f2bf(o[c0+0]*inv*gf[c0+0]);
    w4.y = f2bf(o[c0+1]*inv*gf[c0+1]);
    w4.z = f2bf(o[c0+2]*inv*gf[c0+2]);
    w4.w = f2bf(o[c0+3]*inv*gf[c0+3]);
    *(ushort4*)(op + c0) = w4;
  }
}

extern "C" void kernel_launch(void* const* d_in, const int* in_sizes, int n_in,
                              void* d_out, int out_size, void* d_ws, size_t ws_size,
                              hipStream_t stream)
{
  const float* node         = (const float*)d_in[0];
  const float* pair         = (const float*)d_in[1];
  const float* node_mask    = (const float*)d_in[2];
  const float* row_ln_m_g   = (const float*)d_in[3];
  const float* row_ln_m_b   = (const float*)d_in[4];
  const float* row_ln_z_g   = (const float*)d_in[5];
  const float* row_ln_z_b   = (const float*)d_in[6];
  const float* row_b_w      = (const float*)d_in[7];
  const float* row_wq       = (const float*)d_in[8];
  const float* row_wk       = (const float*)d_in[9];
  const float* row_wv       = (const float*)d_in[10];
  const float* row_wg       = (const float*)d_in[11];
  const float* row_bg       = (const float*)d_in[12];
  const float* row_wo       = (const float*)d_in[13];
  const float* row_out_bias = (const float*)d_in[14];
  const float* col_ln_g     = (const float*)d_in[15];
  const float* col_ln_b     = (const float*)d_in[16];
  const float* col_wq       = (const float*)d_in[17];
  const float* col_wk       = (const float*)d_in[18];
  const float* col_wv       = (const float*)d_in[19];
  const float* col_wg       = (const float*)d_in[20];
  const float* col_bg       = (const float*)d_in[21];
  const float* col_wo       = (const float*)d_in[22];
  const float* col_bo       = (const float*)d_in[23];
  const float* tr_ln_g      = (const float*)d_in[24];
  const float* tr_ln_b      = (const float*)d_in[25];
  const float* tr_w1        = (const float*)d_in[26];
  const float* tr_b1        = (const float*)d_in[27];
  const float* tr_w2        = (const float*)d_in[28];
  const float* tr_b2        = (const float*)d_in[29];

  float* out = (float*)d_out;
  char* ws8 = (char*)d_ws;
  const size_t MB = 1ull << 20;
  u16*   A     = (u16*)(ws8);               // 16 MB  [32768][256] bf16
  u16*   Qb    = (u16*)(ws8 + 16*MB);       // 16 MB
  u16*   Kb    = (u16*)(ws8 + 32*MB);
  u16*   Vb    = (u16*)(ws8 + 48*MB);
  u16*   Gb    = (u16*)(ws8 + 64*MB);
  u16*   Ob    = (u16*)(ws8 + 80*MB);       // attn out (gated), bf16
  float* Dbias = (float*)(ws8 + 96*MB);     // 2 MB  [H][R][R]
  u16*   Wb    = (u16*)(ws8 + 100*MB);      // bf16 weights arena (~2.3 MB)
  u16*   T1    = Qb;                        // 64 MB [32768][1024] bf16 (reuses Q..G)

  const float qs = 0.17677669529663687f;    // 1/sqrt(32)

  // bf16 weight arena offsets
  u16* Wrq = Wb + 0;       u16* Wrk = Wb + 65536;  u16* Wrv = Wb + 131072;
  u16* Wrg = Wb + 196608;  u16* Wro = Wb + 262144;
  u16* Wcq = Wb + 327680;  u16* Wck = Wb + 393216; u16* Wcv = Wb + 458752;
  u16* Wcg = Wb + 524288;  u16* Wco = Wb + 589824;
  u16* W1  = Wb + 655360;  u16* W2  = Wb + 917504;

  CvtArgs ca;
  const float* srcs[12] = {row_wq,row_wk,row_wv,row_wg,row_wo,
                           col_wq,col_wk,col_wv,col_wg,col_wo,tr_w1,tr_w2};
  int offs[12] = {0,65536,131072,196608,262144,327680,393216,458752,524288,589824,655360,917504};
  int ns[12]   = {65536,65536,65536,65536,65536,65536,65536,65536,65536,65536,262144,262144};
  for (int i = 0; i < 12; ++i) {
    ca.src[i] = srcs[i]; ca.off[i] = offs[i]; ca.n[i] = ns[i];
    ca.scale[i] = (i == 0 || i == 5) ? qs : 1.0f;
  }
  cvt_w_kernel<<<dim3(256,12), 256, 0, stream>>>(ca, Wb);

  dim3 g256(2, 256), gdff(8, 256);

  // --- row attention ---
  ln256_kernel<<<8192, 256, 0, stream>>>(node, A, row_ln_m_g, row_ln_m_b, 0);
  pair_bias_kernel<<<16384, 256, 0, stream>>>(pair, row_ln_z_g, row_ln_z_b, row_b_w, Dbias);
  gemm_mfma<<<g256, 256, 0, stream>>>(A, Wrq, Qb, NROWS, 256, 256, 1, nullptr, nullptr);
  gemm_mfma<<<g256, 256, 0, stream>>>(A, Wrk, Kb, NROWS, 256, 256, 1, nullptr, nullptr);
  gemm_mfma<<<g256, 256, 0, stream>>>(A, Wrv, Vb, NROWS, 256, 256, 1, nullptr, nullptr);
  gemm_mfma<<<g256, 256, 0, stream>>>(A, Wrg, Gb, NROWS, 256, 256, 2, row_bg, nullptr);
  row_attn_kernel<<<dim3(8,128), 256, 0, stream>>>(Qb, Kb, Vb, Gb, Dbias, node_mask, Ob);
  gemm_mfma<<<g256, 256, 0, stream>>>(Ob, Wro, out, NROWS, 256, 256, 4, row_out_bias, node);

  // --- column attention (in [r,s,d] layout) ---
  ln256_kernel<<<8192, 256, 0, stream>>>(out, A, col_ln_g, col_ln_b, 1);
  gemm_mfma<<<g256, 256, 0, stream>>>(A, Wcq, Qb, NROWS, 256, 256, 1, nullptr, nullptr);
  gemm_mfma<<<g256, 256, 0, stream>>>(A, Wck, Kb, NROWS, 256, 256, 1, nullptr, nullptr);
  gemm_mfma<<<g256, 256, 0, stream>>>(A, Wcv, Vb, NROWS, 256, 256, 1, nullptr, nullptr);
  gemm_mfma<<<g256, 256, 0, stream>>>(A, Wcg, Gb, NROWS, 256, 256, 2, col_bg, nullptr);
  col_attn_kernel<<<dim3(8,256), 128, 0, stream>>>(Qb, Kb, Vb, Gb, node_mask, Ob);
  gemm_mfma<<<g256, 256, 0, stream>>>(Ob, Wco, out, NROWS, 256, 256, 5, col_bo, out);

  // --- transition ---
  ln256_kernel<<<8192, 256, 0, stream>>>(out, A, tr_ln_g, tr_ln_b, 0);
  gemm_mfma<<<gdff, 256, 0, stream>>>(A, W1, T1, NROWS, DFF, 256, 3, tr_b1, nullptr);
  gemm_mfma<<<g256, 256, 0, stream>>>(T1, W2, out, NROWS, 256, DFF, 4, tr_b2, out);
}

// Round 3
// 568.451 us; speedup vs baseline: 2.9133x; 1.4176x over previous
//
#include <hip/hip_runtime.h>
#include <math.h>

#define S 128
#define R 256
#define DMODEL 256
#define H 8
#define CDIM 32
#define HC 256
#define DFF 1024
#define NROWS (S*R)     // 32768
#define NPAIR (R*R)     // 65536
#define LN_EPS 1e-5f

typedef unsigned short u16;
typedef __attribute__((ext_vector_type(8))) short bf16x8;
typedef __attribute__((ext_vector_type(4))) float f32x4;

__device__ __forceinline__ u16 f2bf(float x) {
  unsigned u = __float_as_uint(x);
  u = (u + 0x7fffu + ((u >> 16) & 1u)) >> 16;
  return (u16)u;
}
__device__ __forceinline__ float bf2f(u16 x) {
  return __uint_as_float(((unsigned)x) << 16);
}

__device__ __forceinline__ void gload_lds16(const u16* g, u16* l) {
  __builtin_amdgcn_global_load_lds(
      (const __attribute__((address_space(1))) unsigned int*)g,
      (__attribute__((address_space(3))) unsigned int*)l, 16, 0, 0);
}

// ---------------- weight f32 -> bf16 conversion (12 segments) ----------------
struct CvtArgs {
  const float* src[12];
  int off[12];
  int n[12];
  float scale[12];
};

__global__ __launch_bounds__(256) void cvt_w_kernel(CvtArgs a, u16* __restrict__ dst) {
  int sg = blockIdx.y;
  int i = (blockIdx.x * 256 + threadIdx.x) * 4;
  if (i >= a.n[sg]) return;
  float4 v = *(const float4*)(a.src[sg] + i);
  float sc = a.scale[sg];
  ushort4 o;
  o.x = f2bf(v.x * sc); o.y = f2bf(v.y * sc);
  o.z = f2bf(v.z * sc); o.w = f2bf(v.w * sc);
  *(ushort4*)(dst + a.off[sg] + i) = o;
}

// ---------------- LayerNorm over 256, one row per wave, bf16 out ----------------
__global__ __launch_bounds__(256) void ln256_kernel(
    const float* __restrict__ in, u16* __restrict__ out,
    const float* __restrict__ gamma, const float* __restrict__ beta,
    int tmode)
{
  int wid = threadIdx.x >> 6, lane = threadIdx.x & 63;
  int m = blockIdx.x * 4 + wid;
  int inrow = m;
  if (tmode) { int r = m >> 7, s = m & 127; inrow = s * R + r; }
  float4 x = *(const float4*)(in + (size_t)inrow * DMODEL + lane * 4);
  float sum = x.x + x.y + x.z + x.w;
  float sq  = x.x*x.x + x.y*x.y + x.z*x.z + x.w*x.w;
  #pragma unroll
  for (int off = 32; off; off >>= 1) {
    sum += __shfl_xor(sum, off);
    sq  += __shfl_xor(sq, off);
  }
  float mean = sum * (1.0f/256.0f);
  float var  = sq  * (1.0f/256.0f) - mean*mean;
  float rstd = rsqrtf(var + LN_EPS);
  float4 g = *(const float4*)(gamma + lane*4);
  float4 b = *(const float4*)(beta  + lane*4);
  ushort4 o;
  o.x = f2bf((x.x-mean)*rstd*g.x + b.x);
  o.y = f2bf((x.y-mean)*rstd*g.y + b.y);
  o.z = f2bf((x.z-mean)*rstd*g.z + b.z);
  o.w = f2bf((x.w-mean)*rstd*g.w + b.w);
  *(ushort4*)(out + (size_t)m * DMODEL + lane*4) = o;
}

// ------------- pair LN (over 128) + bias projection -> bias[h][q][k] (f32) -------------
__global__ __launch_bounds__(256) void pair_bias_kernel(
    const float* __restrict__ pair, const float* __restrict__ gamma,
    const float* __restrict__ beta, const float* __restrict__ bw,
    float* __restrict__ bias)
{
  int wid = threadIdx.x >> 6, lane = threadIdx.x & 63;
  int p = blockIdx.x * 4 + wid;
  float2 x = *(const float2*)(pair + (size_t)p * 128 + lane*2);
  float sum = x.x + x.y, sq = x.x*x.x + x.y*x.y;
  #pragma unroll
  for (int off = 32; off; off >>= 1) {
    sum += __shfl_xor(sum, off);
    sq  += __shfl_xor(sq, off);
  }
  float mean = sum * (1.0f/128.0f);
  float rstd = rsqrtf(sq*(1.0f/128.0f) - mean*mean + LN_EPS);
  float z0 = (x.x-mean)*rstd*gamma[lane*2]   + beta[lane*2];
  float z1 = (x.y-mean)*rstd*gamma[lane*2+1] + beta[lane*2+1];
  float a0 = z0*bw[0*128+lane*2] + z1*bw[0*128+lane*2+1];
  float a1 = z0*bw[1*128+lane*2] + z1*bw[1*128+lane*2+1];
  float a2 = z0*bw[2*128+lane*2] + z1*bw[2*128+lane*2+1];
  float a3 = z0*bw[3*128+lane*2] + z1*bw[3*128+lane*2+1];
  float a4 = z0*bw[4*128+lane*2] + z1*bw[4*128+lane*2+1];
  float a5 = z0*bw[5*128+lane*2] + z1*bw[5*128+lane*2+1];
  float a6 = z0*bw[6*128+lane*2] + z1*bw[6*128+lane*2+1];
  float a7 = z0*bw[7*128+lane*2] + z1*bw[7*128+lane*2+1];
  #pragma unroll
  for (int off = 32; off; off >>= 1) {
    a0 += __shfl_xor(a0, off); a1 += __shfl_xor(a1, off);
    a2 += __shfl_xor(a2, off); a3 += __shfl_xor(a3, off);
    a4 += __shfl_xor(a4, off); a5 += __shfl_xor(a5, off);
    a6 += __shfl_xor(a6, off); a7 += __shfl_xor(a7, off);
  }
  float v = a0;
  v = (lane==1)?a1:v; v = (lane==2)?a2:v; v = (lane==3)?a3:v;
  v = (lane==4)?a4:v; v = (lane==5)?a5:v; v = (lane==6)?a6:v; v = (lane==7)?a7:v;
  if (lane < 8) bias[(size_t)lane*NPAIR + p] = v;
}

// ---------------- bf16 MFMA NT GEMM: C[M,N] = A[M,K] * W[N,K]^T ----------------
// modes: 1: bf16 out  2: bf16 sigmoid(x+bias[n])  3: bf16 relu(x+bias[n])
//        4: f32 out = x + res[m,n] + bias[n]
//        5: f32 transposed: idx=((m&127)*R + (m>>7))*N + n
//        6: bf16 out; cols >= 768 get sigmoid(x + bias[col-768])   (fused QKVG)
__global__ __launch_bounds__(256) void gemm_mfma(
    const u16* __restrict__ A, const u16* __restrict__ W,
    void* __restrict__ Cout, int M, int N, int K,
    int mode, const float* __restrict__ bias, const float* __restrict__ res)
{
  __shared__ u16 As[128*32];
  __shared__ u16 Bs[128*32];
  int t = threadIdx.x;
  int lane = t & 63;
  int w = t >> 6;
  int wm = w >> 1, wn = w & 1;
  int bn = blockIdx.x * 128, bm = blockIdx.y * 128;

  int sr = t >> 2;
  int sc = (t & 3) * 8;
  const u16* Ag = A + (size_t)(bm + sr) * K + sc;
  const u16* Wg = W + (size_t)(bn + sr) * K + sc;
  u16* Al = As + sr*32 + sc;
  u16* Bl = Bs + sr*32 + sc;

  f32x4 acc[4][4];
  #pragma unroll
  for (int m=0;m<4;++m)
    #pragma unroll
    for (int n=0;n<4;++n) acc[m][n] = (f32x4){0.f,0.f,0.f,0.f};

  const u16* ap = As + ((size_t)(wm*64 + (lane&15)))*32 + (lane>>4)*8;
  const u16* bp = Bs + ((size_t)(wn*64 + (lane&15)))*32 + (lane>>4)*8;

  for (int k0 = 0; k0 < K; k0 += 32) {
    gload_lds16(Ag + k0, Al);
    gload_lds16(Ag + (size_t)64*K + k0, Al + 64*32);
    gload_lds16(Wg + k0, Bl);
    gload_lds16(Wg + (size_t)64*K + k0, Bl + 64*32);
    __syncthreads();
    bf16x8 a[4], b[4];
    #pragma unroll
    for (int m=0;m<4;++m) a[m] = *(const bf16x8*)(ap + m*16*32);
    #pragma unroll
    for (int n=0;n<4;++n) b[n] = *(const bf16x8*)(bp + n*16*32);
    #pragma unroll
    for (int m=0;m<4;++m)
      #pragma unroll
      for (int n=0;n<4;++n)
        acc[m][n] = __builtin_amdgcn_mfma_f32_16x16x32_bf16(a[m], b[n], acc[m][n], 0, 0, 0);
    __syncthreads();
  }

  int lm = lane & 15;
  int row0 = bm + wm*64 + ((lane>>4)<<2);
  #pragma unroll
  for (int m=0;m<4;++m) {
    #pragma unroll
    for (int n=0;n<4;++n) {
      int col = bn + wn*64 + n*16 + lm;
      float bb = 0.f;
      if (mode == 2 || mode == 3 || mode == 4) bb = bias[col];
      #pragma unroll
      for (int r=0;r<4;++r) {
        int row = row0 + m*16 + r;
        float val = acc[m][n][r];
        if (mode == 1) {
          ((u16*)Cout)[(size_t)row*N + col] = f2bf(val);
        } else if (mode == 2) {
          ((u16*)Cout)[(size_t)row*N + col] = f2bf(1.0f/(1.0f+__expf(-(val+bb))));
        } else if (mode == 3) {
          ((u16*)Cout)[(size_t)row*N + col] = f2bf(fmaxf(val+bb, 0.0f));
        } else if (mode == 4) {
          size_t i2 = (size_t)row*N + col;
          ((float*)Cout)[i2] = val + res[i2] + bb;
        } else if (mode == 5) {
          int rr = row >> 7, ss = row & 127;
          size_t i2 = ((size_t)ss*R + rr)*N + col;
          ((float*)Cout)[i2] = val + res[i2] + bias[col];
        } else { // 6
          float v2 = val;
          if (col >= 768) v2 = 1.0f/(1.0f+__expf(-(val + bias[col-768])));
          ((u16*)Cout)[(size_t)row*N + col] = f2bf(v2);
        }
      }
    }
  }
}

// ---------------- MFMA attention ----------------
// QKVG: [b-panel rows][1024] bf16, Q at +0, K at +256, V at +512, G at +768.
// One block per (h, b);  b = s (row attn, NKEY=256) or r (col attn, NKEY=128).
// 4 waves; wave w owns q-rows [w*MT*16, (w+1)*MT*16).
// ROWMODE: bias[h][q][k] added, mask indexed mask[b*R + key]; else mask[key*R + b].
template<int NKEY, int MT, bool ROWMODE>
__global__ __launch_bounds__(256) void attn_mfma(
    const u16* __restrict__ QKVG, const float* __restrict__ bias,
    const float* __restrict__ mask, u16* __restrict__ og)
{
  __shared__ u16 Vt[32][NKEY+8];
  __shared__ u16 Ps[4][MT*16][72];
  __shared__ float lmb[NKEY];
  constexpr int KVI = NKEY/64;
  int h = blockIdx.x, b = blockIdx.y;
  int t = threadIdx.x, lane = t & 63, w = t >> 6;
  int g16 = lane >> 4, l16 = lane & 15;

  size_t base1 = (size_t)b * NKEY * 1024 + h * 32;
  const u16* Qp = QKVG + base1;
  const u16* Kp = QKVG + base1 + 256;
  const u16* Vp = QKVG + base1 + 512;
  const u16* Gp = QKVG + base1 + 768;

  // stage V transposed
  if (NKEY == 256) {
    int key = t;
    #pragma unroll
    for (int c0 = 0; c0 < 32; c0 += 8) {
      bf16x8 v8 = *(const bf16x8*)(Vp + (size_t)key*1024 + c0);
      #pragma unroll
      for (int j = 0; j < 8; ++j) Vt[c0+j][key] = (u16)v8[j];
    }
  } else {
    int key = t & 127, ch = (t >> 7) * 16;
    #pragma unroll
    for (int c0 = 0; c0 < 16; c0 += 8) {
      bf16x8 v8 = *(const bf16x8*)(Vp + (size_t)key*1024 + ch + c0);
      #pragma unroll
      for (int j = 0; j < 8; ++j) Vt[ch+c0+j][key] = (u16)v8[j];
    }
  }
  for (int i = t; i < NKEY; i += 256)
    lmb[i] = 1e9f * ((ROWMODE ? mask[b*R + i] : mask[i*R + b]) - 1.0f);
  __syncthreads();

  // Q a-frags (direct global)
  bf16x8 qa[MT];
  #pragma unroll
  for (int m = 0; m < MT; ++m)
    qa[m] = *(const bf16x8*)(Qp + (size_t)(w*MT*16 + m*16 + l16)*1024 + g16*8);

  f32x4 oacc[MT][2];
  f32x4 lsum[MT];
  #pragma unroll
  for (int m = 0; m < MT; ++m) {
    oacc[m][0] = (f32x4){0.f,0.f,0.f,0.f};
    oacc[m][1] = (f32x4){0.f,0.f,0.f,0.f};
    lsum[m]    = (f32x4){0.f,0.f,0.f,0.f};
  }

  for (int kv = 0; kv < KVI; ++kv) {
    // ---- QK^T, one n-tile at a time (keeps regs low) ----
    #pragma unroll
    for (int n = 0; n < 4; ++n) {
      int key0 = kv*64 + n*16;
      bf16x8 kb = *(const bf16x8*)(Kp + (size_t)(key0 + l16)*1024 + g16*8);
      f32x4 sac[MT];
      #pragma unroll
      for (int m = 0; m < MT; ++m)
        sac[m] = __builtin_amdgcn_mfma_f32_16x16x32_bf16(qa[m], kb, (f32x4){0.f,0.f,0.f,0.f}, 0, 0, 0);
      int kcol = key0 + l16;
      float lm = lmb[kcol];
      #pragma unroll
      for (int m = 0; m < MT; ++m) {
        int qrow = w*MT*16 + m*16 + g16*4;
        float p0, p1, p2, p3;
        if (ROWMODE) {
          const float* bp = bias + (size_t)h*NPAIR + (size_t)qrow*R + kcol;
          p0 = __expf(sac[m][0] + lm + bp[0]);
          p1 = __expf(sac[m][1] + lm + bp[256]);
          p2 = __expf(sac[m][2] + lm + bp[512]);
          p3 = __expf(sac[m][3] + lm + bp[768]);
        } else {
          p0 = __expf(sac[m][0] + lm);
          p1 = __expf(sac[m][1] + lm);
          p2 = __expf(sac[m][2] + lm);
          p3 = __expf(sac[m][3] + lm);
        }
        lsum[m][0] += p0; lsum[m][1] += p1;
        lsum[m][2] += p2; lsum[m][3] += p3;
        int qr = m*16 + g16*4;
        int kc = n*16 + l16;
        Ps[w][qr+0][kc] = f2bf(p0);
        Ps[w][qr+1][kc] = f2bf(p1);
        Ps[w][qr+2][kc] = f2bf(p2);
        Ps[w][qr+3][kc] = f2bf(p3);
      }
    }
    // ---- PV ----
    bf16x8 vb[2][2];
    #pragma unroll
    for (int n2 = 0; n2 < 2; ++n2)
      #pragma unroll
      for (int tt = 0; tt < 2; ++tt)
        vb[n2][tt] = *(const bf16x8*)(&Vt[n2*16 + l16][kv*64 + tt*32 + g16*8]);
    #pragma unroll
    for (int m = 0; m < MT; ++m) {
      #pragma unroll
      for (int tt = 0; tt < 2; ++tt) {
        bf16x8 pa = *(const bf16x8*)(&Ps[w][m*16 + l16][tt*32 + g16*8]);
        #pragma unroll
        for (int n2 = 0; n2 < 2; ++n2)
          oacc[m][n2] = __builtin_amdgcn_mfma_f32_16x16x32_bf16(pa, vb[n2][tt], oacc[m][n2], 0, 0, 0);
      }
    }
  }

  // reduce lsum across the 16 lanes holding one row's columns
  #pragma unroll
  for (int m = 0; m < MT; ++m)
    #pragma unroll
    for (int r = 0; r < 4; ++r) {
      float v = lsum[m][r];
      v += __shfl_xor(v, 1); v += __shfl_xor(v, 2);
      v += __shfl_xor(v, 4); v += __shfl_xor(v, 8);
      lsum[m][r] = v;
    }

  size_t baseO = (size_t)b * NKEY * 256 + h * 32;
  #pragma unroll
  for (int m = 0; m < MT; ++m) {
    #pragma unroll
    for (int n2 = 0; n2 < 2; ++n2) {
      int c = n2*16 + l16;
      #pragma unroll
      for (int r = 0; r < 4; ++r) {
        int qrow = w*MT*16 + m*16 + g16*4 + r;
        float gate = bf2f(Gp[(size_t)qrow*1024 + c]);
        og[baseO + (size_t)qrow*256 + c] = f2bf(oacc[m][n2][r] / lsum[m][r] * gate);
      }
    }
  }
}

extern "C" void kernel_launch(void* const* d_in, const int* in_sizes, int n_in,
                              void* d_out, int out_size, void* d_ws, size_t ws_size,
                              hipStream_t stream)
{
  const float* node         = (const float*)d_in[0];
  const float* pair         = (const float*)d_in[1];
  const float* node_mask    = (const float*)d_in[2];
  const float* row_ln_m_g   = (const float*)d_in[3];
  const float* row_ln_m_b   = (const float*)d_in[4];
  const float* row_ln_z_g   = (const float*)d_in[5];
  const float* row_ln_z_b   = (const float*)d_in[6];
  const float* row_b_w      = (const float*)d_in[7];
  const float* row_wq       = (const float*)d_in[8];
  const float* row_wk       = (const float*)d_in[9];
  const float* row_wv       = (const float*)d_in[10];
  const float* row_wg       = (const float*)d_in[11];
  const float* row_bg       = (const float*)d_in[12];
  const float* row_wo       = (const float*)d_in[13];
  const float* row_out_bias = (const float*)d_in[14];
  const float* col_ln_g     = (const float*)d_in[15];
  const float* col_ln_b     = (const float*)d_in[16];
  const float* col_wq       = (const float*)d_in[17];
  const float* col_wk       = (const float*)d_in[18];
  const float* col_wv       = (const float*)d_in[19];
  const float* col_wg       = (const float*)d_in[20];
  const float* col_bg       = (const float*)d_in[21];
  const float* col_wo       = (const float*)d_in[22];
  const float* col_bo       = (const float*)d_in[23];
  const float* tr_ln_g      = (const float*)d_in[24];
  const float* tr_ln_b      = (const float*)d_in[25];
  const float* tr_w1        = (const float*)d_in[26];
  const float* tr_b1        = (const float*)d_in[27];
  const float* tr_w2        = (const float*)d_in[28];
  const float* tr_b2        = (const float*)d_in[29];

  float* out = (float*)d_out;
  char* ws8 = (char*)d_ws;
  const size_t MB = 1ull << 20;
  u16*   A     = (u16*)(ws8);               // 16 MB  LN out [32768][256] bf16
  u16*   QKVG  = (u16*)(ws8 + 16*MB);       // 64 MB  [32768][1024] bf16 (also T1)
  u16*   Ob    = (u16*)(ws8 + 80*MB);       // 16 MB  gated attn out bf16
  float* Dbias = (float*)(ws8 + 96*MB);     // 2 MB   [H][R][R]
  u16*   Wb    = (u16*)(ws8 + 100*MB);      // bf16 weight arena
  u16*   T1    = QKVG;

  const float qs = 0.17677669529663687f;    // 1/sqrt(32)

  // arena: [row q|k|v|g] [row o] [col q|k|v|g] [col o] [w1] [w2]
  u16* Wrqkvg = Wb + 0;        // 4*65536
  u16* Wro    = Wb + 262144;
  u16* Wcqkvg = Wb + 327680;
  u16* Wco    = Wb + 589824;
  u16* W1     = Wb + 655360;
  u16* W2     = Wb + 917504;

  CvtArgs ca;
  const float* srcs[12] = {row_wq,row_wk,row_wv,row_wg,row_wo,
                           col_wq,col_wk,col_wv,col_wg,col_wo,tr_w1,tr_w2};
  int offs[12] = {0,65536,131072,196608,262144,327680,393216,458752,524288,589824,655360,917504};
  int ns[12]   = {65536,65536,65536,65536,65536,65536,65536,65536,65536,65536,262144,262144};
  for (int i = 0; i < 12; ++i) {
    ca.src[i] = srcs[i]; ca.off[i] = offs[i]; ca.n[i] = ns[i];
    ca.scale[i] = (i == 0 || i == 5) ? qs : 1.0f;
  }
  cvt_w_kernel<<<dim3(256,12), 256, 0, stream>>>(ca, Wb);

  dim3 g256(2, 256), g1024(8, 256);

  // --- row attention ---
  ln256_kernel<<<8192, 256, 0, stream>>>(node, A, row_ln_m_g, row_ln_m_b, 0);
  pair_bias_kernel<<<16384, 256, 0, stream>>>(pair, row_ln_z_g, row_ln_z_b, row_b_w, Dbias);
  gemm_mfma<<<g1024, 256, 0, stream>>>(A, Wrqkvg, QKVG, NROWS, 1024, 256, 6, row_bg, nullptr);
  attn_mfma<256,4,true><<<dim3(8,128), 256, 0, stream>>>(QKVG, Dbias, node_mask, Ob);
  gemm_mfma<<<g256, 256, 0, stream>>>(Ob, Wro, out, NROWS, 256, 256, 4, row_out_bias, node);

  // --- column attention (in [r,s,d] layout) ---
  ln256_kernel<<<8192, 256, 0, stream>>>(out, A, col_ln_g, col_ln_b, 1);
  gemm_mfma<<<g1024, 256, 0, stream>>>(A, Wcqkvg, QKVG, NROWS, 1024, 256, 6, col_bg, nullptr);
  attn_mfma<128,2,false><<<dim3(8,256), 256, 0, stream>>>(QKVG, nullptr, node_mask, Ob);
  gemm_mfma<<<g256, 256, 0, stream>>>(Ob, Wco, out, NROWS, 256, 256, 5, col_bo, out);

  // --- transition ---
  ln256_kernel<<<8192, 256, 0, stream>>>(out, A, tr_ln_g, tr_ln_b, 0);
  gemm_mfma<<<g1024, 256, 0, stream>>>(A, W1, T1, NROWS, 1024, 256, 3, tr_b1, nullptr);
  gemm_mfma<<<g256, 256, 0, stream>>>(T1, W2, out, NROWS, 256, 1024, 4, tr_b2, out);
}

// Round 4
// 514.404 us; speedup vs baseline: 3.2194x; 1.1051x over previous
//
#include <hip/hip_runtime.h>
#include <math.h>

#define S 128
#define R 256
#define DMODEL 256
#define H 8
#define CDIM 32
#define HC 256
#define DFF 1024
#define NROWS (S*R)     // 32768
#define NPAIR (R*R)     // 65536
#define LN_EPS 1e-5f

typedef unsigned short u16;
typedef __attribute__((ext_vector_type(8))) short bf16x8;
typedef __attribute__((ext_vector_type(4))) float f32x4;

__device__ __forceinline__ u16 f2bf(float x) {
  unsigned u = __float_as_uint(x);
  u = (u + 0x7fffu + ((u >> 16) & 1u)) >> 16;
  return (u16)u;
}
__device__ __forceinline__ float bf2f(u16 x) {
  return __uint_as_float(((unsigned)x) << 16);
}

__device__ __forceinline__ void gload_lds16(const u16* g, u16* l) {
  __builtin_amdgcn_global_load_lds(
      (const __attribute__((address_space(1))) unsigned int*)g,
      (__attribute__((address_space(3))) unsigned int*)l, 16, 0, 0);
}

// ---------------- weight f32 -> bf16 conversion (12 segments) ----------------
struct CvtArgs {
  const float* src[12];
  int off[12];
  int n[12];
  float scale[12];
};

__global__ __launch_bounds__(256) void cvt_w_kernel(CvtArgs a, u16* __restrict__ dst) {
  int sg = blockIdx.y;
  int i = (blockIdx.x * 256 + threadIdx.x) * 4;
  if (i >= a.n[sg]) return;
  float4 v = *(const float4*)(a.src[sg] + i);
  float sc = a.scale[sg];
  ushort4 o;
  o.x = f2bf(v.x * sc); o.y = f2bf(v.y * sc);
  o.z = f2bf(v.z * sc); o.w = f2bf(v.w * sc);
  *(ushort4*)(dst + a.off[sg] + i) = o;
}

// ---------------- LayerNorm over 256, one row per wave, bf16 out ----------------
__global__ __launch_bounds__(256) void ln256_kernel(
    const float* __restrict__ in, u16* __restrict__ out,
    const float* __restrict__ gamma, const float* __restrict__ beta,
    int tmode)
{
  int wid = threadIdx.x >> 6, lane = threadIdx.x & 63;
  int m = blockIdx.x * 4 + wid;
  int inrow = m;
  if (tmode) { int r = m >> 7, s = m & 127; inrow = s * R + r; }
  float4 x = *(const float4*)(in + (size_t)inrow * DMODEL + lane * 4);
  float sum = x.x + x.y + x.z + x.w;
  float sq  = x.x*x.x + x.y*x.y + x.z*x.z + x.w*x.w;
  #pragma unroll
  for (int off = 32; off; off >>= 1) {
    sum += __shfl_xor(sum, off);
    sq  += __shfl_xor(sq, off);
  }
  float mean = sum * (1.0f/256.0f);
  float var  = sq  * (1.0f/256.0f) - mean*mean;
  float rstd = rsqrtf(var + LN_EPS);
  float4 g = *(const float4*)(gamma + lane*4);
  float4 b = *(const float4*)(beta  + lane*4);
  ushort4 o;
  o.x = f2bf((x.x-mean)*rstd*g.x + b.x);
  o.y = f2bf((x.y-mean)*rstd*g.y + b.y);
  o.z = f2bf((x.z-mean)*rstd*g.z + b.z);
  o.w = f2bf((x.w-mean)*rstd*g.w + b.w);
  *(ushort4*)(out + (size_t)m * DMODEL + lane*4) = o;
}

// ------------- pair LN (over 128) + bias projection -> bias[h][q][k] (f32) -------------
__global__ __launch_bounds__(256) void pair_bias_kernel(
    const float* __restrict__ pair, const float* __restrict__ gamma,
    const float* __restrict__ beta, const float* __restrict__ bw,
    float* __restrict__ bias)
{
  int wid = threadIdx.x >> 6, lane = threadIdx.x & 63;
  int p = blockIdx.x * 4 + wid;
  float2 x = *(const float2*)(pair + (size_t)p * 128 + lane*2);
  float sum = x.x + x.y, sq = x.x*x.x + x.y*x.y;
  #pragma unroll
  for (int off = 32; off; off >>= 1) {
    sum += __shfl_xor(sum, off);
    sq  += __shfl_xor(sq, off);
  }
  float mean = sum * (1.0f/128.0f);
  float rstd = rsqrtf(sq*(1.0f/128.0f) - mean*mean + LN_EPS);
  float z0 = (x.x-mean)*rstd*gamma[lane*2]   + beta[lane*2];
  float z1 = (x.y-mean)*rstd*gamma[lane*2+1] + beta[lane*2+1];
  float a0 = z0*bw[0*128+lane*2] + z1*bw[0*128+lane*2+1];
  float a1 = z0*bw[1*128+lane*2] + z1*bw[1*128+lane*2+1];
  float a2 = z0*bw[2*128+lane*2] + z1*bw[2*128+lane*2+1];
  float a3 = z0*bw[3*128+lane*2] + z1*bw[3*128+lane*2+1];
  float a4 = z0*bw[4*128+lane*2] + z1*bw[4*128+lane*2+1];
  float a5 = z0*bw[5*128+lane*2] + z1*bw[5*128+lane*2+1];
  float a6 = z0*bw[6*128+lane*2] + z1*bw[6*128+lane*2+1];
  float a7 = z0*bw[7*128+lane*2] + z1*bw[7*128+lane*2+1];
  #pragma unroll
  for (int off = 32; off; off >>= 1) {
    a0 += __shfl_xor(a0, off); a1 += __shfl_xor(a1, off);
    a2 += __shfl_xor(a2, off); a3 += __shfl_xor(a3, off);
    a4 += __shfl_xor(a4, off); a5 += __shfl_xor(a5, off);
    a6 += __shfl_xor(a6, off); a7 += __shfl_xor(a7, off);
  }
  float v = a0;
  v = (lane==1)?a1:v; v = (lane==2)?a2:v; v = (lane==3)?a3:v;
  v = (lane==4)?a4:v; v = (lane==5)?a5:v; v = (lane==6)?a6:v; v = (lane==7)?a7:v;
  if (lane < 8) bias[(size_t)lane*NPAIR + p] = v;
}

// ---------------- bf16 MFMA NT GEMM: C[M,N] = A[M,K] * W[N,K]^T ----------------
// modes: 1: bf16 out  2: bf16 sigmoid(x+bias[n])  3: bf16 relu(x+bias[n])
//        4: f32 out = x + res[m,n] + bias[n]
//        5: f32 transposed: idx=((m&127)*R + (m>>7))*N + n
//        6: bf16 out; cols >= 768 get sigmoid(x + bias[col-768])   (fused QKVG)
__global__ __launch_bounds__(256) void gemm_mfma(
    const u16* __restrict__ A, const u16* __restrict__ W,
    void* __restrict__ Cout, int M, int N, int K,
    int mode, const float* __restrict__ bias, const float* __restrict__ res)
{
  __shared__ u16 As[128*32];
  __shared__ u16 Bs[128*32];
  int t = threadIdx.x;
  int lane = t & 63;
  int w = t >> 6;
  int wm = w >> 1, wn = w & 1;
  int bn = blockIdx.x * 128, bm = blockIdx.y * 128;

  int sr = t >> 2;
  int sc = (t & 3) * 8;
  const u16* Ag = A + (size_t)(bm + sr) * K + sc;
  const u16* Wg = W + (size_t)(bn + sr) * K + sc;
  u16* Al = As + sr*32 + sc;
  u16* Bl = Bs + sr*32 + sc;

  f32x4 acc[4][4];
  #pragma unroll
  for (int m=0;m<4;++m)
    #pragma unroll
    for (int n=0;n<4;++n) acc[m][n] = (f32x4){0.f,0.f,0.f,0.f};

  const u16* ap = As + ((size_t)(wm*64 + (lane&15)))*32 + (lane>>4)*8;
  const u16* bp = Bs + ((size_t)(wn*64 + (lane&15)))*32 + (lane>>4)*8;

  for (int k0 = 0; k0 < K; k0 += 32) {
    gload_lds16(Ag + k0, Al);
    gload_lds16(Ag + (size_t)64*K + k0, Al + 64*32);
    gload_lds16(Wg + k0, Bl);
    gload_lds16(Wg + (size_t)64*K + k0, Bl + 64*32);
    __syncthreads();
    bf16x8 a[4], b[4];
    #pragma unroll
    for (int m=0;m<4;++m) a[m] = *(const bf16x8*)(ap + m*16*32);
    #pragma unroll
    for (int n=0;n<4;++n) b[n] = *(const bf16x8*)(bp + n*16*32);
    #pragma unroll
    for (int m=0;m<4;++m)
      #pragma unroll
      for (int n=0;n<4;++n)
        acc[m][n] = __builtin_amdgcn_mfma_f32_16x16x32_bf16(a[m], b[n], acc[m][n], 0, 0, 0);
    __syncthreads();
  }

  int lm = lane & 15;
  int row0 = bm + wm*64 + ((lane>>4)<<2);
  #pragma unroll
  for (int m=0;m<4;++m) {
    #pragma unroll
    for (int n=0;n<4;++n) {
      int col = bn + wn*64 + n*16 + lm;
      float bb = 0.f;
      if (mode == 2 || mode == 3 || mode == 4) bb = bias[col];
      #pragma unroll
      for (int r=0;r<4;++r) {
        int row = row0 + m*16 + r;
        float val = acc[m][n][r];
        if (mode == 1) {
          ((u16*)Cout)[(size_t)row*N + col] = f2bf(val);
        } else if (mode == 2) {
          ((u16*)Cout)[(size_t)row*N + col] = f2bf(1.0f/(1.0f+__expf(-(val+bb))));
        } else if (mode == 3) {
          ((u16*)Cout)[(size_t)row*N + col] = f2bf(fmaxf(val+bb, 0.0f));
        } else if (mode == 4) {
          size_t i2 = (size_t)row*N + col;
          ((float*)Cout)[i2] = val + res[i2] + bb;
        } else if (mode == 5) {
          int rr = row >> 7, ss = row & 127;
          size_t i2 = ((size_t)ss*R + rr)*N + col;
          ((float*)Cout)[i2] = val + res[i2] + bias[col];
        } else { // 6
          float v2 = val;
          if (col >= 768) v2 = 1.0f/(1.0f+__expf(-(val + bias[col-768])));
          ((u16*)Cout)[(size_t)row*N + col] = f2bf(v2);
        }
      }
    }
  }
}

// ---------------- MFMA attention (transposed QK^T: A=K, B=Q) ----------------
// QKVG: [b-panel rows][1024] bf16, Q at +0, K at +256, V at +512, G at +768.
// One block per (h, b); 512 threads = 8 waves; wave owns MT*16 q-rows.
// Lane's 4 QK acc values = 4 consecutive KEYS for one query -> bias/mask are
// float4 loads; P-tile write is one ushort4.
template<int NKEY, int MT, bool ROWMODE>
__global__ __launch_bounds__(512) void attn_mfma(
    const u16* __restrict__ QKVG, const float* __restrict__ bias,
    const float* __restrict__ mask, u16* __restrict__ og)
{
  __shared__ u16 Vt[32][NKEY+8];
  __shared__ u16 Ps[8][16][72];
  __shared__ float lmb[NKEY];
  constexpr int KVI = NKEY/64;
  int h = blockIdx.x, b = blockIdx.y;
  int t = threadIdx.x, lane = t & 63, w = t >> 6;
  int g16 = lane >> 4, l16 = lane & 15;

  size_t base1 = (size_t)b * NKEY * 1024 + h * 32;
  const u16* Qp = QKVG + base1;
  const u16* Kp = QKVG + base1 + 256;
  const u16* Vp = QKVG + base1 + 512;
  const u16* Gp = QKVG + base1 + 768;

  // stage V transposed
  if (NKEY == 256) {
    int key = t & 255, ch0 = (t >> 8) * 16;
    #pragma unroll
    for (int c0 = 0; c0 < 16; c0 += 8) {
      bf16x8 v8 = *(const bf16x8*)(Vp + (size_t)key*1024 + ch0 + c0);
      #pragma unroll
      for (int j = 0; j < 8; ++j) Vt[ch0+c0+j][key] = (u16)v8[j];
    }
  } else {
    int key = t & 127, ch0 = (t >> 7) * 8;
    bf16x8 v8 = *(const bf16x8*)(Vp + (size_t)key*1024 + ch0);
    #pragma unroll
    for (int j = 0; j < 8; ++j) Vt[ch0+j][key] = (u16)v8[j];
  }
  for (int i = t; i < NKEY; i += 512)
    lmb[i] = 1e9f * ((ROWMODE ? mask[b*R + i] : mask[i*R + b]) - 1.0f);
  __syncthreads();

  int qw = w * MT * 16;     // wave's first q row (block-local)
  bf16x8 qb[MT];
  #pragma unroll
  for (int m = 0; m < MT; ++m)
    qb[m] = *(const bf16x8*)(Qp + (size_t)(qw + m*16 + l16)*1024 + g16*8);

  f32x4 oacc[MT][2];
  float lsum[MT];
  #pragma unroll
  for (int m = 0; m < MT; ++m) {
    oacc[m][0] = (f32x4){0.f,0.f,0.f,0.f};
    oacc[m][1] = (f32x4){0.f,0.f,0.f,0.f};
    lsum[m] = 0.f;
  }
  const float* bias_b = bias + (size_t)h*NPAIR;

  for (int kv = 0; kv < KVI; ++kv) {
    int k0w = kv*64;
    bf16x8 ka[4];
    #pragma unroll
    for (int kt = 0; kt < 4; ++kt)
      ka[kt] = *(const bf16x8*)(Kp + (size_t)(k0w + kt*16 + l16)*1024 + g16*8);
    bf16x8 vb[2][2];
    #pragma unroll
    for (int n2 = 0; n2 < 2; ++n2)
      #pragma unroll
      for (int tt = 0; tt < 2; ++tt)
        vb[n2][tt] = *(const bf16x8*)(&Vt[n2*16 + l16][k0w + tt*32 + g16*8]);

    #pragma unroll
    for (int m = 0; m < MT; ++m) {
      int q = qw + m*16 + l16;
      #pragma unroll
      for (int kt = 0; kt < 4; ++kt) {
        f32x4 sac = __builtin_amdgcn_mfma_f32_16x16x32_bf16(
            ka[kt], qb[m], (f32x4){0.f,0.f,0.f,0.f}, 0, 0, 0);
        int k0 = k0w + kt*16 + g16*4;
        float4 lm4 = *(const float4*)&lmb[k0];
        float p0, p1, p2, p3;
        if (ROWMODE) {
          float4 b4 = *(const float4*)(bias_b + (size_t)q*R + k0);
          p0 = __expf(sac[0] + lm4.x + b4.x);
          p1 = __expf(sac[1] + lm4.y + b4.y);
          p2 = __expf(sac[2] + lm4.z + b4.z);
          p3 = __expf(sac[3] + lm4.w + b4.w);
        } else {
          p0 = __expf(sac[0] + lm4.x);
          p1 = __expf(sac[1] + lm4.y);
          p2 = __expf(sac[2] + lm4.z);
          p3 = __expf(sac[3] + lm4.w);
        }
        lsum[m] += (p0 + p1) + (p2 + p3);
        ushort4 pk;
        pk.x = f2bf(p0); pk.y = f2bf(p1); pk.z = f2bf(p2); pk.w = f2bf(p3);
        *(ushort4*)&Ps[w][l16][kt*16 + g16*4] = pk;
      }
      #pragma unroll
      for (int tt = 0; tt < 2; ++tt) {
        bf16x8 pa = *(const bf16x8*)&Ps[w][l16][tt*32 + g16*8];
        oacc[m][0] = __builtin_amdgcn_mfma_f32_16x16x32_bf16(pa, vb[0][tt], oacc[m][0], 0, 0, 0);
        oacc[m][1] = __builtin_amdgcn_mfma_f32_16x16x32_bf16(pa, vb[1][tt], oacc[m][1], 0, 0, 0);
      }
    }
  }

  // lsum held per-lane for q = qw + m*16 + l16; reduce over g16 copies
  #pragma unroll
  for (int m = 0; m < MT; ++m) {
    float v = lsum[m];
    v += __shfl_xor(v, 16);
    v += __shfl_xor(v, 32);
    lsum[m] = v;
  }

  size_t baseO = (size_t)b * NKEY * 256 + h * 32;
  #pragma unroll
  for (int m = 0; m < MT; ++m) {
    float inv[4];
    #pragma unroll
    for (int r = 0; r < 4; ++r) inv[r] = 1.0f / __shfl(lsum[m], g16*4 + r);
    #pragma unroll
    for (int n2 = 0; n2 < 2; ++n2) {
      int c = n2*16 + l16;
      #pragma unroll
      for (int r = 0; r < 4; ++r) {
        int q = qw + m*16 + g16*4 + r;
        float gate = bf2f(Gp[(size_t)q*1024 + c]);
        og[baseO + (size_t)q*256 + c] = f2bf(oacc[m][n2][r] * inv[r] * gate);
      }
    }
  }
}

extern "C" void kernel_launch(void* const* d_in, const int* in_sizes, int n_in,
                              void* d_out, int out_size, void* d_ws, size_t ws_size,
                              hipStream_t stream)
{
  const float* node         = (const float*)d_in[0];
  const float* pair         = (const float*)d_in[1];
  const float* node_mask    = (const float*)d_in[2];
  const float* row_ln_m_g   = (const float*)d_in[3];
  const float* row_ln_m_b   = (const float*)d_in[4];
  const float* row_ln_z_g   = (const float*)d_in[5];
  const float* row_ln_z_b   = (const float*)d_in[6];
  const float* row_b_w      = (const float*)d_in[7];
  const float* row_wq       = (const float*)d_in[8];
  const float* row_wk       = (const float*)d_in[9];
  const float* row_wv       = (const float*)d_in[10];
  const float* row_wg       = (const float*)d_in[11];
  const float* row_bg       = (const float*)d_in[12];
  const float* row_wo       = (const float*)d_in[13];
  const float* row_out_bias = (const float*)d_in[14];
  const float* col_ln_g     = (const float*)d_in[15];
  const float* col_ln_b     = (const float*)d_in[16];
  const float* col_wq       = (const float*)d_in[17];
  const float* col_wk       = (const float*)d_in[18];
  const float* col_wv       = (const float*)d_in[19];
  const float* col_wg       = (const float*)d_in[20];
  const float* col_bg       = (const float*)d_in[21];
  const float* col_wo       = (const float*)d_in[22];
  const float* col_bo       = (const float*)d_in[23];
  const float* tr_ln_g      = (const float*)d_in[24];
  const float* tr_ln_b      = (const float*)d_in[25];
  const float* tr_w1        = (const float*)d_in[26];
  const float* tr_b1        = (const float*)d_in[27];
  const float* tr_w2        = (const float*)d_in[28];
  const float* tr_b2        = (const float*)d_in[29];

  float* out = (float*)d_out;
  char* ws8 = (char*)d_ws;
  const size_t MB = 1ull << 20;
  u16*   A     = (u16*)(ws8);               // 16 MB  LN out [32768][256] bf16
  u16*   QKVG  = (u16*)(ws8 + 16*MB);       // 64 MB  [32768][1024] bf16 (also T1)
  u16*   Ob    = (u16*)(ws8 + 80*MB);       // 16 MB  gated attn out bf16
  float* Dbias = (float*)(ws8 + 96*MB);     // 2 MB   [H][R][R]
  u16*   Wb    = (u16*)(ws8 + 100*MB);      // bf16 weight arena
  u16*   T1    = QKVG;

  const float qs = 0.17677669529663687f;    // 1/sqrt(32)

  // arena: [row q|k|v|g] [row o] [col q|k|v|g] [col o] [w1] [w2]
  u16* Wrqkvg = Wb + 0;
  u16* Wro    = Wb + 262144;
  u16* Wcqkvg = Wb + 327680;
  u16* Wco    = Wb + 589824;
  u16* W1     = Wb + 655360;
  u16* W2     = Wb + 917504;

  CvtArgs ca;
  const float* srcs[12] = {row_wq,row_wk,row_wv,row_wg,row_wo,
                           col_wq,col_wk,col_wv,col_wg,col_wo,tr_w1,tr_w2};
  int offs[12] = {0,65536,131072,196608,262144,327680,393216,458752,524288,589824,655360,917504};
  int ns[12]   = {65536,65536,65536,65536,65536,65536,65536,65536,65536,65536,262144,262144};
  for (int i = 0; i < 12; ++i) {
    ca.src[i] = srcs[i]; ca.off[i] = offs[i]; ca.n[i] = ns[i];
    ca.scale[i] = (i == 0 || i == 5) ? qs : 1.0f;
  }
  cvt_w_kernel<<<dim3(256,12), 256, 0, stream>>>(ca, Wb);

  dim3 g256(2, 256), g1024(8, 256);

  // --- row attention ---
  ln256_kernel<<<8192, 256, 0, stream>>>(node, A, row_ln_m_g, row_ln_m_b, 0);
  pair_bias_kernel<<<16384, 256, 0, stream>>>(pair, row_ln_z_g, row_ln_z_b, row_b_w, Dbias);
  gemm_mfma<<<g1024, 256, 0, stream>>>(A, Wrqkvg, QKVG, NROWS, 1024, 256, 6, row_bg, nullptr);
  attn_mfma<256,2,true><<<dim3(8,128), 512, 0, stream>>>(QKVG, Dbias, node_mask, Ob);
  gemm_mfma<<<g256, 256, 0, stream>>>(Ob, Wro, out, NROWS, 256, 256, 4, row_out_bias, node);

  // --- column attention (in [r,s,d] layout) ---
  ln256_kernel<<<8192, 256, 0, stream>>>(out, A, col_ln_g, col_ln_b, 1);
  gemm_mfma<<<g1024, 256, 0, stream>>>(A, Wcqkvg, QKVG, NROWS, 1024, 256, 6, col_bg, nullptr);
  attn_mfma<128,1,false><<<dim3(8,256), 512, 0, stream>>>(QKVG, Dbias, node_mask, Ob);
  gemm_mfma<<<g256, 256, 0, stream>>>(Ob, Wco, out, NROWS, 256, 256, 5, col_bo, out);

  // --- transition ---
  ln256_kernel<<<8192, 256, 0, stream>>>(out, A, tr_ln_g, tr_ln_b, 0);
  gemm_mfma<<<g1024, 256, 0, stream>>>(A, W1, T1, NROWS, 1024, 256, 3, tr_b1, nullptr);
  gemm_mfma<<<g256, 256, 0, stream>>>(T1, W2, out, NROWS, 256, 1024, 4, tr_b2, out);
}

// Round 5
// 502.883 us; speedup vs baseline: 3.2932x; 1.0229x over previous
//
#include <hip/hip_runtime.h>
#include <math.h>

#define S 128
#define R 256
#define DMODEL 256
#define H 8
#define CDIM 32
#define HC 256
#define DFF 1024
#define NROWS (S*R)     // 32768
#define NPAIR (R*R)     // 65536
#define LN_EPS 1e-5f

typedef unsigned short u16;
typedef __attribute__((ext_vector_type(8))) short bf16x8;
typedef __attribute__((ext_vector_type(4))) float f32x4;

__device__ __forceinline__ u16 f2bf(float x) {
  unsigned u = __float_as_uint(x);
  u = (u + 0x7fffu + ((u >> 16) & 1u)) >> 16;
  return (u16)u;
}
__device__ __forceinline__ float bf2f(u16 x) {
  return __uint_as_float(((unsigned)x) << 16);
}

__device__ __forceinline__ void gload_lds16(const u16* g, u16* l) {
  __builtin_amdgcn_global_load_lds(
      (const __attribute__((address_space(1))) unsigned int*)g,
      (__attribute__((address_space(3))) unsigned int*)l, 16, 0, 0);
}

// ---------------- weight f32 -> bf16 conversion (12 segments) ----------------
struct CvtArgs {
  const float* src[12];
  int off[12];
  int n[12];
  float scale[12];
};

__global__ __launch_bounds__(256) void cvt_w_kernel(CvtArgs a, u16* __restrict__ dst) {
  int sg = blockIdx.y;
  int i = (blockIdx.x * 256 + threadIdx.x) * 4;
  if (i >= a.n[sg]) return;
  float4 v = *(const float4*)(a.src[sg] + i);
  float sc = a.scale[sg];
  ushort4 o;
  o.x = f2bf(v.x * sc); o.y = f2bf(v.y * sc);
  o.z = f2bf(v.z * sc); o.w = f2bf(v.w * sc);
  *(ushort4*)(dst + a.off[sg] + i) = o;
}

// ---------------- LayerNorm over 256, one row per wave, bf16 out ----------------
__global__ __launch_bounds__(256) void ln256_kernel(
    const float* __restrict__ in, u16* __restrict__ out,
    const float* __restrict__ gamma, const float* __restrict__ beta,
    int tmode)
{
  int wid = threadIdx.x >> 6, lane = threadIdx.x & 63;
  int m = blockIdx.x * 4 + wid;
  int inrow = m;
  if (tmode) { int r = m >> 7, s = m & 127; inrow = s * R + r; }
  float4 x = *(const float4*)(in + (size_t)inrow * DMODEL + lane * 4);
  float sum = x.x + x.y + x.z + x.w;
  float sq  = x.x*x.x + x.y*x.y + x.z*x.z + x.w*x.w;
  #pragma unroll
  for (int off = 32; off; off >>= 1) {
    sum += __shfl_xor(sum, off);
    sq  += __shfl_xor(sq, off);
  }
  float mean = sum * (1.0f/256.0f);
  float var  = sq  * (1.0f/256.0f) - mean*mean;
  float rstd = rsqrtf(var + LN_EPS);
  float4 g = *(const float4*)(gamma + lane*4);
  float4 b = *(const float4*)(beta  + lane*4);
  ushort4 o;
  o.x = f2bf((x.x-mean)*rstd*g.x + b.x);
  o.y = f2bf((x.y-mean)*rstd*g.y + b.y);
  o.z = f2bf((x.z-mean)*rstd*g.z + b.z);
  o.w = f2bf((x.w-mean)*rstd*g.w + b.w);
  *(ushort4*)(out + (size_t)m * DMODEL + lane*4) = o;
}

// ------------- pair LN (over 128) + bias projection -> bias[h][q][k] (f32) -------------
__global__ __launch_bounds__(256) void pair_bias_kernel(
    const float* __restrict__ pair, const float* __restrict__ gamma,
    const float* __restrict__ beta, const float* __restrict__ bw,
    float* __restrict__ bias)
{
  int wid = threadIdx.x >> 6, lane = threadIdx.x & 63;
  int p = blockIdx.x * 4 + wid;
  float2 x = *(const float2*)(pair + (size_t)p * 128 + lane*2);
  float sum = x.x + x.y, sq = x.x*x.x + x.y*x.y;
  #pragma unroll
  for (int off = 32; off; off >>= 1) {
    sum += __shfl_xor(sum, off);
    sq  += __shfl_xor(sq, off);
  }
  float mean = sum * (1.0f/128.0f);
  float rstd = rsqrtf(sq*(1.0f/128.0f) - mean*mean + LN_EPS);
  float z0 = (x.x-mean)*rstd*gamma[lane*2]   + beta[lane*2];
  float z1 = (x.y-mean)*rstd*gamma[lane*2+1] + beta[lane*2+1];
  float a0 = z0*bw[0*128+lane*2] + z1*bw[0*128+lane*2+1];
  float a1 = z0*bw[1*128+lane*2] + z1*bw[1*128+lane*2+1];
  float a2 = z0*bw[2*128+lane*2] + z1*bw[2*128+lane*2+1];
  float a3 = z0*bw[3*128+lane*2] + z1*bw[3*128+lane*2+1];
  float a4 = z0*bw[4*128+lane*2] + z1*bw[4*128+lane*2+1];
  float a5 = z0*bw[5*128+lane*2] + z1*bw[5*128+lane*2+1];
  float a6 = z0*bw[6*128+lane*2] + z1*bw[6*128+lane*2+1];
  float a7 = z0*bw[7*128+lane*2] + z1*bw[7*128+lane*2+1];
  #pragma unroll
  for (int off = 32; off; off >>= 1) {
    a0 += __shfl_xor(a0, off); a1 += __shfl_xor(a1, off);
    a2 += __shfl_xor(a2, off); a3 += __shfl_xor(a3, off);
    a4 += __shfl_xor(a4, off); a5 += __shfl_xor(a5, off);
    a6 += __shfl_xor(a6, off); a7 += __shfl_xor(a7, off);
  }
  float v = a0;
  v = (lane==1)?a1:v; v = (lane==2)?a2:v; v = (lane==3)?a3:v;
  v = (lane==4)?a4:v; v = (lane==5)?a5:v; v = (lane==6)?a6:v; v = (lane==7)?a7:v;
  if (lane < 8) bias[(size_t)lane*NPAIR + p] = v;
}

// ---------------- bf16 MFMA NT GEMM: C[M,N] = A[M,K] * W[N,K]^T ----------------
// 2-phase double-buffered pipeline (counted vmcnt) + XOR chunk-swizzle.
// modes: 1: bf16 out  2: bf16 sigmoid(x+bias[n])  3: bf16 relu(x+bias[n])
//        4: f32 out = x + res[m,n] + bias[n]
//        5: f32 transposed: idx=((m&127)*R + (m>>7))*N + n
//        6: bf16 out; cols >= 768 get sigmoid(x + bias[col-768])   (fused QKVG)
__global__ __launch_bounds__(256) void gemm_mfma(
    const u16* __restrict__ A, const u16* __restrict__ W,
    void* __restrict__ Cout, int M, int N, int K,
    int mode, const float* __restrict__ bias, const float* __restrict__ res)
{
  __shared__ u16 As[2][128*32];
  __shared__ u16 Bs[2][128*32];
  int t = threadIdx.x;
  int lane = t & 63;
  int w = t >> 6;
  int wm = w >> 1, wn = w & 1;
  int g16 = lane >> 4, l16 = lane & 15;
  int bn = blockIdx.x * 128, bm = blockIdx.y * 128;

  // staging: thread t covers rows sr, sr+64; chunk scq, source chunk XOR-swizzled
  int sr = t >> 2;
  int scq = t & 3;
  int swz = scq ^ ((sr >> 1) & 3);
  const u16* Ag = A + (size_t)(bm + sr) * K + swz * 8;
  const u16* Wg = W + (size_t)(bn + sr) * K + swz * 8;
  int ldst = t * 8;   // linear dest offset (elems) = sr*32 + scq*8

  // fragment read slot (XOR involution; depends only on l16 -> per-lane const)
  int slot = (g16 ^ ((l16 >> 1) & 3)) * 8;

  f32x4 acc[4][4];
  #pragma unroll
  for (int m=0;m<4;++m)
    #pragma unroll
    for (int n=0;n<4;++n) acc[m][n] = (f32x4){0.f,0.f,0.f,0.f};

  const int nk = K >> 5;

#define STAGE(pb, k0) do { \
    gload_lds16(Ag + (k0), &As[pb][ldst]); \
    gload_lds16(Ag + (size_t)64*K + (k0), &As[pb][64*32 + ldst]); \
    gload_lds16(Wg + (k0), &Bs[pb][ldst]); \
    gload_lds16(Wg + (size_t)64*K + (k0), &Bs[pb][64*32 + ldst]); \
  } while(0)

  STAGE(0, 0);
  int buf = 0;
  for (int k = 0; k < nk; ++k) {
    if (k + 1 < nk) {
      STAGE(buf^1, (k+1)*32);
      asm volatile("s_waitcnt vmcnt(4)" ::: "memory");
    } else {
      asm volatile("s_waitcnt vmcnt(0)" ::: "memory");
    }
    __builtin_amdgcn_s_barrier();
    bf16x8 a[4], b[4];
    #pragma unroll
    for (int m=0;m<4;++m)
      a[m] = *(const bf16x8*)&As[buf][(wm*64 + l16 + m*16)*32 + slot];
    #pragma unroll
    for (int n=0;n<4;++n)
      b[n] = *(const bf16x8*)&Bs[buf][(wn*64 + l16 + n*16)*32 + slot];
    #pragma unroll
    for (int m=0;m<4;++m)
      #pragma unroll
      for (int n=0;n<4;++n)
        acc[m][n] = __builtin_amdgcn_mfma_f32_16x16x32_bf16(a[m], b[n], acc[m][n], 0, 0, 0);
    __builtin_amdgcn_s_barrier();
    buf ^= 1;
  }
#undef STAGE

  int lm = lane & 15;
  int row0 = bm + wm*64 + (g16<<2);
  #pragma unroll
  for (int m=0;m<4;++m) {
    #pragma unroll
    for (int n=0;n<4;++n) {
      int col = bn + wn*64 + n*16 + lm;
      float bb = 0.f;
      if (mode == 2 || mode == 3 || mode == 4) bb = bias[col];
      #pragma unroll
      for (int r=0;r<4;++r) {
        int row = row0 + m*16 + r;
        float val = acc[m][n][r];
        if (mode == 1) {
          ((u16*)Cout)[(size_t)row*N + col] = f2bf(val);
        } else if (mode == 2) {
          ((u16*)Cout)[(size_t)row*N + col] = f2bf(1.0f/(1.0f+__expf(-(val+bb))));
        } else if (mode == 3) {
          ((u16*)Cout)[(size_t)row*N + col] = f2bf(fmaxf(val+bb, 0.0f));
        } else if (mode == 4) {
          size_t i2 = (size_t)row*N + col;
          ((float*)Cout)[i2] = val + res[i2] + bb;
        } else if (mode == 5) {
          int rr = row >> 7, ss = row & 127;
          size_t i2 = ((size_t)ss*R + rr)*N + col;
          ((float*)Cout)[i2] = val + res[i2] + bias[col];
        } else { // 6
          float v2 = val;
          if (col >= 768) v2 = 1.0f/(1.0f+__expf(-(val + bias[col-768])));
          ((u16*)Cout)[(size_t)row*N + col] = f2bf(v2);
        }
      }
    }
  }
}

// ---------------- MFMA attention (transposed QK^T: A=K, B=Q) ----------------
// QKVG: [b-panel rows][1024] bf16, Q at +0, K at +256, V at +512, G at +768.
// One block per (h, b); 512 threads = 8 waves; wave owns MT*16 q-rows.
template<int NKEY, int MT, bool ROWMODE>
__global__ __launch_bounds__(512) void attn_mfma(
    const u16* __restrict__ QKVG, const float* __restrict__ bias,
    const float* __restrict__ mask, u16* __restrict__ og)
{
  __shared__ u16 Vt[32][NKEY+8];
  __shared__ u16 Ps[8][16][72];
  __shared__ float lmb[NKEY];
  constexpr int KVI = NKEY/64;
  int h = blockIdx.x, b = blockIdx.y;
  int t = threadIdx.x, lane = t & 63, w = t >> 6;
  int g16 = lane >> 4, l16 = lane & 15;

  size_t base1 = (size_t)b * NKEY * 1024 + h * 32;
  const u16* Qp = QKVG + base1;
  const u16* Kp = QKVG + base1 + 256;
  const u16* Vp = QKVG + base1 + 512;
  const u16* Gp = QKVG + base1 + 768;

  // stage V transposed
  if (NKEY == 256) {
    int key = t & 255, ch0 = (t >> 8) * 16;
    #pragma unroll
    for (int c0 = 0; c0 < 16; c0 += 8) {
      bf16x8 v8 = *(const bf16x8*)(Vp + (size_t)key*1024 + ch0 + c0);
      #pragma unroll
      for (int j = 0; j < 8; ++j) Vt[ch0+c0+j][key] = (u16)v8[j];
    }
  } else {
    int key = t & 127, ch0 = (t >> 7) * 8;
    bf16x8 v8 = *(const bf16x8*)(Vp + (size_t)key*1024 + ch0);
    #pragma unroll
    for (int j = 0; j < 8; ++j) Vt[ch0+j][key] = (u16)v8[j];
  }
  for (int i = t; i < NKEY; i += 512)
    lmb[i] = 1e9f * ((ROWMODE ? mask[b*R + i] : mask[i*R + b]) - 1.0f);
  __syncthreads();

  int qw = w * MT * 16;
  bf16x8 qb[MT];
  #pragma unroll
  for (int m = 0; m < MT; ++m)
    qb[m] = *(const bf16x8*)(Qp + (size_t)(qw + m*16 + l16)*1024 + g16*8);

  f32x4 oacc[MT][2];
  float lsum[MT];
  #pragma unroll
  for (int m = 0; m < MT; ++m) {
    oacc[m][0] = (f32x4){0.f,0.f,0.f,0.f};
    oacc[m][1] = (f32x4){0.f,0.f,0.f,0.f};
    lsum[m] = 0.f;
  }
  const float* bias_b = bias + (size_t)h*NPAIR;

  for (int kv = 0; kv < KVI; ++kv) {
    int k0w = kv*64;
    bf16x8 ka[4];
    #pragma unroll
    for (int kt = 0; kt < 4; ++kt)
      ka[kt] = *(const bf16x8*)(Kp + (size_t)(k0w + kt*16 + l16)*1024 + g16*8);
    bf16x8 vb[2][2];
    #pragma unroll
    for (int n2 = 0; n2 < 2; ++n2)
      #pragma unroll
      for (int tt = 0; tt < 2; ++tt)
        vb[n2][tt] = *(const bf16x8*)(&Vt[n2*16 + l16][k0w + tt*32 + g16*8]);

    #pragma unroll
    for (int m = 0; m < MT; ++m) {
      int q = qw + m*16 + l16;
      #pragma unroll
      for (int kt = 0; kt < 4; ++kt) {
        f32x4 sac = __builtin_amdgcn_mfma_f32_16x16x32_bf16(
            ka[kt], qb[m], (f32x4){0.f,0.f,0.f,0.f}, 0, 0, 0);
        int k0 = k0w + kt*16 + g16*4;
        float4 lm4 = *(const float4*)&lmb[k0];
        float p0, p1, p2, p3;
        if (ROWMODE) {
          float4 b4 = *(const float4*)(bias_b + (size_t)q*R + k0);
          p0 = __expf(sac[0] + lm4.x + b4.x);
          p1 = __expf(sac[1] + lm4.y + b4.y);
          p2 = __expf(sac[2] + lm4.z + b4.z);
          p3 = __expf(sac[3] + lm4.w + b4.w);
        } else {
          p0 = __expf(sac[0] + lm4.x);
          p1 = __expf(sac[1] + lm4.y);
          p2 = __expf(sac[2] + lm4.z);
          p3 = __expf(sac[3] + lm4.w);
        }
        lsum[m] += (p0 + p1) + (p2 + p3);
        ushort4 pk;
        pk.x = f2bf(p0); pk.y = f2bf(p1); pk.z = f2bf(p2); pk.w = f2bf(p3);
        *(ushort4*)&Ps[w][l16][kt*16 + g16*4] = pk;
      }
      #pragma unroll
      for (int tt = 0; tt < 2; ++tt) {
        bf16x8 pa = *(const bf16x8*)&Ps[w][l16][tt*32 + g16*8];
        oacc[m][0] = __builtin_amdgcn_mfma_f32_16x16x32_bf16(pa, vb[0][tt], oacc[m][0], 0, 0, 0);
        oacc[m][1] = __builtin_amdgcn_mfma_f32_16x16x32_bf16(pa, vb[1][tt], oacc[m][1], 0, 0, 0);
      }
    }
  }

  #pragma unroll
  for (int m = 0; m < MT; ++m) {
    float v = lsum[m];
    v += __shfl_xor(v, 16);
    v += __shfl_xor(v, 32);
    lsum[m] = v;
  }

  size_t baseO = (size_t)b * NKEY * 256 + h * 32;
  #pragma unroll
  for (int m = 0; m < MT; ++m) {
    float inv[4];
    #pragma unroll
    for (int r = 0; r < 4; ++r) inv[r] = 1.0f / __shfl(lsum[m], g16*4 + r);
    #pragma unroll
    for (int n2 = 0; n2 < 2; ++n2) {
      int c = n2*16 + l16;
      #pragma unroll
      for (int r = 0; r < 4; ++r) {
        int q = qw + m*16 + g16*4 + r;
        float gate = bf2f(Gp[(size_t)q*1024 + c]);
        og[baseO + (size_t)q*256 + c] = f2bf(oacc[m][n2][r] * inv[r] * gate);
      }
    }
  }
}

extern "C" void kernel_launch(void* const* d_in, const int* in_sizes, int n_in,
                              void* d_out, int out_size, void* d_ws, size_t ws_size,
                              hipStream_t stream)
{
  const float* node         = (const float*)d_in[0];
  const float* pair         = (const float*)d_in[1];
  const float* node_mask    = (const float*)d_in[2];
  const float* row_ln_m_g   = (const float*)d_in[3];
  const float* row_ln_m_b   = (const float*)d_in[4];
  const float* row_ln_z_g   = (const float*)d_in[5];
  const float* row_ln_z_b   = (const float*)d_in[6];
  const float* row_b_w      = (const float*)d_in[7];
  const float* row_wq       = (const float*)d_in[8];
  const float* row_wk       = (const float*)d_in[9];
  const float* row_wv       = (const float*)d_in[10];
  const float* row_wg       = (const float*)d_in[11];
  const float* row_bg       = (const float*)d_in[12];
  const float* row_wo       = (const float*)d_in[13];
  const float* row_out_bias = (const float*)d_in[14];
  const float* col_ln_g     = (const float*)d_in[15];
  const float* col_ln_b     = (const float*)d_in[16];
  const float* col_wq       = (const float*)d_in[17];
  const float* col_wk       = (const float*)d_in[18];
  const float* col_wv       = (const float*)d_in[19];
  const float* col_wg       = (const float*)d_in[20];
  const float* col_bg       = (const float*)d_in[21];
  const float* col_wo       = (const float*)d_in[22];
  const float* col_bo       = (const float*)d_in[23];
  const float* tr_ln_g      = (const float*)d_in[24];
  const float* tr_ln_b      = (const float*)d_in[25];
  const float* tr_w1        = (const float*)d_in[26];
  const float* tr_b1        = (const float*)d_in[27];
  const float* tr_w2        = (const float*)d_in[28];
  const float* tr_b2        = (const float*)d_in[29];

  float* out = (float*)d_out;
  char* ws8 = (char*)d_ws;
  const size_t MB = 1ull << 20;
  u16*   A     = (u16*)(ws8);               // 16 MB  LN out [32768][256] bf16
  u16*   QKVG  = (u16*)(ws8 + 16*MB);       // 64 MB  [32768][1024] bf16 (also T1)
  u16*   Ob    = (u16*)(ws8 + 80*MB);       // 16 MB  gated attn out bf16
  float* Dbias = (float*)(ws8 + 96*MB);     // 2 MB   [H][R][R]
  u16*   Wb    = (u16*)(ws8 + 100*MB);      // bf16 weight arena
  u16*   T1    = QKVG;

  const float qs = 0.17677669529663687f;    // 1/sqrt(32)

  u16* Wrqkvg = Wb + 0;
  u16* Wro    = Wb + 262144;
  u16* Wcqkvg = Wb + 327680;
  u16* Wco    = Wb + 589824;
  u16* W1     = Wb + 655360;
  u16* W2     = Wb + 917504;

  CvtArgs ca;
  const float* srcs[12] = {row_wq,row_wk,row_wv,row_wg,row_wo,
                           col_wq,col_wk,col_wv,col_wg,col_wo,tr_w1,tr_w2};
  int offs[12] = {0,65536,131072,196608,262144,327680,393216,458752,524288,589824,655360,917504};
  int ns[12]   = {65536,65536,65536,65536,65536,65536,65536,65536,65536,65536,262144,262144};
  for (int i = 0; i < 12; ++i) {
    ca.src[i] = srcs[i]; ca.off[i] = offs[i]; ca.n[i] = ns[i];
    ca.scale[i] = (i == 0 || i == 5) ? qs : 1.0f;
  }
  cvt_w_kernel<<<dim3(256,12), 256, 0, stream>>>(ca, Wb);

  dim3 g256(2, 256), g1024(8, 256);

  // --- row attention ---
  ln256_kernel<<<8192, 256, 0, stream>>>(node, A, row_ln_m_g, row_ln_m_b, 0);
  pair_bias_kernel<<<16384, 256, 0, stream>>>(pair, row_ln_z_g, row_ln_z_b, row_b_w, Dbias);
  gemm_mfma<<<g1024, 256, 0, stream>>>(A, Wrqkvg, QKVG, NROWS, 1024, 256, 6, row_bg, nullptr);
  attn_mfma<256,2,true><<<dim3(8,128), 512, 0, stream>>>(QKVG, Dbias, node_mask, Ob);
  gemm_mfma<<<g256, 256, 0, stream>>>(Ob, Wro, out, NROWS, 256, 256, 4, row_out_bias, node);

  // --- column attention (in [r,s,d] layout) ---
  ln256_kernel<<<8192, 256, 0, stream>>>(out, A, col_ln_g, col_ln_b, 1);
  gemm_mfma<<<g1024, 256, 0, stream>>>(A, Wcqkvg, QKVG, NROWS, 1024, 256, 6, col_bg, nullptr);
  attn_mfma<128,1,false><<<dim3(8,256), 512, 0, stream>>>(QKVG, Dbias, node_mask, Ob);
  gemm_mfma<<<g256, 256, 0, stream>>>(Ob, Wco, out, NROWS, 256, 256, 5, col_bo, out);

  // --- transition ---
  ln256_kernel<<<8192, 256, 0, stream>>>(out, A, tr_ln_g, tr_ln_b, 0);
  gemm_mfma<<<g1024, 256, 0, stream>>>(A, W1, T1, NROWS, 1024, 256, 3, tr_b1, nullptr);
  gemm_mfma<<<g256, 256, 0, stream>>>(T1, W2, out, NROWS, 256, 1024, 4, tr_b2, out);
}

// Round 6
// 435.030 us; speedup vs baseline: 3.8068x; 1.1560x over previous
//
#include <hip/hip_runtime.h>
#include <math.h>

#define S 128
#define R 256
#define DMODEL 256
#define H 8
#define CDIM 32
#define HC 256
#define DFF 1024
#define NROWS (S*R)     // 32768
#define NPAIR (R*R)     // 65536
#define LN_EPS 1e-5f

typedef unsigned short u16;
typedef __attribute__((ext_vector_type(8))) short bf16x8;
typedef __attribute__((ext_vector_type(4))) float f32x4;

__device__ __forceinline__ u16 f2bf(float x) {
  unsigned u = __float_as_uint(x);
  u = (u + 0x7fffu + ((u >> 16) & 1u)) >> 16;
  return (u16)u;
}
__device__ __forceinline__ float bf2f(u16 x) {
  return __uint_as_float(((unsigned)x) << 16);
}

__device__ __forceinline__ void gload_lds16(const u16* g, u16* l) {
  __builtin_amdgcn_global_load_lds(
      (const __attribute__((address_space(1))) unsigned int*)g,
      (__attribute__((address_space(3))) unsigned int*)l, 16, 0, 0);
}

// ---------------- weight f32 -> bf16 conversion (12 segments) ----------------
struct CvtArgs {
  const float* src[12];
  int off[12];
  int n[12];
  float scale[12];
};

__global__ __launch_bounds__(256) void cvt_w_kernel(CvtArgs a, u16* __restrict__ dst) {
  int sg = blockIdx.y;
  int i = (blockIdx.x * 256 + threadIdx.x) * 4;
  if (i >= a.n[sg]) return;
  float4 v = *(const float4*)(a.src[sg] + i);
  float sc = a.scale[sg];
  ushort4 o;
  o.x = f2bf(v.x * sc); o.y = f2bf(v.y * sc);
  o.z = f2bf(v.z * sc); o.w = f2bf(v.w * sc);
  *(ushort4*)(dst + a.off[sg] + i) = o;
}

// ---------------- LayerNorm over 256, one row per wave, bf16 out ----------------
__global__ __launch_bounds__(256) void ln256_kernel(
    const float* __restrict__ in, u16* __restrict__ out,
    const float* __restrict__ gamma, const float* __restrict__ beta,
    int tmode)
{
  int wid = threadIdx.x >> 6, lane = threadIdx.x & 63;
  int m = blockIdx.x * 4 + wid;
  int inrow = m;
  if (tmode) { int r = m >> 7, s = m & 127; inrow = s * R + r; }
  float4 x = *(const float4*)(in + (size_t)inrow * DMODEL + lane * 4);
  float sum = x.x + x.y + x.z + x.w;
  float sq  = x.x*x.x + x.y*x.y + x.z*x.z + x.w*x.w;
  #pragma unroll
  for (int off = 32; off; off >>= 1) {
    sum += __shfl_xor(sum, off);
    sq  += __shfl_xor(sq, off);
  }
  float mean = sum * (1.0f/256.0f);
  float var  = sq  * (1.0f/256.0f) - mean*mean;
  float rstd = rsqrtf(var + LN_EPS);
  float4 g = *(const float4*)(gamma + lane*4);
  float4 b = *(const float4*)(beta  + lane*4);
  ushort4 o;
  o.x = f2bf((x.x-mean)*rstd*g.x + b.x);
  o.y = f2bf((x.y-mean)*rstd*g.y + b.y);
  o.z = f2bf((x.z-mean)*rstd*g.z + b.z);
  o.w = f2bf((x.w-mean)*rstd*g.w + b.w);
  *(ushort4*)(out + (size_t)m * DMODEL + lane*4) = o;
}

// ------------- pair LN (over 128) + bias projection -> bias[h][q][k] (f32) -------------
__global__ __launch_bounds__(256) void pair_bias_kernel(
    const float* __restrict__ pair, const float* __restrict__ gamma,
    const float* __restrict__ beta, const float* __restrict__ bw,
    float* __restrict__ bias)
{
  int wid = threadIdx.x >> 6, lane = threadIdx.x & 63;
  int p = blockIdx.x * 4 + wid;
  float2 x = *(const float2*)(pair + (size_t)p * 128 + lane*2);
  float sum = x.x + x.y, sq = x.x*x.x + x.y*x.y;
  #pragma unroll
  for (int off = 32; off; off >>= 1) {
    sum += __shfl_xor(sum, off);
    sq  += __shfl_xor(sq, off);
  }
  float mean = sum * (1.0f/128.0f);
  float rstd = rsqrtf(sq*(1.0f/128.0f) - mean*mean + LN_EPS);
  float z0 = (x.x-mean)*rstd*gamma[lane*2]   + beta[lane*2];
  float z1 = (x.y-mean)*rstd*gamma[lane*2+1] + beta[lane*2+1];
  float a0 = z0*bw[0*128+lane*2] + z1*bw[0*128+lane*2+1];
  float a1 = z0*bw[1*128+lane*2] + z1*bw[1*128+lane*2+1];
  float a2 = z0*bw[2*128+lane*2] + z1*bw[2*128+lane*2+1];
  float a3 = z0*bw[3*128+lane*2] + z1*bw[3*128+lane*2+1];
  float a4 = z0*bw[4*128+lane*2] + z1*bw[4*128+lane*2+1];
  float a5 = z0*bw[5*128+lane*2] + z1*bw[5*128+lane*2+1];
  float a6 = z0*bw[6*128+lane*2] + z1*bw[6*128+lane*2+1];
  float a7 = z0*bw[7*128+lane*2] + z1*bw[7*128+lane*2+1];
  #pragma unroll
  for (int off = 32; off; off >>= 1) {
    a0 += __shfl_xor(a0, off); a1 += __shfl_xor(a1, off);
    a2 += __shfl_xor(a2, off); a3 += __shfl_xor(a3, off);
    a4 += __shfl_xor(a4, off); a5 += __shfl_xor(a5, off);
    a6 += __shfl_xor(a6, off); a7 += __shfl_xor(a7, off);
  }
  float v = a0;
  v = (lane==1)?a1:v; v = (lane==2)?a2:v; v = (lane==3)?a3:v;
  v = (lane==4)?a4:v; v = (lane==5)?a5:v; v = (lane==6)?a6:v; v = (lane==7)?a7:v;
  if (lane < 8) bias[(size_t)lane*NPAIR + p] = v;
}

// ---------------- bf16 MFMA NT GEMM: C[M,N] = A[M,K] * W[N,K]^T ----------------
// 256x128 tile, 512 threads (8 waves, 4Mx2N), BK=32, double-buffered counted-vmcnt,
// chunk XOR-swizzle, bijective XCD swizzle (requires nwg % 8 == 0).
// modes: 1: bf16 out  2: bf16 sigmoid(x+bias[n])  3: bf16 relu(x+bias[n])
//        4: f32 out = x + res[m,n] + bias[n]
//        5: f32 transposed: idx=((m&127)*R + (m>>7))*N + n
//        6: bf16 out; cols >= 768 get sigmoid(x + bias[col-768])   (fused QKVG)
__global__ __launch_bounds__(512, 4) void gemm_mfma(
    const u16* __restrict__ A, const u16* __restrict__ W,
    void* __restrict__ Cout, int N, int K,
    int mode, const float* __restrict__ bias, const float* __restrict__ res)
{
  __shared__ u16 As[2][256*32];
  __shared__ u16 Bs[2][128*32];
  int t = threadIdx.x;
  int lane = t & 63;
  int w = t >> 6;
  int wm = w >> 1, wn = w & 1;
  int g16 = lane >> 4, l16 = lane & 15;

  // bijective XCD swizzle: consecutive logical blocks (same A-panel) -> same XCD
  int nwg = gridDim.x * gridDim.y;
  int p = blockIdx.y * gridDim.x + blockIdx.x;
  int cpx = nwg >> 3;
  int lg = (p & 7) * cpx + (p >> 3);
  int bn = (lg % gridDim.x) * 128;
  int bm = (lg / gridDim.x) * 256;

  // staging: thread t covers A rows sr, sr+128 and B row sr; chunk scq,
  // global source chunk XOR-swizzled (inverse == forward, involution)
  int sr = t >> 2;
  int scq = t & 3;
  int swz = scq ^ ((sr >> 1) & 3);
  const u16* Ag0 = A + (size_t)(bm + sr) * K + swz * 8;
  const u16* Ag1 = A + (size_t)(bm + 128 + sr) * K + swz * 8;
  const u16* Wg  = W + (size_t)(bn + sr) * K + swz * 8;
  int ldst = t * 8;   // linear dest (elems) = sr*32 + scq*8

  // fragment read slot (same involution, depends only on l16)
  int slot = (g16 ^ ((l16 >> 1) & 3)) * 8;

  f32x4 acc[4][4];
  #pragma unroll
  for (int m=0;m<4;++m)
    #pragma unroll
    for (int n=0;n<4;++n) acc[m][n] = (f32x4){0.f,0.f,0.f,0.f};

  const int nk = K >> 5;

#define STAGE(pb, k0) do { \
    gload_lds16(Ag0 + (k0), &As[pb][ldst]); \
    gload_lds16(Ag1 + (k0), &As[pb][128*32 + ldst]); \
    gload_lds16(Wg  + (k0), &Bs[pb][ldst]); \
  } while(0)

  STAGE(0, 0);
  int buf = 0;
  for (int k = 0; k < nk; ++k) {
    if (k + 1 < nk) {
      STAGE(buf^1, (k+1)*32);
      asm volatile("s_waitcnt vmcnt(3)" ::: "memory");
    } else {
      asm volatile("s_waitcnt vmcnt(0)" ::: "memory");
    }
    __builtin_amdgcn_s_barrier();
    bf16x8 a[4], b[4];
    #pragma unroll
    for (int m=0;m<4;++m)
      a[m] = *(const bf16x8*)&As[buf][(wm*64 + m*16 + l16)*32 + slot];
    #pragma unroll
    for (int n=0;n<4;++n)
      b[n] = *(const bf16x8*)&Bs[buf][(wn*64 + n*16 + l16)*32 + slot];
    #pragma unroll
    for (int m=0;m<4;++m)
      #pragma unroll
      for (int n=0;n<4;++n)
        acc[m][n] = __builtin_amdgcn_mfma_f32_16x16x32_bf16(a[m], b[n], acc[m][n], 0, 0, 0);
    __builtin_amdgcn_s_barrier();
    buf ^= 1;
  }
#undef STAGE

  int row0 = bm + wm*64 + (g16<<2);
  #pragma unroll
  for (int m=0;m<4;++m) {
    #pragma unroll
    for (int n=0;n<4;++n) {
      int col = bn + wn*64 + n*16 + l16;
      float bb = 0.f;
      if (mode == 2 || mode == 3 || mode == 4) bb = bias[col];
      #pragma unroll
      for (int r=0;r<4;++r) {
        int row = row0 + m*16 + r;
        float val = acc[m][n][r];
        if (mode == 1) {
          ((u16*)Cout)[(size_t)row*N + col] = f2bf(val);
        } else if (mode == 2) {
          ((u16*)Cout)[(size_t)row*N + col] = f2bf(1.0f/(1.0f+__expf(-(val+bb))));
        } else if (mode == 3) {
          ((u16*)Cout)[(size_t)row*N + col] = f2bf(fmaxf(val+bb, 0.0f));
        } else if (mode == 4) {
          size_t i2 = (size_t)row*N + col;
          ((float*)Cout)[i2] = val + res[i2] + bb;
        } else if (mode == 5) {
          int rr = row >> 7, ss = row & 127;
          size_t i2 = ((size_t)ss*R + rr)*N + col;
          ((float*)Cout)[i2] = val + res[i2] + bias[col];
        } else { // 6
          float v2 = val;
          if (col >= 768) v2 = 1.0f/(1.0f+__expf(-(val + bias[col-768])));
          ((u16*)Cout)[(size_t)row*N + col] = f2bf(v2);
        }
      }
    }
  }
}

// ---------------- MFMA attention (transposed QK^T: A=K, B=Q) ----------------
// QKVG: [b-panel rows][1024] bf16, Q at +0, K at +256, V at +512, G at +768.
// One block per (h, b); 512 threads = 8 waves; wave owns MT*16 q-rows.
template<int NKEY, int MT, bool ROWMODE>
__global__ __launch_bounds__(512) void attn_mfma(
    const u16* __restrict__ QKVG, const float* __restrict__ bias,
    const float* __restrict__ mask, u16* __restrict__ og)
{
  __shared__ u16 Vt[32][NKEY+8];
  __shared__ u16 Ps[8][16][72];
  __shared__ float lmb[NKEY];
  constexpr int KVI = NKEY/64;
  int h = blockIdx.x, b = blockIdx.y;
  int t = threadIdx.x, lane = t & 63, w = t >> 6;
  int g16 = lane >> 4, l16 = lane & 15;

  size_t base1 = (size_t)b * NKEY * 1024 + h * 32;
  const u16* Qp = QKVG + base1;
  const u16* Kp = QKVG + base1 + 256;
  const u16* Vp = QKVG + base1 + 512;
  const u16* Gp = QKVG + base1 + 768;

  // stage V transposed
  if (NKEY == 256) {
    int key = t & 255, ch0 = (t >> 8) * 16;
    #pragma unroll
    for (int c0 = 0; c0 < 16; c0 += 8) {
      bf16x8 v8 = *(const bf16x8*)(Vp + (size_t)key*1024 + ch0 + c0);
      #pragma unroll
      for (int j = 0; j < 8; ++j) Vt[ch0+c0+j][key] = (u16)v8[j];
    }
  } else {
    int key = t & 127, ch0 = (t >> 7) * 8;
    bf16x8 v8 = *(const bf16x8*)(Vp + (size_t)key*1024 + ch0);
    #pragma unroll
    for (int j = 0; j < 8; ++j) Vt[ch0+j][key] = (u16)v8[j];
  }
  for (int i = t; i < NKEY; i += 512)
    lmb[i] = 1e9f * ((ROWMODE ? mask[b*R + i] : mask[i*R + b]) - 1.0f);
  __syncthreads();

  int qw = w * MT * 16;
  bf16x8 qb[MT];
  #pragma unroll
  for (int m = 0; m < MT; ++m)
    qb[m] = *(const bf16x8*)(Qp + (size_t)(qw + m*16 + l16)*1024 + g16*8);

  f32x4 oacc[MT][2];
  float lsum[MT];
  #pragma unroll
  for (int m = 0; m < MT; ++m) {
    oacc[m][0] = (f32x4){0.f,0.f,0.f,0.f};
    oacc[m][1] = (f32x4){0.f,0.f,0.f,0.f};
    lsum[m] = 0.f;
  }
  const float* bias_b = bias + (size_t)h*NPAIR;

  for (int kv = 0; kv < KVI; ++kv) {
    int k0w = kv*64;
    bf16x8 ka[4];
    #pragma unroll
    for (int kt = 0; kt < 4; ++kt)
      ka[kt] = *(const bf16x8*)(Kp + (size_t)(k0w + kt*16 + l16)*1024 + g16*8);
    bf16x8 vb[2][2];
    #pragma unroll
    for (int n2 = 0; n2 < 2; ++n2)
      #pragma unroll
      for (int tt = 0; tt < 2; ++tt)
        vb[n2][tt] = *(const bf16x8*)(&Vt[n2*16 + l16][k0w + tt*32 + g16*8]);

    #pragma unroll
    for (int m = 0; m < MT; ++m) {
      int q = qw + m*16 + l16;
      #pragma unroll
      for (int kt = 0; kt < 4; ++kt) {
        f32x4 sac = __builtin_amdgcn_mfma_f32_16x16x32_bf16(
            ka[kt], qb[m], (f32x4){0.f,0.f,0.f,0.f}, 0, 0, 0);
        int k0 = k0w + kt*16 + g16*4;
        float4 lm4 = *(const float4*)&lmb[k0];
        float p0, p1, p2, p3;
        if (ROWMODE) {
          float4 b4 = *(const float4*)(bias_b + (size_t)q*R + k0);
          p0 = __expf(sac[0] + lm4.x + b4.x);
          p1 = __expf(sac[1] + lm4.y + b4.y);
          p2 = __expf(sac[2] + lm4.z + b4.z);
          p3 = __expf(sac[3] + lm4.w + b4.w);
        } else {
          p0 = __expf(sac[0] + lm4.x);
          p1 = __expf(sac[1] + lm4.y);
          p2 = __expf(sac[2] + lm4.z);
          p3 = __expf(sac[3] + lm4.w);
        }
        lsum[m] += (p0 + p1) + (p2 + p3);
        ushort4 pk;
        pk.x = f2bf(p0); pk.y = f2bf(p1); pk.z = f2bf(p2); pk.w = f2bf(p3);
        *(ushort4*)&Ps[w][l16][kt*16 + g16*4] = pk;
      }
      #pragma unroll
      for (int tt = 0; tt < 2; ++tt) {
        bf16x8 pa = *(const bf16x8*)&Ps[w][l16][tt*32 + g16*8];
        oacc[m][0] = __builtin_amdgcn_mfma_f32_16x16x32_bf16(pa, vb[0][tt], oacc[m][0], 0, 0, 0);
        oacc[m][1] = __builtin_amdgcn_mfma_f32_16x16x32_bf16(pa, vb[1][tt], oacc[m][1], 0, 0, 0);
      }
    }
  }

  #pragma unroll
  for (int m = 0; m < MT; ++m) {
    float v = lsum[m];
    v += __shfl_xor(v, 16);
    v += __shfl_xor(v, 32);
    lsum[m] = v;
  }

  size_t baseO = (size_t)b * NKEY * 256 + h * 32;
  #pragma unroll
  for (int m = 0; m < MT; ++m) {
    float inv[4];
    #pragma unroll
    for (int r = 0; r < 4; ++r) inv[r] = 1.0f / __shfl(lsum[m], g16*4 + r);
    #pragma unroll
    for (int n2 = 0; n2 < 2; ++n2) {
      int c = n2*16 + l16;
      #pragma unroll
      for (int r = 0; r < 4; ++r) {
        int q = qw + m*16 + g16*4 + r;
        float gate = bf2f(Gp[(size_t)q*1024 + c]);
        og[baseO + (size_t)q*256 + c] = f2bf(oacc[m][n2][r] * inv[r] * gate);
      }
    }
  }
}

extern "C" void kernel_launch(void* const* d_in, const int* in_sizes, int n_in,
                              void* d_out, int out_size, void* d_ws, size_t ws_size,
                              hipStream_t stream)
{
  const float* node         = (const float*)d_in[0];
  const float* pair         = (const float*)d_in[1];
  const float* node_mask    = (const float*)d_in[2];
  const float* row_ln_m_g   = (const float*)d_in[3];
  const float* row_ln_m_b   = (const float*)d_in[4];
  const float* row_ln_z_g   = (const float*)d_in[5];
  const float* row_ln_z_b   = (const float*)d_in[6];
  const float* row_b_w      = (const float*)d_in[7];
  const float* row_wq       = (const float*)d_in[8];
  const float* row_wk       = (const float*)d_in[9];
  const float* row_wv       = (const float*)d_in[10];
  const float* row_wg       = (const float*)d_in[11];
  const float* row_bg       = (const float*)d_in[12];
  const float* row_wo       = (const float*)d_in[13];
  const float* row_out_bias = (const float*)d_in[14];
  const float* col_ln_g     = (const float*)d_in[15];
  const float* col_ln_b     = (const float*)d_in[16];
  const float* col_wq       = (const float*)d_in[17];
  const float* col_wk       = (const float*)d_in[18];
  const float* col_wv       = (const float*)d_in[19];
  const float* col_wg       = (const float*)d_in[20];
  const float* col_bg       = (const float*)d_in[21];
  const float* col_wo       = (const float*)d_in[22];
  const float* col_bo       = (const float*)d_in[23];
  const float* tr_ln_g      = (const float*)d_in[24];
  const float* tr_ln_b      = (const float*)d_in[25];
  const float* tr_w1        = (const float*)d_in[26];
  const float* tr_b1        = (const float*)d_in[27];
  const float* tr_w2        = (const float*)d_in[28];
  const float* tr_b2        = (const float*)d_in[29];

  float* out = (float*)d_out;
  char* ws8 = (char*)d_ws;
  const size_t MB = 1ull << 20;
  u16*   A     = (u16*)(ws8);               // 16 MB  LN out [32768][256] bf16
  u16*   QKVG  = (u16*)(ws8 + 16*MB);       // 64 MB  [32768][1024] bf16 (also T1)
  u16*   Ob    = (u16*)(ws8 + 80*MB);       // 16 MB  gated attn out bf16
  float* Dbias = (float*)(ws8 + 96*MB);     // 2 MB   [H][R][R]
  u16*   Wb    = (u16*)(ws8 + 100*MB);      // bf16 weight arena
  u16*   T1    = QKVG;

  const float qs = 0.17677669529663687f;    // 1/sqrt(32)

  u16* Wrqkvg = Wb + 0;
  u16* Wro    = Wb + 262144;
  u16* Wcqkvg = Wb + 327680;
  u16* Wco    = Wb + 589824;
  u16* W1     = Wb + 655360;
  u16* W2     = Wb + 917504;

  CvtArgs ca;
  const float* srcs[12] = {row_wq,row_wk,row_wv,row_wg,row_wo,
                           col_wq,col_wk,col_wv,col_wg,col_wo,tr_w1,tr_w2};
  int offs[12] = {0,65536,131072,196608,262144,327680,393216,458752,524288,589824,655360,917504};
  int ns[12]   = {65536,65536,65536,65536,65536,65536,65536,65536,65536,65536,262144,262144};
  for (int i = 0; i < 12; ++i) {
    ca.src[i] = srcs[i]; ca.off[i] = offs[i]; ca.n[i] = ns[i];
    ca.scale[i] = (i == 0 || i == 5) ? qs : 1.0f;
  }
  cvt_w_kernel<<<dim3(256,12), 256, 0, stream>>>(ca, Wb);

  // grids: BM=256, BN=128 -> (N/128, 128)
  dim3 g256(2, 128), g1024(8, 128);

  // --- row attention ---
  ln256_kernel<<<8192, 256, 0, stream>>>(node, A, row_ln_m_g, row_ln_m_b, 0);
  pair_bias_kernel<<<16384, 256, 0, stream>>>(pair, row_ln_z_g, row_ln_z_b, row_b_w, Dbias);
  gemm_mfma<<<g1024, 512, 0, stream>>>(A, Wrqkvg, QKVG, 1024, 256, 6, row_bg, nullptr);
  attn_mfma<256,2,true><<<dim3(8,128), 512, 0, stream>>>(QKVG, Dbias, node_mask, Ob);
  gemm_mfma<<<g256, 512, 0, stream>>>(Ob, Wro, out, 256, 256, 4, row_out_bias, node);

  // --- column attention (in [r,s,d] layout) ---
  ln256_kernel<<<8192, 256, 0, stream>>>(out, A, col_ln_g, col_ln_b, 1);
  gemm_mfma<<<g1024, 512, 0, stream>>>(A, Wcqkvg, QKVG, 1024, 256, 6, col_bg, nullptr);
  attn_mfma<128,1,false><<<dim3(8,256), 512, 0, stream>>>(QKVG, Dbias, node_mask, Ob);
  gemm_mfma<<<g256, 512, 0, stream>>>(Ob, Wco, out, 256, 256, 5, col_bo, out);

  // --- transition ---
  ln256_kernel<<<8192, 256, 0, stream>>>(out, A, tr_ln_g, tr_ln_b, 0);
  gemm_mfma<<<g1024, 512, 0, stream>>>(A, W1, T1, 1024, 256, 3, tr_b1, nullptr);
  gemm_mfma<<<g256, 512, 0, stream>>>(T1, W2, out, 256, 1024, 4, tr_b2, out);
}

// Round 7
// 401.597 us; speedup vs baseline: 4.1237x; 1.0833x over previous
//
#include <hip/hip_runtime.h>
#include <math.h>

#define S 128
#define R 256
#define DMODEL 256
#define H 8
#define CDIM 32
#define HC 256
#define DFF 1024
#define NROWS (S*R)     // 32768
#define NPAIR (R*R)     // 65536
#define LN_EPS 1e-5f

typedef unsigned short u16;
typedef __attribute__((ext_vector_type(8))) short bf16x8;
typedef __attribute__((ext_vector_type(4))) float f32x4;

__device__ __forceinline__ u16 f2bf(float x) {
  unsigned u = __float_as_uint(x);
  u = (u + 0x7fffu + ((u >> 16) & 1u)) >> 16;
  return (u16)u;
}
__device__ __forceinline__ float bf2f(u16 x) {
  return __uint_as_float(((unsigned)x) << 16);
}

__device__ __forceinline__ void gload_lds16(const u16* g, u16* l) {
  __builtin_amdgcn_global_load_lds(
      (const __attribute__((address_space(1))) unsigned int*)g,
      (__attribute__((address_space(3))) unsigned int*)l, 16, 0, 0);
}

// ---------------- weight f32 -> bf16 conversion (12 segments) ----------------
struct CvtArgs {
  const float* src[12];
  int off[12];
  int n[12];
  float scale[12];
};

__global__ __launch_bounds__(256) void cvt_w_kernel(CvtArgs a, u16* __restrict__ dst) {
  int sg = blockIdx.y;
  int i = (blockIdx.x * 256 + threadIdx.x) * 4;
  if (i >= a.n[sg]) return;
  float4 v = *(const float4*)(a.src[sg] + i);
  float sc = a.scale[sg];
  ushort4 o;
  o.x = f2bf(v.x * sc); o.y = f2bf(v.y * sc);
  o.z = f2bf(v.z * sc); o.w = f2bf(v.w * sc);
  *(ushort4*)(dst + a.off[sg] + i) = o;
}

// ---------------- LayerNorm over 256, one row per wave, bf16 out ----------------
__global__ __launch_bounds__(256) void ln256_kernel(
    const float* __restrict__ in, u16* __restrict__ out,
    const float* __restrict__ gamma, const float* __restrict__ beta,
    int tmode)
{
  int wid = threadIdx.x >> 6, lane = threadIdx.x & 63;
  int m = blockIdx.x * 4 + wid;
  int inrow = m;
  if (tmode) { int r = m >> 7, s = m & 127; inrow = s * R + r; }
  float4 x = *(const float4*)(in + (size_t)inrow * DMODEL + lane * 4);
  float sum = x.x + x.y + x.z + x.w;
  float sq  = x.x*x.x + x.y*x.y + x.z*x.z + x.w*x.w;
  #pragma unroll
  for (int off = 32; off; off >>= 1) {
    sum += __shfl_xor(sum, off);
    sq  += __shfl_xor(sq, off);
  }
  float mean = sum * (1.0f/256.0f);
  float var  = sq  * (1.0f/256.0f) - mean*mean;
  float rstd = rsqrtf(var + LN_EPS);
  float4 g = *(const float4*)(gamma + lane*4);
  float4 b = *(const float4*)(beta  + lane*4);
  ushort4 o;
  o.x = f2bf((x.x-mean)*rstd*g.x + b.x);
  o.y = f2bf((x.y-mean)*rstd*g.y + b.y);
  o.z = f2bf((x.z-mean)*rstd*g.z + b.z);
  o.w = f2bf((x.w-mean)*rstd*g.w + b.w);
  *(ushort4*)(out + (size_t)m * DMODEL + lane*4) = o;
}

// ------------- pair LN (over 128) + bias projection -> bias[h][q][k] (f32) -------------
__global__ __launch_bounds__(256) void pair_bias_kernel(
    const float* __restrict__ pair, const float* __restrict__ gamma,
    const float* __restrict__ beta, const float* __restrict__ bw,
    float* __restrict__ bias)
{
  int wid = threadIdx.x >> 6, lane = threadIdx.x & 63;
  int p = blockIdx.x * 4 + wid;
  float2 x = *(const float2*)(pair + (size_t)p * 128 + lane*2);
  float sum = x.x + x.y, sq = x.x*x.x + x.y*x.y;
  #pragma unroll
  for (int off = 32; off; off >>= 1) {
    sum += __shfl_xor(sum, off);
    sq  += __shfl_xor(sq, off);
  }
  float mean = sum * (1.0f/128.0f);
  float rstd = rsqrtf(sq*(1.0f/128.0f) - mean*mean + LN_EPS);
  float z0 = (x.x-mean)*rstd*gamma[lane*2]   + beta[lane*2];
  float z1 = (x.y-mean)*rstd*gamma[lane*2+1] + beta[lane*2+1];
  float a0 = z0*bw[0*128+lane*2] + z1*bw[0*128+lane*2+1];
  float a1 = z0*bw[1*128+lane*2] + z1*bw[1*128+lane*2+1];
  float a2 = z0*bw[2*128+lane*2] + z1*bw[2*128+lane*2+1];
  float a3 = z0*bw[3*128+lane*2] + z1*bw[3*128+lane*2+1];
  float a4 = z0*bw[4*128+lane*2] + z1*bw[4*128+lane*2+1];
  float a5 = z0*bw[5*128+lane*2] + z1*bw[5*128+lane*2+1];
  float a6 = z0*bw[6*128+lane*2] + z1*bw[6*128+lane*2+1];
  float a7 = z0*bw[7*128+lane*2] + z1*bw[7*128+lane*2+1];
  #pragma unroll
  for (int off = 32; off; off >>= 1) {
    a0 += __shfl_xor(a0, off); a1 += __shfl_xor(a1, off);
    a2 += __shfl_xor(a2, off); a3 += __shfl_xor(a3, off);
    a4 += __shfl_xor(a4, off); a5 += __shfl_xor(a5, off);
    a6 += __shfl_xor(a6, off); a7 += __shfl_xor(a7, off);
  }
  float v = a0;
  v = (lane==1)?a1:v; v = (lane==2)?a2:v; v = (lane==3)?a3:v;
  v = (lane==4)?a4:v; v = (lane==5)?a5:v; v = (lane==6)?a6:v; v = (lane==7)?a7:v;
  if (lane < 8) bias[(size_t)lane*NPAIR + p] = v;
}

// ---------------- bf16 MFMA NT GEMM, 256x256 tile, BK=64, counted-vmcnt ----------------
// C[M,N] = A[M,K] * W[N,K]^T.  512 threads = 8 waves (2M x 4N), per-wave 128x64.
// LDS: 2 dbuf x 4 half-tiles [128][64] = 128 KB. Swapped MFMA operands (W as A-op)
// so each lane holds 4 consecutive N-cols -> vector epilogue.
// modes: 1: bf16  2: bf16 sigmoid(x+bias)  3: bf16 relu(x+bias)
//        4: f32 x+res+bias   5: f32 transposed idx   6: bf16, cols>=768 sigmoid(+bias)
__global__ __launch_bounds__(512, 2) void gemm_8ph(
    const u16* __restrict__ A, const u16* __restrict__ W,
    void* __restrict__ Cout, int N, int K,
    int mode, const float* __restrict__ bias, const float* __restrict__ res)
{
  __shared__ u16 lds[2][4][128*64];
  int t = threadIdx.x, lane = t & 63, wv = t >> 6;
  int g16 = (lane >> 4) & 3, l16 = lane & 15;
  int wm = wv >> 2, wn = wv & 3;
  int lrow = lane >> 3, lchunk = lane & 7;

  // bijective XCD swizzle (nwg % 8 == 0 for all our grids)
  int gx = gridDim.x;
  int nwg = gx * gridDim.y;
  int p = blockIdx.y * gx + blockIdx.x;
  int cpx = nwg >> 3;
  int lg = (p & 7) * cpx + (p >> 3);
  int bn = (lg % gx) * 256;
  int bm = (lg / gx) * 256;

  int srcc = (lchunk ^ lrow) << 3;          // pre-swizzled global k-chunk
  int ch0  = (g16 ^ (l16 & 7)) << 3;        // swizzled LDS read chunk (k32=0)
  int rdoff = l16 * 64 + ch0;               // k32=1 -> rdoff ^ 32
  const int wnh = 2 + (wn >> 1);
  const int wnr = (wn & 1) * 4096;

  f32x4 acc[8][4];
  #pragma unroll
  for (int i = 0; i < 8; ++i)
    #pragma unroll
    for (int j = 0; j < 4; ++j) acc[i][j] = (f32x4){0.f,0.f,0.f,0.f};

  const int nkt = K >> 6;

#define STG_HALF(buf_, h_, base_, row0_, kc_) do { \
    gload_lds16(base_ + (size_t)((row0_) + (wv*2+0)*8 + lrow) * K + (kc_) + srcc, \
                &lds[buf_][h_][(wv*2+0)*512 + lane*8]); \
    gload_lds16(base_ + (size_t)((row0_) + (wv*2+1)*8 + lrow) * K + (kc_) + srcc, \
                &lds[buf_][h_][(wv*2+1)*512 + lane*8]); \
  } while(0)
#define STG_A(buf_, kc_) do { STG_HALF(buf_,0,A,bm,kc_); STG_HALF(buf_,1,A,bm+128,kc_); } while(0)
#define STG_B(buf_, kc_) do { STG_HALF(buf_,2,W,bn,kc_); STG_HALF(buf_,3,W,bn+128,kc_); } while(0)

  int buf = 0;
  STG_A(0, 0); STG_B(0, 0);                 // 8 loads in flight
  for (int kt = 0; kt < nkt; ++kt) {
    int kc = kt << 6;
    if (kt + 1 < nkt) {
      STG_A(buf^1, kc + 64);                // +4 (issue-early)
      asm volatile("s_waitcnt vmcnt(4)" ::: "memory");   // this kt's 8 done
    } else {
      asm volatile("s_waitcnt vmcnt(0)" ::: "memory");
    }
    __builtin_amdgcn_s_barrier();
    asm volatile("" ::: "memory");
    if (kt + 1 < nkt) STG_B(buf^1, kc + 64);

    const u16* Abase = &lds[buf][wm][0];
    const u16* Wbase = &lds[buf][wnh][wnr];
    bf16x8 wf[4][2];
    #pragma unroll
    for (int nf = 0; nf < 4; ++nf) {
      wf[nf][0] = *(const bf16x8*)(Wbase + nf*1024 + rdoff);
      wf[nf][1] = *(const bf16x8*)(Wbase + nf*1024 + (rdoff ^ 32));
    }
    __builtin_amdgcn_s_setprio(1);
    #pragma unroll
    for (int mf = 0; mf < 8; ++mf) {
      bf16x8 a0 = *(const bf16x8*)(Abase + mf*1024 + rdoff);
      bf16x8 a1 = *(const bf16x8*)(Abase + mf*1024 + (rdoff ^ 32));
      #pragma unroll
      for (int nf = 0; nf < 4; ++nf) {
        acc[mf][nf] = __builtin_amdgcn_mfma_f32_16x16x32_bf16(wf[nf][0], a0, acc[mf][nf], 0, 0, 0);
        acc[mf][nf] = __builtin_amdgcn_mfma_f32_16x16x32_bf16(wf[nf][1], a1, acc[mf][nf], 0, 0, 0);
      }
    }
    __builtin_amdgcn_s_setprio(0);
    asm volatile("" ::: "memory");
    __builtin_amdgcn_s_barrier();
    buf ^= 1;
  }
#undef STG_A
#undef STG_B
#undef STG_HALF

  // epilogue: lane holds rows (l16-based), 4 consecutive cols (g16*4 + r)
  int rowb = bm + wm*128 + l16;
  int colb = bn + wn*64 + (g16 << 2);
  #pragma unroll
  for (int mf = 0; mf < 8; ++mf) {
    int row = rowb + mf*16;
    #pragma unroll
    for (int nf = 0; nf < 4; ++nf) {
      int col0 = colb + nf*16;
      f32x4 v = acc[mf][nf];
      if (mode == 6) {
        if (col0 >= 768) {
          float4 b4 = *(const float4*)(bias + col0 - 768);
          v[0] = 1.0f/(1.0f+__expf(-(v[0]+b4.x)));
          v[1] = 1.0f/(1.0f+__expf(-(v[1]+b4.y)));
          v[2] = 1.0f/(1.0f+__expf(-(v[2]+b4.z)));
          v[3] = 1.0f/(1.0f+__expf(-(v[3]+b4.w)));
        }
        ushort4 o; o.x=f2bf(v[0]); o.y=f2bf(v[1]); o.z=f2bf(v[2]); o.w=f2bf(v[3]);
        *(ushort4*)((u16*)Cout + (size_t)row*N + col0) = o;
      } else if (mode == 3) {
        float4 b4 = *(const float4*)(bias + col0);
        ushort4 o;
        o.x = f2bf(fmaxf(v[0]+b4.x, 0.f)); o.y = f2bf(fmaxf(v[1]+b4.y, 0.f));
        o.z = f2bf(fmaxf(v[2]+b4.z, 0.f)); o.w = f2bf(fmaxf(v[3]+b4.w, 0.f));
        *(ushort4*)((u16*)Cout + (size_t)row*N + col0) = o;
      } else if (mode == 4) {
        size_t i2 = (size_t)row*N + col0;
        float4 r4 = *(const float4*)(res + i2);
        float4 b4 = *(const float4*)(bias + col0);
        float4 o = make_float4(v[0]+r4.x+b4.x, v[1]+r4.y+b4.y,
                               v[2]+r4.z+b4.z, v[3]+r4.w+b4.w);
        *(float4*)((float*)Cout + i2) = o;
      } else if (mode == 5) {
        int rr = row >> 7, ss = row & 127;
        size_t i2 = ((size_t)ss*R + rr)*(size_t)N + col0;
        float4 r4 = *(const float4*)(res + i2);
        float4 b4 = *(const float4*)(bias + col0);
        float4 o = make_float4(v[0]+r4.x+b4.x, v[1]+r4.y+b4.y,
                               v[2]+r4.z+b4.z, v[3]+r4.w+b4.w);
        *(float4*)((float*)Cout + i2) = o;
      } else if (mode == 2) {
        float4 b4 = *(const float4*)(bias + col0);
        ushort4 o;
        o.x = f2bf(1.0f/(1.0f+__expf(-(v[0]+b4.x))));
        o.y = f2bf(1.0f/(1.0f+__expf(-(v[1]+b4.y))));
        o.z = f2bf(1.0f/(1.0f+__expf(-(v[2]+b4.z))));
        o.w = f2bf(1.0f/(1.0f+__expf(-(v[3]+b4.w))));
        *(ushort4*)((u16*)Cout + (size_t)row*N + col0) = o;
      } else {
        ushort4 o; o.x=f2bf(v[0]); o.y=f2bf(v[1]); o.z=f2bf(v[2]); o.w=f2bf(v[3]);
        *(ushort4*)((u16*)Cout + (size_t)row*N + col0) = o;
      }
    }
  }
}

// ---------------- MFMA attention (QK^T: A=K,B=Q ; PV: A=V^T,B=P) ----------------
// QKVG: [b-panel rows][1024] bf16, Q at +0, K at +256, V at +512, G at +768.
// One block per (h, b); 512 threads = 8 waves; wave owns MT*16 q-rows.
template<int NKEY, int MT, bool ROWMODE>
__global__ __launch_bounds__(512) void attn_mfma(
    const u16* __restrict__ QKVG, const float* __restrict__ bias,
    const float* __restrict__ mask, u16* __restrict__ og)
{
  __shared__ u16 Vt[32][NKEY+8];
  __shared__ u16 Ps[8][16][72];
  __shared__ float lmb[NKEY];
  constexpr int KVI = NKEY/64;
  int h = blockIdx.x, b = blockIdx.y;
  int t = threadIdx.x, lane = t & 63, w = t >> 6;
  int g16 = lane >> 4, l16 = lane & 15;

  size_t base1 = (size_t)b * NKEY * 1024 + h * 32;
  const u16* Qp = QKVG + base1;
  const u16* Kp = QKVG + base1 + 256;
  const u16* Vp = QKVG + base1 + 512;
  const u16* Gp = QKVG + base1 + 768;

  // stage V transposed
  if (NKEY == 256) {
    int key = t & 255, ch0 = (t >> 8) * 16;
    #pragma unroll
    for (int c0 = 0; c0 < 16; c0 += 8) {
      bf16x8 v8 = *(const bf16x8*)(Vp + (size_t)key*1024 + ch0 + c0);
      #pragma unroll
      for (int j = 0; j < 8; ++j) Vt[ch0+c0+j][key] = (u16)v8[j];
    }
  } else {
    int key = t & 127, ch0 = (t >> 7) * 8;
    bf16x8 v8 = *(const bf16x8*)(Vp + (size_t)key*1024 + ch0);
    #pragma unroll
    for (int j = 0; j < 8; ++j) Vt[ch0+j][key] = (u16)v8[j];
  }
  for (int i = t; i < NKEY; i += 512)
    lmb[i] = 1e9f * ((ROWMODE ? mask[b*R + i] : mask[i*R + b]) - 1.0f);
  __syncthreads();

  int qw = w * MT * 16;
  bf16x8 qb[MT];
  #pragma unroll
  for (int m = 0; m < MT; ++m)
    qb[m] = *(const bf16x8*)(Qp + (size_t)(qw + m*16 + l16)*1024 + g16*8);

  f32x4 oacc[MT][2];
  float lsum[MT];
  #pragma unroll
  for (int m = 0; m < MT; ++m) {
    oacc[m][0] = (f32x4){0.f,0.f,0.f,0.f};
    oacc[m][1] = (f32x4){0.f,0.f,0.f,0.f};
    lsum[m] = 0.f;
  }
  const float* bias_b = bias + (size_t)h*NPAIR;

  for (int kv = 0; kv < KVI; ++kv) {
    int k0w = kv*64;
    bf16x8 ka[4];
    #pragma unroll
    for (int kt = 0; kt < 4; ++kt)
      ka[kt] = *(const bf16x8*)(Kp + (size_t)(k0w + kt*16 + l16)*1024 + g16*8);
    bf16x8 vb[2][2];
    #pragma unroll
    for (int n2 = 0; n2 < 2; ++n2)
      #pragma unroll
      for (int tt = 0; tt < 2; ++tt)
        vb[n2][tt] = *(const bf16x8*)(&Vt[n2*16 + l16][k0w + tt*32 + g16*8]);

    #pragma unroll
    for (int m = 0; m < MT; ++m) {
      int q = qw + m*16 + l16;
      #pragma unroll
      for (int kt = 0; kt < 4; ++kt) {
        f32x4 sac = __builtin_amdgcn_mfma_f32_16x16x32_bf16(
            ka[kt], qb[m], (f32x4){0.f,0.f,0.f,0.f}, 0, 0, 0);
        int k0 = k0w + kt*16 + g16*4;
        float4 lm4 = *(const float4*)&lmb[k0];
        float p0, p1, p2, p3;
        if (ROWMODE) {
          float4 b4 = *(const float4*)(bias_b + (size_t)q*R + k0);
          p0 = __expf(sac[0] + lm4.x + b4.x);
          p1 = __expf(sac[1] + lm4.y + b4.y);
          p2 = __expf(sac[2] + lm4.z + b4.z);
          p3 = __expf(sac[3] + lm4.w + b4.w);
        } else {
          p0 = __expf(sac[0] + lm4.x);
          p1 = __expf(sac[1] + lm4.y);
          p2 = __expf(sac[2] + lm4.z);
          p3 = __expf(sac[3] + lm4.w);
        }
        lsum[m] += (p0 + p1) + (p2 + p3);
        ushort4 pk;
        pk.x = f2bf(p0); pk.y = f2bf(p1); pk.z = f2bf(p2); pk.w = f2bf(p3);
        *(ushort4*)&Ps[w][l16][kt*16 + g16*4] = pk;
      }
      #pragma unroll
      for (int tt = 0; tt < 2; ++tt) {
        bf16x8 pa = *(const bf16x8*)&Ps[w][l16][tt*32 + g16*8];
        oacc[m][0] = __builtin_amdgcn_mfma_f32_16x16x32_bf16(vb[0][tt], pa, oacc[m][0], 0, 0, 0);
        oacc[m][1] = __builtin_amdgcn_mfma_f32_16x16x32_bf16(vb[1][tt], pa, oacc[m][1], 0, 0, 0);
      }
    }
  }

  // lsum per-lane covers q = qw + m*16 + l16, its g16 key-slice; reduce over g16
  #pragma unroll
  for (int m = 0; m < MT; ++m) {
    float v = lsum[m];
    v += __shfl_xor(v, 16);
    v += __shfl_xor(v, 32);
    lsum[m] = v;
  }

  // PV-swapped output: lane holds q = qw+m*16+l16 (fixed), cols n2*16+g16*4..+3
  size_t baseO = (size_t)b * NKEY * 256 + h * 32;
  #pragma unroll
  for (int m = 0; m < MT; ++m) {
    float inv = 1.0f / lsum[m];
    int q = qw + m*16 + l16;
    const u16* gp = Gp + (size_t)q*1024;
    u16* op = og + baseO + (size_t)q*256;
    #pragma unroll
    for (int n2 = 0; n2 < 2; ++n2) {
      int c0 = n2*16 + (g16<<2);
      ushort4 g4 = *(const ushort4*)(gp + c0);
      ushort4 o4;
      o4.x = f2bf(oacc[m][n2][0] * inv * bf2f(g4.x));
      o4.y = f2bf(oacc[m][n2][1] * inv * bf2f(g4.y));
      o4.z = f2bf(oacc[m][n2][2] * inv * bf2f(g4.z));
      o4.w = f2bf(oacc[m][n2][3] * inv * bf2f(g4.w));
      *(ushort4*)(op + c0) = o4;
    }
  }
}

extern "C" void kernel_launch(void* const* d_in, const int* in_sizes, int n_in,
                              void* d_out, int out_size, void* d_ws, size_t ws_size,
                              hipStream_t stream)
{
  const float* node         = (const float*)d_in[0];
  const float* pair         = (const float*)d_in[1];
  const float* node_mask    = (const float*)d_in[2];
  const float* row_ln_m_g   = (const float*)d_in[3];
  const float* row_ln_m_b   = (const float*)d_in[4];
  const float* row_ln_z_g   = (const float*)d_in[5];
  const float* row_ln_z_b   = (const float*)d_in[6];
  const float* row_b_w      = (const float*)d_in[7];
  const float* row_wq       = (const float*)d_in[8];
  const float* row_wk       = (const float*)d_in[9];
  const float* row_wv       = (const float*)d_in[10];
  const float* row_wg       = (const float*)d_in[11];
  const float* row_bg       = (const float*)d_in[12];
  const float* row_wo       = (const float*)d_in[13];
  const float* row_out_bias = (const float*)d_in[14];
  const float* col_ln_g     = (const float*)d_in[15];
  const float* col_ln_b     = (const float*)d_in[16];
  const float* col_wq       = (const float*)d_in[17];
  const float* col_wk       = (const float*)d_in[18];
  const float* col_wv       = (const float*)d_in[19];
  const float* col_wg       = (const float*)d_in[20];
  const float* col_bg       = (const float*)d_in[21];
  const float* col_wo       = (const float*)d_in[22];
  const float* col_bo       = (const float*)d_in[23];
  const float* tr_ln_g      = (const float*)d_in[24];
  const float* tr_ln_b      = (const float*)d_in[25];
  const float* tr_w1        = (const float*)d_in[26];
  const float* tr_b1        = (const float*)d_in[27];
  const float* tr_w2        = (const float*)d_in[28];
  const float* tr_b2        = (const float*)d_in[29];

  float* out = (float*)d_out;
  char* ws8 = (char*)d_ws;
  const size_t MB = 1ull << 20;
  u16*   A     = (u16*)(ws8);               // 16 MB  LN out [32768][256] bf16
  u16*   QKVG  = (u16*)(ws8 + 16*MB);       // 64 MB  [32768][1024] bf16 (also T1)
  u16*   Ob    = (u16*)(ws8 + 80*MB);       // 16 MB  gated attn out bf16
  float* Dbias = (float*)(ws8 + 96*MB);     // 2 MB   [H][R][R]
  u16*   Wb    = (u16*)(ws8 + 100*MB);      // bf16 weight arena
  u16*   T1    = QKVG;

  const float qs = 0.17677669529663687f;    // 1/sqrt(32)

  u16* Wrqkvg = Wb + 0;
  u16* Wro    = Wb + 262144;
  u16* Wcqkvg = Wb + 327680;
  u16* Wco    = Wb + 589824;
  u16* W1     = Wb + 655360;
  u16* W2     = Wb + 917504;

  CvtArgs ca;
  const float* srcs[12] = {row_wq,row_wk,row_wv,row_wg,row_wo,
                           col_wq,col_wk,col_wv,col_wg,col_wo,tr_w1,tr_w2};
  int offs[12] = {0,65536,131072,196608,262144,327680,393216,458752,524288,589824,655360,917504};
  int ns[12]   = {65536,65536,65536,65536,65536,65536,65536,65536,65536,65536,262144,262144};
  for (int i = 0; i < 12; ++i) {
    ca.src[i] = srcs[i]; ca.off[i] = offs[i]; ca.n[i] = ns[i];
    ca.scale[i] = (i == 0 || i == 5) ? qs : 1.0f;
  }
  cvt_w_kernel<<<dim3(256,12), 256, 0, stream>>>(ca, Wb);

  // grids: BM=256, BN=256 -> (N/256, 128)
  dim3 gq(4, 128), go(1, 128);

  // --- row attention ---
  ln256_kernel<<<8192, 256, 0, stream>>>(node, A, row_ln_m_g, row_ln_m_b, 0);
  pair_bias_kernel<<<16384, 256, 0, stream>>>(pair, row_ln_z_g, row_ln_z_b, row_b_w, Dbias);
  gemm_8ph<<<gq, 512, 0, stream>>>(A, Wrqkvg, QKVG, 1024, 256, 6, row_bg, nullptr);
  attn_mfma<256,2,true><<<dim3(8,128), 512, 0, stream>>>(QKVG, Dbias, node_mask, Ob);
  gemm_8ph<<<go, 512, 0, stream>>>(Ob, Wro, out, 256, 256, 4, row_out_bias, node);

  // --- column attention (in [r,s,d] layout) ---
  ln256_kernel<<<8192, 256, 0, stream>>>(out, A, col_ln_g, col_ln_b, 1);
  gemm_8ph<<<gq, 512, 0, stream>>>(A, Wcqkvg, QKVG, 1024, 256, 6, col_bg, nullptr);
  attn_mfma<128,1,false><<<dim3(8,256), 512, 0, stream>>>(QKVG, Dbias, node_mask, Ob);
  gemm_8ph<<<go, 512, 0, stream>>>(Ob, Wco, out, 256, 256, 5, col_bo, out);

  // --- transition ---
  ln256_kernel<<<8192, 256, 0, stream>>>(out, A, tr_ln_g, tr_ln_b, 0);
  gemm_8ph<<<gq, 512, 0, stream>>>(A, W1, T1, 1024, 256, 3, tr_b1, nullptr);
  gemm_8ph<<<go, 512, 0, stream>>>(T1, W2, out, 256, 1024, 4, tr_b2, out);
}

// Round 8
// 396.463 us; speedup vs baseline: 4.1771x; 1.0129x over previous
//
#include <hip/hip_runtime.h>
#include <math.h>

#define S 128
#define R 256
#define DMODEL 256
#define H 8
#define CDIM 32
#define HC 256
#define DFF 1024
#define NROWS (S*R)     // 32768
#define NPAIR (R*R)     // 65536
#define LN_EPS 1e-5f
#define LOG2E 1.4426950408889634f

typedef unsigned short u16;
typedef __attribute__((ext_vector_type(8))) short bf16x8;
typedef __attribute__((ext_vector_type(4))) float f32x4;

__device__ __forceinline__ u16 f2bf(float x) {
  unsigned u = __float_as_uint(x);
  u = (u + 0x7fffu + ((u >> 16) & 1u)) >> 16;
  return (u16)u;
}
__device__ __forceinline__ float bf2f(u16 x) {
  return __uint_as_float(((unsigned)x) << 16);
}
// pack 2 f32 -> 2 bf16 in one u32 (lo = a, hi = b), RNE
__device__ __forceinline__ unsigned cvt_pk(float a, float b) {
  unsigned r;
  asm("v_cvt_pk_bf16_f32 %0, %1, %2" : "=v"(r) : "v"(a), "v"(b));
  return r;
}

__device__ __forceinline__ void gload_lds16(const u16* g, u16* l) {
  __builtin_amdgcn_global_load_lds(
      (const __attribute__((address_space(1))) unsigned int*)g,
      (__attribute__((address_space(3))) unsigned int*)l, 16, 0, 0);
}

// ---------------- weight f32 -> bf16 conversion (12 segments) ----------------
struct CvtArgs {
  const float* src[12];
  int off[12];
  int n[12];
  float scale[12];
};

__global__ __launch_bounds__(256) void cvt_w_kernel(CvtArgs a, u16* __restrict__ dst) {
  int sg = blockIdx.y;
  int i = (blockIdx.x * 256 + threadIdx.x) * 4;
  if (i >= a.n[sg]) return;
  float4 v = *(const float4*)(a.src[sg] + i);
  float sc = a.scale[sg];
  uint2 o;
  o.x = cvt_pk(v.x * sc, v.y * sc);
  o.y = cvt_pk(v.z * sc, v.w * sc);
  *(uint2*)(dst + a.off[sg] + i) = o;
}

// ---------------- LayerNorm over 256, one row per wave, bf16 out ----------------
__global__ __launch_bounds__(256) void ln256_kernel(
    const float* __restrict__ in, u16* __restrict__ out,
    const float* __restrict__ gamma, const float* __restrict__ beta,
    int tmode)
{
  int wid = threadIdx.x >> 6, lane = threadIdx.x & 63;
  int m = blockIdx.x * 4 + wid;
  int inrow = m;
  if (tmode) { int r = m >> 7, s = m & 127; inrow = s * R + r; }
  float4 x = *(const float4*)(in + (size_t)inrow * DMODEL + lane * 4);
  float sum = x.x + x.y + x.z + x.w;
  float sq  = x.x*x.x + x.y*x.y + x.z*x.z + x.w*x.w;
  #pragma unroll
  for (int off = 32; off; off >>= 1) {
    sum += __shfl_xor(sum, off);
    sq  += __shfl_xor(sq, off);
  }
  float mean = sum * (1.0f/256.0f);
  float var  = sq  * (1.0f/256.0f) - mean*mean;
  float rstd = rsqrtf(var + LN_EPS);
  float4 g = *(const float4*)(gamma + lane*4);
  float4 b = *(const float4*)(beta  + lane*4);
  uint2 o;
  o.x = cvt_pk((x.x-mean)*rstd*g.x + b.x, (x.y-mean)*rstd*g.y + b.y);
  o.y = cvt_pk((x.z-mean)*rstd*g.z + b.z, (x.w-mean)*rstd*g.w + b.w);
  *(uint2*)(out + (size_t)m * DMODEL + lane*4) = o;
}

// ------- pair LN (over 128) + bias projection -> bias[h][q][k] (bf16, *log2e) -------
__global__ __launch_bounds__(256) void pair_bias_kernel(
    const float* __restrict__ pair, const float* __restrict__ gamma,
    const float* __restrict__ beta, const float* __restrict__ bw,
    u16* __restrict__ bias)
{
  int wid = threadIdx.x >> 6, lane = threadIdx.x & 63;
  int p = blockIdx.x * 4 + wid;
  float2 x = *(const float2*)(pair + (size_t)p * 128 + lane*2);
  float sum = x.x + x.y, sq = x.x*x.x + x.y*x.y;
  #pragma unroll
  for (int off = 32; off; off >>= 1) {
    sum += __shfl_xor(sum, off);
    sq  += __shfl_xor(sq, off);
  }
  float mean = sum * (1.0f/128.0f);
  float rstd = rsqrtf(sq*(1.0f/128.0f) - mean*mean + LN_EPS);
  float z0 = (x.x-mean)*rstd*gamma[lane*2]   + beta[lane*2];
  float z1 = (x.y-mean)*rstd*gamma[lane*2+1] + beta[lane*2+1];
  float a0 = z0*bw[0*128+lane*2] + z1*bw[0*128+lane*2+1];
  float a1 = z0*bw[1*128+lane*2] + z1*bw[1*128+lane*2+1];
  float a2 = z0*bw[2*128+lane*2] + z1*bw[2*128+lane*2+1];
  float a3 = z0*bw[3*128+lane*2] + z1*bw[3*128+lane*2+1];
  float a4 = z0*bw[4*128+lane*2] + z1*bw[4*128+lane*2+1];
  float a5 = z0*bw[5*128+lane*2] + z1*bw[5*128+lane*2+1];
  float a6 = z0*bw[6*128+lane*2] + z1*bw[6*128+lane*2+1];
  float a7 = z0*bw[7*128+lane*2] + z1*bw[7*128+lane*2+1];
  #pragma unroll
  for (int off = 32; off; off >>= 1) {
    a0 += __shfl_xor(a0, off); a1 += __shfl_xor(a1, off);
    a2 += __shfl_xor(a2, off); a3 += __shfl_xor(a3, off);
    a4 += __shfl_xor(a4, off); a5 += __shfl_xor(a5, off);
    a6 += __shfl_xor(a6, off); a7 += __shfl_xor(a7, off);
  }
  float v = a0;
  v = (lane==1)?a1:v; v = (lane==2)?a2:v; v = (lane==3)?a3:v;
  v = (lane==4)?a4:v; v = (lane==5)?a5:v; v = (lane==6)?a6:v; v = (lane==7)?a7:v;
  if (lane < 8) bias[(size_t)lane*NPAIR + p] = f2bf(v * LOG2E);
}

// ---------------- bf16 MFMA NT GEMM, 256x256 tile, BK=64, counted-vmcnt ----------------
// C[M,N] = A[M,K] * W[N,K]^T.  512 threads = 8 waves (2M x 4N), per-wave 128x64.
// LDS: 2 dbuf x 4 half-tiles [128][64] = 128 KB. Swapped MFMA operands (W as A-op)
// so each lane holds 4 consecutive N-cols -> vector epilogue.
// modes: 1: bf16  2: bf16 sigmoid(x+bias)  3: bf16 relu(x+bias)
//        4: f32 x+res+bias   5: f32 transposed idx   6: bf16, cols>=768 sigmoid(+bias)
__global__ __launch_bounds__(512, 2) void gemm_8ph(
    const u16* __restrict__ A, const u16* __restrict__ W,
    void* __restrict__ Cout, int N, int K,
    int mode, const float* __restrict__ bias, const float* __restrict__ res)
{
  __shared__ u16 lds[2][4][128*64];
  int t = threadIdx.x, lane = t & 63, wv = t >> 6;
  int g16 = (lane >> 4) & 3, l16 = lane & 15;
  int wm = wv >> 2, wn = wv & 3;
  int lrow = lane >> 3, lchunk = lane & 7;

  // bijective XCD swizzle (nwg % 8 == 0 for all our grids)
  int gx = gridDim.x;
  int nwg = gx * gridDim.y;
  int p = blockIdx.y * gx + blockIdx.x;
  int cpx = nwg >> 3;
  int lg = (p & 7) * cpx + (p >> 3);
  int bn = (lg % gx) * 256;
  int bm = (lg / gx) * 256;

  int srcc = (lchunk ^ lrow) << 3;          // pre-swizzled global k-chunk
  int ch0  = (g16 ^ (l16 & 7)) << 3;        // swizzled LDS read chunk (k32=0)
  int rdoff = l16 * 64 + ch0;               // k32=1 -> rdoff ^ 32
  const int wnh = 2 + (wn >> 1);
  const int wnr = (wn & 1) * 4096;

  f32x4 acc[8][4];
  #pragma unroll
  for (int i = 0; i < 8; ++i)
    #pragma unroll
    for (int j = 0; j < 4; ++j) acc[i][j] = (f32x4){0.f,0.f,0.f,0.f};

  const int nkt = K >> 6;

#define STG_HALF(buf_, h_, base_, row0_, kc_) do { \
    gload_lds16(base_ + (size_t)((row0_) + (wv*2+0)*8 + lrow) * K + (kc_) + srcc, \
                &lds[buf_][h_][(wv*2+0)*512 + lane*8]); \
    gload_lds16(base_ + (size_t)((row0_) + (wv*2+1)*8 + lrow) * K + (kc_) + srcc, \
                &lds[buf_][h_][(wv*2+1)*512 + lane*8]); \
  } while(0)
#define STG_A(buf_, kc_) do { STG_HALF(buf_,0,A,bm,kc_); STG_HALF(buf_,1,A,bm+128,kc_); } while(0)
#define STG_B(buf_, kc_) do { STG_HALF(buf_,2,W,bn,kc_); STG_HALF(buf_,3,W,bn+128,kc_); } while(0)

  int buf = 0;
  STG_A(0, 0); STG_B(0, 0);                 // 8 loads in flight
  for (int kt = 0; kt < nkt; ++kt) {
    int kc = kt << 6;
    if (kt + 1 < nkt) {
      STG_A(buf^1, kc + 64);                // +4 (issue-early)
      asm volatile("s_waitcnt vmcnt(4)" ::: "memory");   // this kt's 8 done
    } else {
      asm volatile("s_waitcnt vmcnt(0)" ::: "memory");
    }
    __builtin_amdgcn_s_barrier();
    asm volatile("" ::: "memory");
    if (kt + 1 < nkt) STG_B(buf^1, kc + 64);

    const u16* Abase = &lds[buf][wm][0];
    const u16* Wbase = &lds[buf][wnh][wnr];
    bf16x8 wf[4][2];
    #pragma unroll
    for (int nf = 0; nf < 4; ++nf) {
      wf[nf][0] = *(const bf16x8*)(Wbase + nf*1024 + rdoff);
      wf[nf][1] = *(const bf16x8*)(Wbase + nf*1024 + (rdoff ^ 32));
    }
    __builtin_amdgcn_s_setprio(1);
    #pragma unroll
    for (int mf = 0; mf < 8; ++mf) {
      bf16x8 a0 = *(const bf16x8*)(Abase + mf*1024 + rdoff);
      bf16x8 a1 = *(const bf16x8*)(Abase + mf*1024 + (rdoff ^ 32));
      #pragma unroll
      for (int nf = 0; nf < 4; ++nf) {
        acc[mf][nf] = __builtin_amdgcn_mfma_f32_16x16x32_bf16(wf[nf][0], a0, acc[mf][nf], 0, 0, 0);
        acc[mf][nf] = __builtin_amdgcn_mfma_f32_16x16x32_bf16(wf[nf][1], a1, acc[mf][nf], 0, 0, 0);
      }
    }
    __builtin_amdgcn_s_setprio(0);
    asm volatile("" ::: "memory");
    __builtin_amdgcn_s_barrier();
    buf ^= 1;
  }
#undef STG_A
#undef STG_B
#undef STG_HALF

  // epilogue: lane holds rows (l16-based), 4 consecutive cols (g16*4 + r)
  int rowb = bm + wm*128 + l16;
  int colb = bn + wn*64 + (g16 << 2);
  #pragma unroll
  for (int mf = 0; mf < 8; ++mf) {
    int row = rowb + mf*16;
    #pragma unroll
    for (int nf = 0; nf < 4; ++nf) {
      int col0 = colb + nf*16;
      f32x4 v = acc[mf][nf];
      if (mode == 6) {
        if (col0 >= 768) {
          float4 b4 = *(const float4*)(bias + col0 - 768);
          v[0] = 1.0f/(1.0f+__expf(-(v[0]+b4.x)));
          v[1] = 1.0f/(1.0f+__expf(-(v[1]+b4.y)));
          v[2] = 1.0f/(1.0f+__expf(-(v[2]+b4.z)));
          v[3] = 1.0f/(1.0f+__expf(-(v[3]+b4.w)));
        }
        uint2 o; o.x = cvt_pk(v[0], v[1]); o.y = cvt_pk(v[2], v[3]);
        *(uint2*)((u16*)Cout + (size_t)row*N + col0) = o;
      } else if (mode == 3) {
        float4 b4 = *(const float4*)(bias + col0);
        uint2 o;
        o.x = cvt_pk(fmaxf(v[0]+b4.x, 0.f), fmaxf(v[1]+b4.y, 0.f));
        o.y = cvt_pk(fmaxf(v[2]+b4.z, 0.f), fmaxf(v[3]+b4.w, 0.f));
        *(uint2*)((u16*)Cout + (size_t)row*N + col0) = o;
      } else if (mode == 4) {
        size_t i2 = (size_t)row*N + col0;
        float4 r4 = *(const float4*)(res + i2);
        float4 b4 = *(const float4*)(bias + col0);
        float4 o = make_float4(v[0]+r4.x+b4.x, v[1]+r4.y+b4.y,
                               v[2]+r4.z+b4.z, v[3]+r4.w+b4.w);
        *(float4*)((float*)Cout + i2) = o;
      } else if (mode == 5) {
        int rr = row >> 7, ss = row & 127;
        size_t i2 = ((size_t)ss*R + rr)*(size_t)N + col0;
        float4 r4 = *(const float4*)(res + i2);
        float4 b4 = *(const float4*)(bias + col0);
        float4 o = make_float4(v[0]+r4.x+b4.x, v[1]+r4.y+b4.y,
                               v[2]+r4.z+b4.z, v[3]+r4.w+b4.w);
        *(float4*)((float*)Cout + i2) = o;
      } else if (mode == 2) {
        float4 b4 = *(const float4*)(bias + col0);
        uint2 o;
        o.x = cvt_pk(1.0f/(1.0f+__expf(-(v[0]+b4.x))),
                     1.0f/(1.0f+__expf(-(v[1]+b4.y))));
        o.y = cvt_pk(1.0f/(1.0f+__expf(-(v[2]+b4.z))),
                     1.0f/(1.0f+__expf(-(v[3]+b4.w))));
        *(uint2*)((u16*)Cout + (size_t)row*N + col0) = o;
      } else {
        uint2 o; o.x = cvt_pk(v[0], v[1]); o.y = cvt_pk(v[2], v[3]);
        *(uint2*)((u16*)Cout + (size_t)row*N + col0) = o;
      }
    }
  }
}

// ---------------- MFMA attention (QK^T: A=K,B=Q ; PV: A=V^T,B=P) ----------------
// QKVG: [b-panel rows][1024] bf16, Q at +0, K at +256, V at +512, G at +768.
// Q pre-scaled by qs*log2e; bias (bf16) and mask additive pre-scaled by log2e;
// softmax uses exp2.
template<int NKEY, int MT, bool ROWMODE>
__global__ __launch_bounds__(512) void attn_mfma(
    const u16* __restrict__ QKVG, const u16* __restrict__ bias,
    const float* __restrict__ mask, u16* __restrict__ og)
{
  __shared__ u16 Vt[32][NKEY+8];
  __shared__ u16 Ps[8][16][72];
  __shared__ float lmb[NKEY];
  constexpr int KVI = NKEY/64;
  int h = blockIdx.x, b = blockIdx.y;
  int t = threadIdx.x, lane = t & 63, w = t >> 6;
  int g16 = lane >> 4, l16 = lane & 15;

  size_t base1 = (size_t)b * NKEY * 1024 + h * 32;
  const u16* Qp = QKVG + base1;
  const u16* Kp = QKVG + base1 + 256;
  const u16* Vp = QKVG + base1 + 512;
  const u16* Gp = QKVG + base1 + 768;

  // stage V transposed
  if (NKEY == 256) {
    int key = t & 255, ch0 = (t >> 8) * 16;
    #pragma unroll
    for (int c0 = 0; c0 < 16; c0 += 8) {
      bf16x8 v8 = *(const bf16x8*)(Vp + (size_t)key*1024 + ch0 + c0);
      #pragma unroll
      for (int j = 0; j < 8; ++j) Vt[ch0+c0+j][key] = (u16)v8[j];
    }
  } else {
    int key = t & 127, ch0 = (t >> 7) * 8;
    bf16x8 v8 = *(const bf16x8*)(Vp + (size_t)key*1024 + ch0);
    #pragma unroll
    for (int j = 0; j < 8; ++j) Vt[ch0+j][key] = (u16)v8[j];
  }
  for (int i = t; i < NKEY; i += 512)
    lmb[i] = 1.4426950e9f * ((ROWMODE ? mask[b*R + i] : mask[i*R + b]) - 1.0f);
  __syncthreads();

  int qw = w * MT * 16;
  bf16x8 qb[MT];
  #pragma unroll
  for (int m = 0; m < MT; ++m)
    qb[m] = *(const bf16x8*)(Qp + (size_t)(qw + m*16 + l16)*1024 + g16*8);

  f32x4 oacc[MT][2];
  float lsum[MT];
  #pragma unroll
  for (int m = 0; m < MT; ++m) {
    oacc[m][0] = (f32x4){0.f,0.f,0.f,0.f};
    oacc[m][1] = (f32x4){0.f,0.f,0.f,0.f};
    lsum[m] = 0.f;
  }
  const u16* bias_b = bias + (size_t)h*NPAIR;

  for (int kv = 0; kv < KVI; ++kv) {
    int k0w = kv*64;
    bf16x8 ka[4];
    #pragma unroll
    for (int kt = 0; kt < 4; ++kt)
      ka[kt] = *(const bf16x8*)(Kp + (size_t)(k0w + kt*16 + l16)*1024 + g16*8);
    bf16x8 vb[2][2];
    #pragma unroll
    for (int n2 = 0; n2 < 2; ++n2)
      #pragma unroll
      for (int tt = 0; tt < 2; ++tt)
        vb[n2][tt] = *(const bf16x8*)(&Vt[n2*16 + l16][k0w + tt*32 + g16*8]);

    #pragma unroll
    for (int m = 0; m < MT; ++m) {
      int q = qw + m*16 + l16;
      f32x4 sac[4];
      __builtin_amdgcn_s_setprio(1);
      #pragma unroll
      for (int kt = 0; kt < 4; ++kt)
        sac[kt] = __builtin_amdgcn_mfma_f32_16x16x32_bf16(
            ka[kt], qb[m], (f32x4){0.f,0.f,0.f,0.f}, 0, 0, 0);
      __builtin_amdgcn_s_setprio(0);
      #pragma unroll
      for (int kt = 0; kt < 4; ++kt) {
        int k0 = k0w + kt*16 + g16*4;
        float4 lm4 = *(const float4*)&lmb[k0];
        float p0, p1, p2, p3;
        if (ROWMODE) {
          ushort4 b4 = *(const ushort4*)(bias_b + (size_t)q*R + k0);
          p0 = exp2f(sac[kt][0] + lm4.x + bf2f(b4.x));
          p1 = exp2f(sac[kt][1] + lm4.y + bf2f(b4.y));
          p2 = exp2f(sac[kt][2] + lm4.z + bf2f(b4.z));
          p3 = exp2f(sac[kt][3] + lm4.w + bf2f(b4.w));
        } else {
          p0 = exp2f(sac[kt][0] + lm4.x);
          p1 = exp2f(sac[kt][1] + lm4.y);
          p2 = exp2f(sac[kt][2] + lm4.z);
          p3 = exp2f(sac[kt][3] + lm4.w);
        }
        lsum[m] += (p0 + p1) + (p2 + p3);
        uint2 pk2;
        pk2.x = cvt_pk(p0, p1);
        pk2.y = cvt_pk(p2, p3);
        *(uint2*)&Ps[w][l16][kt*16 + g16*4] = pk2;
      }
      __builtin_amdgcn_s_setprio(1);
      #pragma unroll
      for (int tt = 0; tt < 2; ++tt) {
        bf16x8 pa = *(const bf16x8*)&Ps[w][l16][tt*32 + g16*8];
        oacc[m][0] = __builtin_amdgcn_mfma_f32_16x16x32_bf16(vb[0][tt], pa, oacc[m][0], 0, 0, 0);
        oacc[m][1] = __builtin_amdgcn_mfma_f32_16x16x32_bf16(vb[1][tt], pa, oacc[m][1], 0, 0, 0);
      }
      __builtin_amdgcn_s_setprio(0);
    }
  }

  // lsum per-lane covers q = qw + m*16 + l16, its g16 key-slice; reduce over g16
  #pragma unroll
  for (int m = 0; m < MT; ++m) {
    float v = lsum[m];
    v += __shfl_xor(v, 16);
    v += __shfl_xor(v, 32);
    lsum[m] = v;
  }

  // PV-swapped output: lane holds q = qw+m*16+l16 (fixed), cols n2*16+g16*4..+3
  size_t baseO = (size_t)b * NKEY * 256 + h * 32;
  #pragma unroll
  for (int m = 0; m < MT; ++m) {
    float inv = 1.0f / lsum[m];
    int q = qw + m*16 + l16;
    const u16* gp = Gp + (size_t)q*1024;
    u16* op = og + baseO + (size_t)q*256;
    #pragma unroll
    for (int n2 = 0; n2 < 2; ++n2) {
      int c0 = n2*16 + (g16<<2);
      ushort4 g4 = *(const ushort4*)(gp + c0);
      float f0 = oacc[m][n2][0] * inv * bf2f(g4.x);
      float f1 = oacc[m][n2][1] * inv * bf2f(g4.y);
      float f2 = oacc[m][n2][2] * inv * bf2f(g4.z);
      float f3 = oacc[m][n2][3] * inv * bf2f(g4.w);
      uint2 o2; o2.x = cvt_pk(f0, f1); o2.y = cvt_pk(f2, f3);
      *(uint2*)(op + c0) = o2;
    }
  }
}

extern "C" void kernel_launch(void* const* d_in, const int* in_sizes, int n_in,
                              void* d_out, int out_size, void* d_ws, size_t ws_size,
                              hipStream_t stream)
{
  const float* node         = (const float*)d_in[0];
  const float* pair         = (const float*)d_in[1];
  const float* node_mask    = (const float*)d_in[2];
  const float* row_ln_m_g   = (const float*)d_in[3];
  const float* row_ln_m_b   = (const float*)d_in[4];
  const float* row_ln_z_g   = (const float*)d_in[5];
  const float* row_ln_z_b   = (const float*)d_in[6];
  const float* row_b_w      = (const float*)d_in[7];
  const float* row_wq       = (const float*)d_in[8];
  const float* row_wk       = (const float*)d_in[9];
  const float* row_wv       = (const float*)d_in[10];
  const float* row_wg       = (const float*)d_in[11];
  const float* row_bg       = (const float*)d_in[12];
  const float* row_wo       = (const float*)d_in[13];
  const float* row_out_bias = (const float*)d_in[14];
  const float* col_ln_g     = (const float*)d_in[15];
  const float* col_ln_b     = (const float*)d_in[16];
  const float* col_wq       = (const float*)d_in[17];
  const float* col_wk       = (const float*)d_in[18];
  const float* col_wv       = (const float*)d_in[19];
  const float* col_wg       = (const float*)d_in[20];
  const float* col_bg       = (const float*)d_in[21];
  const float* col_wo       = (const float*)d_in[22];
  const float* col_bo       = (const float*)d_in[23];
  const float* tr_ln_g      = (const float*)d_in[24];
  const float* tr_ln_b      = (const float*)d_in[25];
  const float* tr_w1        = (const float*)d_in[26];
  const float* tr_b1        = (const float*)d_in[27];
  const float* tr_w2        = (const float*)d_in[28];
  const float* tr_b2        = (const float*)d_in[29];

  float* out = (float*)d_out;
  char* ws8 = (char*)d_ws;
  const size_t MB = 1ull << 20;
  u16*   A     = (u16*)(ws8);               // 16 MB  LN out [32768][256] bf16
  u16*   QKVG  = (u16*)(ws8 + 16*MB);       // 64 MB  [32768][1024] bf16 (also T1)
  u16*   Ob    = (u16*)(ws8 + 80*MB);       // 16 MB  gated attn out bf16
  u16*   Dbias = (u16*)(ws8 + 96*MB);       // 1 MB   [H][R][R] bf16 (log2e-scaled)
  u16*   Wb    = (u16*)(ws8 + 100*MB);      // bf16 weight arena
  u16*   T1    = QKVG;

  const float qs = 0.17677669529663687f;    // 1/sqrt(32)

  u16* Wrqkvg = Wb + 0;
  u16* Wro    = Wb + 262144;
  u16* Wcqkvg = Wb + 327680;
  u16* Wco    = Wb + 589824;
  u16* W1     = Wb + 655360;
  u16* W2     = Wb + 917504;

  CvtArgs ca;
  const float* srcs[12] = {row_wq,row_wk,row_wv,row_wg,row_wo,
                           col_wq,col_wk,col_wv,col_wg,col_wo,tr_w1,tr_w2};
  int offs[12] = {0,65536,131072,196608,262144,327680,393216,458752,524288,589824,655360,917504};
  int ns[12]   = {65536,65536,65536,65536,65536,65536,65536,65536,65536,65536,262144,262144};
  for (int i = 0; i < 12; ++i) {
    ca.src[i] = srcs[i]; ca.off[i] = offs[i]; ca.n[i] = ns[i];
    ca.scale[i] = (i == 0 || i == 5) ? qs * LOG2E : 1.0f;
  }
  cvt_w_kernel<<<dim3(256,12), 256, 0, stream>>>(ca, Wb);

  // grids: BM=256, BN=256 -> (N/256, 128)
  dim3 gq(4, 128), go(1, 128);

  // --- row attention ---
  ln256_kernel<<<8192, 256, 0, stream>>>(node, A, row_ln_m_g, row_ln_m_b, 0);
  pair_bias_kernel<<<16384, 256, 0, stream>>>(pair, row_ln_z_g, row_ln_z_b, row_b_w, Dbias);
  gemm_8ph<<<gq, 512, 0, stream>>>(A, Wrqkvg, QKVG, 1024, 256, 6, row_bg, nullptr);
  attn_mfma<256,2,true><<<dim3(8,128), 512, 0, stream>>>(QKVG, Dbias, node_mask, Ob);
  gemm_8ph<<<go, 512, 0, stream>>>(Ob, Wro, out, 256, 256, 4, row_out_bias, node);

  // --- column attention (in [r,s,d] layout) ---
  ln256_kernel<<<8192, 256, 0, stream>>>(out, A, col_ln_g, col_ln_b, 1);
  gemm_8ph<<<gq, 512, 0, stream>>>(A, Wcqkvg, QKVG, 1024, 256, 6, col_bg, nullptr);
  attn_mfma<128,1,false><<<dim3(8,256), 512, 0, stream>>>(QKVG, Dbias, node_mask, Ob);
  gemm_8ph<<<go, 512, 0, stream>>>(Ob, Wco, out, 256, 256, 5, col_bo, out);

  // --- transition ---
  ln256_kernel<<<8192, 256, 0, stream>>>(out, A, tr_ln_g, tr_ln_b, 0);
  gemm_8ph<<<gq, 512, 0, stream>>>(A, W1, T1, 1024, 256, 3, tr_b1, nullptr);
  gemm_8ph<<<go, 512, 0, stream>>>(T1, W2, out, 256, 1024, 4, tr_b2, out);
}

// Round 9
// 378.266 us; speedup vs baseline: 4.3781x; 1.0481x over previous
//
#include <hip/hip_runtime.h>
#include <math.h>

#define S 128
#define R 256
#define DMODEL 256
#define H 8
#define CDIM 32
#define HC 256
#define DFF 1024
#define NROWS (S*R)     // 32768
#define NPAIR (R*R)     // 65536
#define LN_EPS 1e-5f
#define LOG2E 1.4426950408889634f

typedef unsigned short u16;
typedef __attribute__((ext_vector_type(8))) short bf16x8;
typedef __attribute__((ext_vector_type(4))) float f32x4;
typedef __attribute__((ext_vector_type(16))) float f32x16;

__device__ __forceinline__ u16 f2bf(float x) {
  unsigned u = __float_as_uint(x);
  u = (u + 0x7fffu + ((u >> 16) & 1u)) >> 16;
  return (u16)u;
}
__device__ __forceinline__ float bf2f(u16 x) {
  return __uint_as_float(((unsigned)x) << 16);
}
// pack 2 f32 -> 2 bf16 in one u32 (lo = a, hi = b), RNE
__device__ __forceinline__ unsigned cvt_pk(float a, float b) {
  unsigned r;
  asm("v_cvt_pk_bf16_f32 %0, %1, %2" : "=v"(r) : "v"(a), "v"(b));
  return r;
}
// swap a[32:63] <-> b[0:31]
__device__ __forceinline__ void pl32swap(unsigned &a, unsigned &b) {
  asm("v_permlane32_swap_b32 %0, %1" : "+v"(a), "+v"(b));
}
__device__ __forceinline__ bf16x8 mk_frag(unsigned a, unsigned b, unsigned c, unsigned d) {
  uint4 t = make_uint4(a, b, c, d);
  return __builtin_bit_cast(bf16x8, t);
}

__device__ __forceinline__ void gload_lds16(const u16* g, u16* l) {
  __builtin_amdgcn_global_load_lds(
      (const __attribute__((address_space(1))) unsigned int*)g,
      (__attribute__((address_space(3))) unsigned int*)l, 16, 0, 0);
}

// ---------------- weight f32 -> bf16 conversion (12 segments) ----------------
struct CvtArgs {
  const float* src[12];
  int off[12];
  int n[12];
  float scale[12];
};

__global__ __launch_bounds__(256) void cvt_w_kernel(CvtArgs a, u16* __restrict__ dst) {
  int sg = blockIdx.y;
  int i = (blockIdx.x * 256 + threadIdx.x) * 4;
  if (i >= a.n[sg]) return;
  float4 v = *(const float4*)(a.src[sg] + i);
  float sc = a.scale[sg];
  uint2 o;
  o.x = cvt_pk(v.x * sc, v.y * sc);
  o.y = cvt_pk(v.z * sc, v.w * sc);
  *(uint2*)(dst + a.off[sg] + i) = o;
}

// ---------------- LayerNorm over 256, one row per wave, bf16 out ----------------
__global__ __launch_bounds__(256) void ln256_kernel(
    const float* __restrict__ in, u16* __restrict__ out,
    const float* __restrict__ gamma, const float* __restrict__ beta,
    int tmode)
{
  int wid = threadIdx.x >> 6, lane = threadIdx.x & 63;
  int m = blockIdx.x * 4 + wid;
  int inrow = m;
  if (tmode) { int r = m >> 7, s = m & 127; inrow = s * R + r; }
  float4 x = *(const float4*)(in + (size_t)inrow * DMODEL + lane * 4);
  float sum = x.x + x.y + x.z + x.w;
  float sq  = x.x*x.x + x.y*x.y + x.z*x.z + x.w*x.w;
  #pragma unroll
  for (int off = 32; off; off >>= 1) {
    sum += __shfl_xor(sum, off);
    sq  += __shfl_xor(sq, off);
  }
  float mean = sum * (1.0f/256.0f);
  float var  = sq  * (1.0f/256.0f) - mean*mean;
  float rstd = rsqrtf(var + LN_EPS);
  float4 g = *(const float4*)(gamma + lane*4);
  float4 b = *(const float4*)(beta  + lane*4);
  uint2 o;
  o.x = cvt_pk((x.x-mean)*rstd*g.x + b.x, (x.y-mean)*rstd*g.y + b.y);
  o.y = cvt_pk((x.z-mean)*rstd*g.z + b.z, (x.w-mean)*rstd*g.w + b.w);
  *(uint2*)(out + (size_t)m * DMODEL + lane*4) = o;
}

// ------- pair LN (over 128) + bias projection -> bias[h][q][k] (bf16, *log2e) -------
__global__ __launch_bounds__(256) void pair_bias_kernel(
    const float* __restrict__ pair, const float* __restrict__ gamma,
    const float* __restrict__ beta, const float* __restrict__ bw,
    u16* __restrict__ bias)
{
  int wid = threadIdx.x >> 6, lane = threadIdx.x & 63;
  int p = blockIdx.x * 4 + wid;
  float2 x = *(const float2*)(pair + (size_t)p * 128 + lane*2);
  float sum = x.x + x.y, sq = x.x*x.x + x.y*x.y;
  #pragma unroll
  for (int off = 32; off; off >>= 1) {
    sum += __shfl_xor(sum, off);
    sq  += __shfl_xor(sq, off);
  }
  float mean = sum * (1.0f/128.0f);
  float rstd = rsqrtf(sq*(1.0f/128.0f) - mean*mean + LN_EPS);
  float z0 = (x.x-mean)*rstd*gamma[lane*2]   + beta[lane*2];
  float z1 = (x.y-mean)*rstd*gamma[lane*2+1] + beta[lane*2+1];
  float a0 = z0*bw[0*128+lane*2] + z1*bw[0*128+lane*2+1];
  float a1 = z0*bw[1*128+lane*2] + z1*bw[1*128+lane*2+1];
  float a2 = z0*bw[2*128+lane*2] + z1*bw[2*128+lane*2+1];
  float a3 = z0*bw[3*128+lane*2] + z1*bw[3*128+lane*2+1];
  float a4 = z0*bw[4*128+lane*2] + z1*bw[4*128+lane*2+1];
  float a5 = z0*bw[5*128+lane*2] + z1*bw[5*128+lane*2+1];
  float a6 = z0*bw[6*128+lane*2] + z1*bw[6*128+lane*2+1];
  float a7 = z0*bw[7*128+lane*2] + z1*bw[7*128+lane*2+1];
  #pragma unroll
  for (int off = 32; off; off >>= 1) {
    a0 += __shfl_xor(a0, off); a1 += __shfl_xor(a1, off);
    a2 += __shfl_xor(a2, off); a3 += __shfl_xor(a3, off);
    a4 += __shfl_xor(a4, off); a5 += __shfl_xor(a5, off);
    a6 += __shfl_xor(a6, off); a7 += __shfl_xor(a7, off);
  }
  float v = a0;
  v = (lane==1)?a1:v; v = (lane==2)?a2:v; v = (lane==3)?a3:v;
  v = (lane==4)?a4:v; v = (lane==5)?a5:v; v = (lane==6)?a6:v; v = (lane==7)?a7:v;
  if (lane < 8) bias[(size_t)lane*NPAIR + p] = f2bf(v * LOG2E);
}

// ---------------- bf16 MFMA NT GEMM, (AM*128)x256 tile, BK=64, counted-vmcnt ----------------
// C[M,N] = A[M,K] * W[N,K]^T.  512 threads = 8 waves (2M x 4N).
// AM = A half-tiles (2 -> BM=256, 1 -> BM=128 for N=256 GEMMs / full-GPU grids).
// modes: 1: bf16  2: bf16 sigmoid(x+bias)  3: bf16 relu(x+bias)
//        4: f32 x+res+bias   5: f32 transposed idx   6: bf16, cols>=768 sigmoid(+bias)
template<int AM>
__global__ __launch_bounds__(512, 2) void gemm_8ph(
    const u16* __restrict__ A, const u16* __restrict__ W,
    void* __restrict__ Cout, int N, int K,
    int mode, const float* __restrict__ bias, const float* __restrict__ res)
{
  __shared__ u16 lds[2][AM+2][128*64];
  int t = threadIdx.x, lane = t & 63, wv = t >> 6;
  int g16 = (lane >> 4) & 3, l16 = lane & 15;
  int wm = wv >> 2, wn = wv & 3;
  int lrow = lane >> 3, lchunk = lane & 7;

  // bijective XCD swizzle (nwg % 8 == 0 for all our grids)
  int gx = gridDim.x;
  int nwg = gx * gridDim.y;
  int p = blockIdx.y * gx + blockIdx.x;
  int cpx = nwg >> 3;
  int lg = (p & 7) * cpx + (p >> 3);
  int bn = (lg % gx) * 256;
  int bm = (lg / gx) * (AM * 128);

  int srcc = (lchunk ^ lrow) << 3;          // pre-swizzled global k-chunk
  int ch0  = (g16 ^ (l16 & 7)) << 3;        // swizzled LDS read chunk (k32=0)
  int rdoff = l16 * 64 + ch0;               // k32=1 -> rdoff ^ 32
  const int wnh = AM + (wn >> 1);
  const int wnr = (wn & 1) * 4096;

  f32x4 acc[AM*4][4];
  #pragma unroll
  for (int i = 0; i < AM*4; ++i)
    #pragma unroll
    for (int j = 0; j < 4; ++j) acc[i][j] = (f32x4){0.f,0.f,0.f,0.f};

  const int nkt = K >> 6;

#define STG_HALF(buf_, h_, base_, row0_, kc_) do { \
    gload_lds16(base_ + (size_t)((row0_) + (wv*2+0)*8 + lrow) * K + (kc_) + srcc, \
                &lds[buf_][h_][(wv*2+0)*512 + lane*8]); \
    gload_lds16(base_ + (size_t)((row0_) + (wv*2+1)*8 + lrow) * K + (kc_) + srcc, \
                &lds[buf_][h_][(wv*2+1)*512 + lane*8]); \
  } while(0)
#define STG_A(buf_, kc_) do { STG_HALF(buf_,0,A,bm,kc_); \
    if (AM==2) STG_HALF(buf_,1,A,bm+128,kc_); } while(0)
#define STG_B(buf_, kc_) do { STG_HALF(buf_,AM,W,bn,kc_); STG_HALF(buf_,AM+1,W,bn+128,kc_); } while(0)

  int buf = 0;
  STG_A(0, 0); STG_B(0, 0);
  for (int kt = 0; kt < nkt; ++kt) {
    int kc = kt << 6;
    if (kt + 1 < nkt) {
      STG_A(buf^1, kc + 64);                // issue-early next A
      if (AM == 2) asm volatile("s_waitcnt vmcnt(4)" ::: "memory");
      else         asm volatile("s_waitcnt vmcnt(2)" ::: "memory");
    } else {
      asm volatile("s_waitcnt vmcnt(0)" ::: "memory");
    }
    __builtin_amdgcn_s_barrier();
    asm volatile("" ::: "memory");
    if (kt + 1 < nkt) STG_B(buf^1, kc + 64);

    const u16* Abase = (AM==2) ? &lds[buf][wm][0] : &lds[buf][0][wm*4096];
    const u16* Wbase = &lds[buf][wnh][wnr];
    bf16x8 wf[4][2];
    #pragma unroll
    for (int nf = 0; nf < 4; ++nf) {
      wf[nf][0] = *(const bf16x8*)(Wbase + nf*1024 + rdoff);
      wf[nf][1] = *(const bf16x8*)(Wbase + nf*1024 + (rdoff ^ 32));
    }
    __builtin_amdgcn_s_setprio(1);
    #pragma unroll
    for (int mf = 0; mf < AM*4; ++mf) {
      bf16x8 a0 = *(const bf16x8*)(Abase + mf*1024 + rdoff);
      bf16x8 a1 = *(const bf16x8*)(Abase + mf*1024 + (rdoff ^ 32));
      #pragma unroll
      for (int nf = 0; nf < 4; ++nf) {
        acc[mf][nf] = __builtin_amdgcn_mfma_f32_16x16x32_bf16(wf[nf][0], a0, acc[mf][nf], 0, 0, 0);
        acc[mf][nf] = __builtin_amdgcn_mfma_f32_16x16x32_bf16(wf[nf][1], a1, acc[mf][nf], 0, 0, 0);
      }
    }
    __builtin_amdgcn_s_setprio(0);
    asm volatile("" ::: "memory");
    __builtin_amdgcn_s_barrier();
    buf ^= 1;
  }
#undef STG_A
#undef STG_B
#undef STG_HALF

  int rowb = bm + wm*(AM*64) + l16;
  int colb = bn + wn*64 + (g16 << 2);
  #pragma unroll
  for (int mf = 0; mf < AM*4; ++mf) {
    int row = rowb + mf*16;
    #pragma unroll
    for (int nf = 0; nf < 4; ++nf) {
      int col0 = colb + nf*16;
      f32x4 v = acc[mf][nf];
      if (mode == 6) {
        if (col0 >= 768) {
          float4 b4 = *(const float4*)(bias + col0 - 768);
          v[0] = 1.0f/(1.0f+__expf(-(v[0]+b4.x)));
          v[1] = 1.0f/(1.0f+__expf(-(v[1]+b4.y)));
          v[2] = 1.0f/(1.0f+__expf(-(v[2]+b4.z)));
          v[3] = 1.0f/(1.0f+__expf(-(v[3]+b4.w)));
        }
        uint2 o; o.x = cvt_pk(v[0], v[1]); o.y = cvt_pk(v[2], v[3]);
        *(uint2*)((u16*)Cout + (size_t)row*N + col0) = o;
      } else if (mode == 3) {
        float4 b4 = *(const float4*)(bias + col0);
        uint2 o;
        o.x = cvt_pk(fmaxf(v[0]+b4.x, 0.f), fmaxf(v[1]+b4.y, 0.f));
        o.y = cvt_pk(fmaxf(v[2]+b4.z, 0.f), fmaxf(v[3]+b4.w, 0.f));
        *(uint2*)((u16*)Cout + (size_t)row*N + col0) = o;
      } else if (mode == 4) {
        size_t i2 = (size_t)row*N + col0;
        float4 r4 = *(const float4*)(res + i2);
        float4 b4 = *(const float4*)(bias + col0);
        float4 o = make_float4(v[0]+r4.x+b4.x, v[1]+r4.y+b4.y,
                               v[2]+r4.z+b4.z, v[3]+r4.w+b4.w);
        *(float4*)((float*)Cout + i2) = o;
      } else if (mode == 5) {
        int rr = row >> 7, ss = row & 127;
        size_t i2 = ((size_t)ss*R + rr)*(size_t)N + col0;
        float4 r4 = *(const float4*)(res + i2);
        float4 b4 = *(const float4*)(bias + col0);
        float4 o = make_float4(v[0]+r4.x+b4.x, v[1]+r4.y+b4.y,
                               v[2]+r4.z+b4.z, v[3]+r4.w+b4.w);
        *(float4*)((float*)Cout + i2) = o;
      } else if (mode == 2) {
        float4 b4 = *(const float4*)(bias + col0);
        uint2 o;
        o.x = cvt_pk(1.0f/(1.0f+__expf(-(v[0]+b4.x))),
                     1.0f/(1.0f+__expf(-(v[1]+b4.y))));
        o.y = cvt_pk(1.0f/(1.0f+__expf(-(v[2]+b4.z))),
                     1.0f/(1.0f+__expf(-(v[3]+b4.w))));
        *(uint2*)((u16*)Cout + (size_t)row*N + col0) = o;
      } else {
        uint2 o; o.x = cvt_pk(v[0], v[1]); o.y = cvt_pk(v[2], v[3]);
        *(uint2*)((u16*)Cout + (size_t)row*N + col0) = o;
      }
    }
  }
}

// ---------------- MFMA attention, 32x32 shape, in-register P (cvt_pk + permlane32_swap) ----
// QKVG: [b-panel rows][1024] bf16, Q +0, K +256, V +512, G +768 (Q pre-scaled qs*log2e).
// QK^T: mfma_32x32x16(A=K, B=Q) -> P[key][q], lane: col q = lane&31,
//   row key = (reg&3) + 8*(reg>>2) + 4*(lane>>5).
// PV: mfma_32x32x16(A=V^T, B=P). B-frag built in-register via cvt_pk + permlane32_swap.
// HPB = heads per block (row: 1 head x 8 q-tiles; col: 2 heads x 4 q-tiles).
template<int NKEY, int HPB, bool ROWMODE>
__global__ __launch_bounds__(512, 4) void attn_mfma(
    const u16* __restrict__ QKVG, const u16* __restrict__ bias,
    const float* __restrict__ mask, u16* __restrict__ og)
{
  __shared__ __align__(16) u16 Vt[HPB][32][NKEY + 8];
  __shared__ float lmb[NKEY];
  constexpr int NKV = NKEY / 32;
  int b = blockIdx.y;
  int t = threadIdx.x, lane = t & 63, w = t >> 6;
  int c31 = lane & 31, hi = lane >> 5;

  int lh = (HPB == 2) ? (w >> 2) : 0;
  int hh = blockIdx.x * HPB + lh;
  int q0 = ((HPB == 2) ? (w & 3) : w) * 32;

  size_t base1 = (size_t)b * NKEY * 1024 + (size_t)hh * 32;
  const u16* Qp = QKVG + base1;
  const u16* Kp = QKVG + base1 + 256;
  const u16* Gp = QKVG + base1 + 768;

  // ---- stage V transposed ----
  if (HPB == 1) {
    int key = t & 255, ch0 = (t >> 8) * 16;
    const u16* Vps = QKVG + (size_t)b*NKEY*1024 + (size_t)blockIdx.x*32 + 512;
    #pragma unroll
    for (int c0 = 0; c0 < 16; c0 += 8) {
      bf16x8 v8 = *(const bf16x8*)(Vps + (size_t)key*1024 + ch0 + c0);
      #pragma unroll
      for (int j = 0; j < 8; ++j) Vt[0][ch0+c0+j][key] = (u16)v8[j];
    }
  } else {
    int sh = t >> 8, tt = t & 255;
    int key = tt & 127, ch0 = (tt >> 7) * 16;
    const u16* Vps = QKVG + (size_t)b*NKEY*1024 + (size_t)(blockIdx.x*2+sh)*32 + 512;
    #pragma unroll
    for (int c0 = 0; c0 < 16; c0 += 8) {
      bf16x8 v8 = *(const bf16x8*)(Vps + (size_t)key*1024 + ch0 + c0);
      #pragma unroll
      for (int j = 0; j < 8; ++j) Vt[sh][ch0+c0+j][key] = (u16)v8[j];
    }
  }
  for (int i = t; i < NKEY; i += 512)
    lmb[i] = 1.4426950e9f * ((ROWMODE ? mask[b*R + i] : mask[i*R + b]) - 1.0f);
  __syncthreads();

  int q = q0 + c31;
  bf16x8 qf0 = *(const bf16x8*)(Qp + (size_t)q*1024 + hi*8);
  bf16x8 qf1 = *(const bf16x8*)(Qp + (size_t)q*1024 + 16 + hi*8);

  f32x16 oacc = (f32x16)(0.0f);
  float lsum = 0.f;
  const u16* bias_q = bias + (size_t)hh*NPAIR + (size_t)q*R;

  #pragma unroll 2
  for (int g = 0; g < NKV; ++g) {
    int kb = g * 32;
    const u16* krow = Kp + (size_t)(kb + c31)*1024 + hi*8;
    bf16x8 ka0 = *(const bf16x8*)(krow);
    bf16x8 ka1 = *(const bf16x8*)(krow + 16);
    __builtin_amdgcn_s_setprio(1);
    f32x16 sac = __builtin_amdgcn_mfma_f32_32x32x16_bf16(ka0, qf0, (f32x16)(0.0f), 0, 0, 0);
    sac = __builtin_amdgcn_mfma_f32_32x32x16_bf16(ka1, qf1, sac, 0, 0, 0);
    __builtin_amdgcn_s_setprio(0);
    float p[16];
    #pragma unroll
    for (int rq = 0; rq < 4; ++rq) {
      int k0 = kb + 8*rq + 4*hi;
      float4 lm4 = *(const float4*)&lmb[k0];
      float b0 = lm4.x, b1 = lm4.y, b2 = lm4.z, b3 = lm4.w;
      if (ROWMODE) {
        ushort4 b4 = *(const ushort4*)(bias_q + k0);
        b0 += bf2f(b4.x); b1 += bf2f(b4.y); b2 += bf2f(b4.z); b3 += bf2f(b4.w);
      }
      p[4*rq+0] = exp2f(sac[4*rq+0] + b0);
      p[4*rq+1] = exp2f(sac[4*rq+1] + b1);
      p[4*rq+2] = exp2f(sac[4*rq+2] + b2);
      p[4*rq+3] = exp2f(sac[4*rq+3] + b3);
      lsum += (p[4*rq+0] + p[4*rq+1]) + (p[4*rq+2] + p[4*rq+3]);
    }
    unsigned u0 = cvt_pk(p[0],  p[1]),  u1 = cvt_pk(p[2],  p[3]);
    unsigned u2 = cvt_pk(p[4],  p[5]),  u3 = cvt_pk(p[6],  p[7]);
    unsigned u4 = cvt_pk(p[8],  p[9]),  u5 = cvt_pk(p[10], p[11]);
    unsigned u6 = cvt_pk(p[12], p[13]), u7 = cvt_pk(p[14], p[15]);
    pl32swap(u0, u2); pl32swap(u1, u3);
    pl32swap(u4, u6); pl32swap(u5, u7);
    bf16x8 pf0 = mk_frag(u0, u1, u2, u3);   // keys kb+0..15
    bf16x8 pf1 = mk_frag(u4, u5, u6, u7);   // keys kb+16..31
    bf16x8 va0 = *(const bf16x8*)&Vt[lh][c31][kb + hi*8];
    bf16x8 va1 = *(const bf16x8*)&Vt[lh][c31][kb + 16 + hi*8];
    __builtin_amdgcn_s_setprio(1);
    oacc = __builtin_amdgcn_mfma_f32_32x32x16_bf16(va0, pf0, oacc, 0, 0, 0);
    oacc = __builtin_amdgcn_mfma_f32_32x32x16_bf16(va1, pf1, oacc, 0, 0, 0);
    __builtin_amdgcn_s_setprio(0);
  }
  lsum += __shfl_xor(lsum, 32);
  float inv = 1.0f / lsum;

  size_t baseO = (size_t)b * NKEY * 256 + (size_t)hh * 32;
  u16* op = og + baseO + (size_t)q * 256;
  const u16* gp = Gp + (size_t)q * 1024;
  #pragma unroll
  for (int rq = 0; rq < 4; ++rq) {
    int c0 = 8*rq + 4*hi;
    ushort4 g4 = *(const ushort4*)(gp + c0);
    float f0 = oacc[4*rq+0] * inv * bf2f(g4.x);
    float f1 = oacc[4*rq+1] * inv * bf2f(g4.y);
    float f2 = oacc[4*rq+2] * inv * bf2f(g4.z);
    float f3 = oacc[4*rq+3] * inv * bf2f(g4.w);
    uint2 o2; o2.x = cvt_pk(f0, f1); o2.y = cvt_pk(f2, f3);
    *(uint2*)(op + c0) = o2;
  }
}

extern "C" void kernel_launch(void* const* d_in, const int* in_sizes, int n_in,
                              void* d_out, int out_size, void* d_ws, size_t ws_size,
                              hipStream_t stream)
{
  const float* node         = (const float*)d_in[0];
  const float* pair         = (const float*)d_in[1];
  const float* node_mask    = (const float*)d_in[2];
  const float* row_ln_m_g   = (const float*)d_in[3];
  const float* row_ln_m_b   = (const float*)d_in[4];
  const float* row_ln_z_g   = (const float*)d_in[5];
  const float* row_ln_z_b   = (const float*)d_in[6];
  const float* row_b_w      = (const float*)d_in[7];
  const float* row_wq       = (const float*)d_in[8];
  const float* row_wk       = (const float*)d_in[9];
  const float* row_wv       = (const float*)d_in[10];
  const float* row_wg       = (const float*)d_in[11];
  const float* row_bg       = (const float*)d_in[12];
  const float* row_wo       = (const float*)d_in[13];
  const float* row_out_bias = (const float*)d_in[14];
  const float* col_ln_g     = (const float*)d_in[15];
  const float* col_ln_b     = (const float*)d_in[16];
  const float* col_wq       = (const float*)d_in[17];
  const float* col_wk       = (const float*)d_in[18];
  const float* col_wv       = (const float*)d_in[19];
  const float* col_wg       = (const float*)d_in[20];
  const float* col_bg       = (const float*)d_in[21];
  const float* col_wo       = (const float*)d_in[22];
  const float* col_bo       = (const float*)d_in[23];
  const float* tr_ln_g      = (const float*)d_in[24];
  const float* tr_ln_b      = (const float*)d_in[25];
  const float* tr_w1        = (const float*)d_in[26];
  const float* tr_b1        = (const float*)d_in[27];
  const float* tr_w2        = (const float*)d_in[28];
  const float* tr_b2        = (const float*)d_in[29];

  float* out = (float*)d_out;
  char* ws8 = (char*)d_ws;
  const size_t MB = 1ull << 20;
  u16*   A     = (u16*)(ws8);               // 16 MB  LN out [32768][256] bf16
  u16*   QKVG  = (u16*)(ws8 + 16*MB);       // 64 MB  [32768][1024] bf16 (also T1)
  u16*   Ob    = (u16*)(ws8 + 80*MB);       // 16 MB  gated attn out bf16
  u16*   Dbias = (u16*)(ws8 + 96*MB);       // 1 MB   [H][R][R] bf16 (log2e-scaled)
  u16*   Wb    = (u16*)(ws8 + 100*MB);      // bf16 weight arena
  u16*   T1    = QKVG;

  const float qs = 0.17677669529663687f;    // 1/sqrt(32)

  u16* Wrqkvg = Wb + 0;
  u16* Wro    = Wb + 262144;
  u16* Wcqkvg = Wb + 327680;
  u16* Wco    = Wb + 589824;
  u16* W1     = Wb + 655360;
  u16* W2     = Wb + 917504;

  CvtArgs ca;
  const float* srcs[12] = {row_wq,row_wk,row_wv,row_wg,row_wo,
                           col_wq,col_wk,col_wv,col_wg,col_wo,tr_w1,tr_w2};
  int offs[12] = {0,65536,131072,196608,262144,327680,393216,458752,524288,589824,655360,917504};
  int ns[12]   = {65536,65536,65536,65536,65536,65536,65536,65536,65536,65536,262144,262144};
  for (int i = 0; i < 12; ++i) {
    ca.src[i] = srcs[i]; ca.off[i] = offs[i]; ca.n[i] = ns[i];
    ca.scale[i] = (i == 0 || i == 5) ? qs * LOG2E : 1.0f;
  }
  cvt_w_kernel<<<dim3(256,12), 256, 0, stream>>>(ca, Wb);

  dim3 gq(4, 128);     // AM=2: 256x256 tiles, N=1024
  dim3 go(1, 256);     // AM=1: 128x256 tiles, N=256 (full-GPU grid)

  // --- row attention ---
  ln256_kernel<<<8192, 256, 0, stream>>>(node, A, row_ln_m_g, row_ln_m_b, 0);
  pair_bias_kernel<<<16384, 256, 0, stream>>>(pair, row_ln_z_g, row_ln_z_b, row_b_w, Dbias);
  gemm_8ph<2><<<gq, 512, 0, stream>>>(A, Wrqkvg, QKVG, 1024, 256, 6, row_bg, nullptr);
  attn_mfma<256,1,true><<<dim3(8,128), 512, 0, stream>>>(QKVG, Dbias, node_mask, Ob);
  gemm_8ph<1><<<go, 512, 0, stream>>>(Ob, Wro, out, 256, 256, 4, row_out_bias, node);

  // --- column attention (in [r,s,d] layout) ---
  ln256_kernel<<<8192, 256, 0, stream>>>(out, A, col_ln_g, col_ln_b, 1);
  gemm_8ph<2><<<gq, 512, 0, stream>>>(A, Wcqkvg, QKVG, 1024, 256, 6, col_bg, nullptr);
  attn_mfma<128,2,false><<<dim3(4,256), 512, 0, stream>>>(QKVG, Dbias, node_mask, Ob);
  gemm_8ph<1><<<go, 512, 0, stream>>>(Ob, Wco, out, 256, 256, 5, col_bo, out);

  // --- transition ---
  ln256_kernel<<<8192, 256, 0, stream>>>(out, A, tr_ln_g, tr_ln_b, 0);
  gemm_8ph<2><<<gq, 512, 0, stream>>>(A, W1, T1, 1024, 256, 3, tr_b1, nullptr);
  gemm_8ph<1><<<go, 512, 0, stream>>>(T1, W2, out, 256, 1024, 4, tr_b2, out);
}

// Round 10
// 368.037 us; speedup vs baseline: 4.4997x; 1.0278x over previous
//
#include <hip/hip_runtime.h>
#include <math.h>

#define S 128
#define R 256
#define DMODEL 256
#define H 8
#define CDIM 32
#define HC 256
#define DFF 1024
#define NROWS (S*R)     // 32768
#define NPAIR (R*R)     // 65536
#define LN_EPS 1e-5f
#define LOG2E 1.4426950408889634f

typedef unsigned short u16;
typedef __attribute__((ext_vector_type(8))) short bf16x8;
typedef __attribute__((ext_vector_type(4))) float f32x4;
typedef __attribute__((ext_vector_type(16))) float f32x16;

__device__ __forceinline__ u16 f2bf(float x) {
  unsigned u = __float_as_uint(x);
  u = (u + 0x7fffu + ((u >> 16) & 1u)) >> 16;
  return (u16)u;
}
__device__ __forceinline__ float bf2f(u16 x) {
  return __uint_as_float(((unsigned)x) << 16);
}
// pack 2 f32 -> 2 bf16 in one u32 (lo = a, hi = b), RNE
__device__ __forceinline__ unsigned cvt_pk(float a, float b) {
  unsigned r;
  asm("v_cvt_pk_bf16_f32 %0, %1, %2" : "=v"(r) : "v"(a), "v"(b));
  return r;
}
// swap a[32:63] <-> b[0:31]
__device__ __forceinline__ void pl32swap(unsigned &a, unsigned &b) {
  asm("v_permlane32_swap_b32 %0, %1" : "+v"(a), "+v"(b));
}
__device__ __forceinline__ bf16x8 mk_frag(unsigned a, unsigned b, unsigned c, unsigned d) {
  uint4 t = make_uint4(a, b, c, d);
  return __builtin_bit_cast(bf16x8, t);
}

__device__ __forceinline__ void gload_lds16(const u16* g, u16* l) {
  __builtin_amdgcn_global_load_lds(
      (const __attribute__((address_space(1))) unsigned int*)g,
      (__attribute__((address_space(3))) unsigned int*)l, 16, 0, 0);
}

// ---------------- weight f32 -> bf16 conversion (12 segments) ----------------
struct CvtArgs {
  const float* src[12];
  int off[12];
  int n[12];
  float scale[12];
};

__global__ __launch_bounds__(256) void cvt_w_kernel(CvtArgs a, u16* __restrict__ dst) {
  int sg = blockIdx.y;
  int i = (blockIdx.x * 256 + threadIdx.x) * 4;
  if (i >= a.n[sg]) return;
  float4 v = *(const float4*)(a.src[sg] + i);
  float sc = a.scale[sg];
  uint2 o;
  o.x = cvt_pk(v.x * sc, v.y * sc);
  o.y = cvt_pk(v.z * sc, v.w * sc);
  *(uint2*)(dst + a.off[sg] + i) = o;
}

// ---------------- LayerNorm over 256, one row per wave, bf16 out ----------------
__global__ __launch_bounds__(256) void ln256_kernel(
    const float* __restrict__ in, u16* __restrict__ out,
    const float* __restrict__ gamma, const float* __restrict__ beta,
    int tmode)
{
  int wid = threadIdx.x >> 6, lane = threadIdx.x & 63;
  int m = blockIdx.x * 4 + wid;
  int inrow = m;
  if (tmode) { int r = m >> 7, s = m & 127; inrow = s * R + r; }
  float4 x = *(const float4*)(in + (size_t)inrow * DMODEL + lane * 4);
  float sum = x.x + x.y + x.z + x.w;
  float sq  = x.x*x.x + x.y*x.y + x.z*x.z + x.w*x.w;
  #pragma unroll
  for (int off = 32; off; off >>= 1) {
    sum += __shfl_xor(sum, off);
    sq  += __shfl_xor(sq, off);
  }
  float mean = sum * (1.0f/256.0f);
  float var  = sq  * (1.0f/256.0f) - mean*mean;
  float rstd = rsqrtf(var + LN_EPS);
  float4 g = *(const float4*)(gamma + lane*4);
  float4 b = *(const float4*)(beta  + lane*4);
  uint2 o;
  o.x = cvt_pk((x.x-mean)*rstd*g.x + b.x, (x.y-mean)*rstd*g.y + b.y);
  o.y = cvt_pk((x.z-mean)*rstd*g.z + b.z, (x.w-mean)*rstd*g.w + b.w);
  *(uint2*)(out + (size_t)m * DMODEL + lane*4) = o;
}

// ------- pair LN (over 128) + bias projection -> bias[h][q][k] (bf16, *log2e) -------
__global__ __launch_bounds__(256) void pair_bias_kernel(
    const float* __restrict__ pair, const float* __restrict__ gamma,
    const float* __restrict__ beta, const float* __restrict__ bw,
    u16* __restrict__ bias)
{
  int wid = threadIdx.x >> 6, lane = threadIdx.x & 63;
  int p = blockIdx.x * 4 + wid;
  float2 x = *(const float2*)(pair + (size_t)p * 128 + lane*2);
  float sum = x.x + x.y, sq = x.x*x.x + x.y*x.y;
  #pragma unroll
  for (int off = 32; off; off >>= 1) {
    sum += __shfl_xor(sum, off);
    sq  += __shfl_xor(sq, off);
  }
  float mean = sum * (1.0f/128.0f);
  float rstd = rsqrtf(sq*(1.0f/128.0f) - mean*mean + LN_EPS);
  float z0 = (x.x-mean)*rstd*gamma[lane*2]   + beta[lane*2];
  float z1 = (x.y-mean)*rstd*gamma[lane*2+1] + beta[lane*2+1];
  float a0 = z0*bw[0*128+lane*2] + z1*bw[0*128+lane*2+1];
  float a1 = z0*bw[1*128+lane*2] + z1*bw[1*128+lane*2+1];
  float a2 = z0*bw[2*128+lane*2] + z1*bw[2*128+lane*2+1];
  float a3 = z0*bw[3*128+lane*2] + z1*bw[3*128+lane*2+1];
  float a4 = z0*bw[4*128+lane*2] + z1*bw[4*128+lane*2+1];
  float a5 = z0*bw[5*128+lane*2] + z1*bw[5*128+lane*2+1];
  float a6 = z0*bw[6*128+lane*2] + z1*bw[6*128+lane*2+1];
  float a7 = z0*bw[7*128+lane*2] + z1*bw[7*128+lane*2+1];
  #pragma unroll
  for (int off = 32; off; off >>= 1) {
    a0 += __shfl_xor(a0, off); a1 += __shfl_xor(a1, off);
    a2 += __shfl_xor(a2, off); a3 += __shfl_xor(a3, off);
    a4 += __shfl_xor(a4, off); a5 += __shfl_xor(a5, off);
    a6 += __shfl_xor(a6, off); a7 += __shfl_xor(a7, off);
  }
  float v = a0;
  v = (lane==1)?a1:v; v = (lane==2)?a2:v; v = (lane==3)?a3:v;
  v = (lane==4)?a4:v; v = (lane==5)?a5:v; v = (lane==6)?a6:v; v = (lane==7)?a7:v;
  if (lane < 8) bias[(size_t)lane*NPAIR + p] = f2bf(v * LOG2E);
}

// ---------------- bf16 MFMA NT GEMM, (AM*128)x256 tile, BK=64, counted-vmcnt ----------------
// C[M,N] = A[M,K] * W[N,K]^T.  512 threads = 8 waves (2M x 4N).
// AM = A half-tiles (2 -> BM=256, 1 -> BM=128 for N=256 GEMMs / full-GPU grids).
// modes: 1: bf16  2: bf16 sigmoid(x+bias)  3: bf16 relu(x+bias)
//        4: f32 x+res+bias   5: f32 transposed idx   6: bf16, cols>=768 sigmoid(+bias)
template<int AM>
__global__ __launch_bounds__(512, 2) void gemm_8ph(
    const u16* __restrict__ A, const u16* __restrict__ W,
    void* __restrict__ Cout, int N, int K,
    int mode, const float* __restrict__ bias, const float* __restrict__ res)
{
  __shared__ u16 lds[2][AM+2][128*64];
  int t = threadIdx.x, lane = t & 63, wv = t >> 6;
  int g16 = (lane >> 4) & 3, l16 = lane & 15;
  int wm = wv >> 2, wn = wv & 3;
  int lrow = lane >> 3, lchunk = lane & 7;

  // bijective XCD swizzle (nwg % 8 == 0 for all our grids)
  int gx = gridDim.x;
  int nwg = gx * gridDim.y;
  int p = blockIdx.y * gx + blockIdx.x;
  int cpx = nwg >> 3;
  int lg = (p & 7) * cpx + (p >> 3);
  int bn = (lg % gx) * 256;
  int bm = (lg / gx) * (AM * 128);

  int srcc = (lchunk ^ lrow) << 3;          // pre-swizzled global k-chunk
  int ch0  = (g16 ^ (l16 & 7)) << 3;        // swizzled LDS read chunk (k32=0)
  int rdoff = l16 * 64 + ch0;               // k32=1 -> rdoff ^ 32
  const int wnh = AM + (wn >> 1);
  const int wnr = (wn & 1) * 4096;

  f32x4 acc[AM*4][4];
  #pragma unroll
  for (int i = 0; i < AM*4; ++i)
    #pragma unroll
    for (int j = 0; j < 4; ++j) acc[i][j] = (f32x4){0.f,0.f,0.f,0.f};

  const int nkt = K >> 6;

#define STG_HALF(buf_, h_, base_, row0_, kc_) do { \
    gload_lds16(base_ + (size_t)((row0_) + (wv*2+0)*8 + lrow) * K + (kc_) + srcc, \
                &lds[buf_][h_][(wv*2+0)*512 + lane*8]); \
    gload_lds16(base_ + (size_t)((row0_) + (wv*2+1)*8 + lrow) * K + (kc_) + srcc, \
                &lds[buf_][h_][(wv*2+1)*512 + lane*8]); \
  } while(0)
#define STG_A(buf_, kc_) do { STG_HALF(buf_,0,A,bm,kc_); \
    if (AM==2) STG_HALF(buf_,1,A,bm+128,kc_); } while(0)
#define STG_B(buf_, kc_) do { STG_HALF(buf_,AM,W,bn,kc_); STG_HALF(buf_,AM+1,W,bn+128,kc_); } while(0)

  int buf = 0;
  STG_A(0, 0); STG_B(0, 0);
  for (int kt = 0; kt < nkt; ++kt) {
    int kc = kt << 6;
    if (kt + 1 < nkt) {
      STG_A(buf^1, kc + 64);                // issue-early next A
      if (AM == 2) asm volatile("s_waitcnt vmcnt(4)" ::: "memory");
      else         asm volatile("s_waitcnt vmcnt(2)" ::: "memory");
    } else {
      asm volatile("s_waitcnt vmcnt(0)" ::: "memory");
    }
    __builtin_amdgcn_s_barrier();
    asm volatile("" ::: "memory");
    if (kt + 1 < nkt) STG_B(buf^1, kc + 64);

    const u16* Abase = (AM==2) ? &lds[buf][wm][0] : &lds[buf][0][wm*4096];
    const u16* Wbase = &lds[buf][wnh][wnr];
    bf16x8 wf[4][2];
    #pragma unroll
    for (int nf = 0; nf < 4; ++nf) {
      wf[nf][0] = *(const bf16x8*)(Wbase + nf*1024 + rdoff);
      wf[nf][1] = *(const bf16x8*)(Wbase + nf*1024 + (rdoff ^ 32));
    }
    __builtin_amdgcn_s_setprio(1);
    #pragma unroll
    for (int mf = 0; mf < AM*4; ++mf) {
      bf16x8 a0 = *(const bf16x8*)(Abase + mf*1024 + rdoff);
      bf16x8 a1 = *(const bf16x8*)(Abase + mf*1024 + (rdoff ^ 32));
      #pragma unroll
      for (int nf = 0; nf < 4; ++nf) {
        acc[mf][nf] = __builtin_amdgcn_mfma_f32_16x16x32_bf16(wf[nf][0], a0, acc[mf][nf], 0, 0, 0);
        acc[mf][nf] = __builtin_amdgcn_mfma_f32_16x16x32_bf16(wf[nf][1], a1, acc[mf][nf], 0, 0, 0);
      }
    }
    __builtin_amdgcn_s_setprio(0);
    asm volatile("" ::: "memory");
    __builtin_amdgcn_s_barrier();
    buf ^= 1;
  }
#undef STG_A
#undef STG_B
#undef STG_HALF

  int rowb = bm + wm*(AM*64) + l16;
  int colb = bn + wn*64 + (g16 << 2);
  #pragma unroll
  for (int mf = 0; mf < AM*4; ++mf) {
    int row = rowb + mf*16;
    #pragma unroll
    for (int nf = 0; nf < 4; ++nf) {
      int col0 = colb + nf*16;
      f32x4 v = acc[mf][nf];
      if (mode == 6) {
        if (col0 >= 768) {
          float4 b4 = *(const float4*)(bias + col0 - 768);
          v[0] = 1.0f/(1.0f+__expf(-(v[0]+b4.x)));
          v[1] = 1.0f/(1.0f+__expf(-(v[1]+b4.y)));
          v[2] = 1.0f/(1.0f+__expf(-(v[2]+b4.z)));
          v[3] = 1.0f/(1.0f+__expf(-(v[3]+b4.w)));
        }
        uint2 o; o.x = cvt_pk(v[0], v[1]); o.y = cvt_pk(v[2], v[3]);
        *(uint2*)((u16*)Cout + (size_t)row*N + col0) = o;
      } else if (mode == 3) {
        float4 b4 = *(const float4*)(bias + col0);
        uint2 o;
        o.x = cvt_pk(fmaxf(v[0]+b4.x, 0.f), fmaxf(v[1]+b4.y, 0.f));
        o.y = cvt_pk(fmaxf(v[2]+b4.z, 0.f), fmaxf(v[3]+b4.w, 0.f));
        *(uint2*)((u16*)Cout + (size_t)row*N + col0) = o;
      } else if (mode == 4) {
        size_t i2 = (size_t)row*N + col0;
        float4 r4 = *(const float4*)(res + i2);
        float4 b4 = *(const float4*)(bias + col0);
        float4 o = make_float4(v[0]+r4.x+b4.x, v[1]+r4.y+b4.y,
                               v[2]+r4.z+b4.z, v[3]+r4.w+b4.w);
        *(float4*)((float*)Cout + i2) = o;
      } else if (mode == 5) {
        int rr = row >> 7, ss = row & 127;
        size_t i2 = ((size_t)ss*R + rr)*(size_t)N + col0;
        float4 r4 = *(const float4*)(res + i2);
        float4 b4 = *(const float4*)(bias + col0);
        float4 o = make_float4(v[0]+r4.x+b4.x, v[1]+r4.y+b4.y,
                               v[2]+r4.z+b4.z, v[3]+r4.w+b4.w);
        *(float4*)((float*)Cout + i2) = o;
      } else if (mode == 2) {
        float4 b4 = *(const float4*)(bias + col0);
        uint2 o;
        o.x = cvt_pk(1.0f/(1.0f+__expf(-(v[0]+b4.x))),
                     1.0f/(1.0f+__expf(-(v[1]+b4.y))));
        o.y = cvt_pk(1.0f/(1.0f+__expf(-(v[2]+b4.z))),
                     1.0f/(1.0f+__expf(-(v[3]+b4.w))));
        *(uint2*)((u16*)Cout + (size_t)row*N + col0) = o;
      } else {
        uint2 o; o.x = cvt_pk(v[0], v[1]); o.y = cvt_pk(v[2], v[3]);
        *(uint2*)((u16*)Cout + (size_t)row*N + col0) = o;
      }
    }
  }
}

// ---- softmax + pack one 32-key group's P (for one 32-q tile) into PV B-frags ----
template<bool RM>
__device__ __forceinline__ void softmax_pack(
    const f32x16 &sac, const float* __restrict__ lmbp,
    const u16* __restrict__ bias_q, int kb, int hi,
    float &lsum, bf16x8 &pf0, bf16x8 &pf1)
{
  float p[16];
  #pragma unroll
  for (int rq = 0; rq < 4; ++rq) {
    int k0 = kb + 8*rq + 4*hi;
    float4 lm4 = *(const float4*)&lmbp[k0];
    float b0 = lm4.x, b1 = lm4.y, b2 = lm4.z, b3 = lm4.w;
    if (RM) {
      ushort4 b4 = *(const ushort4*)(bias_q + k0);
      b0 += bf2f(b4.x); b1 += bf2f(b4.y); b2 += bf2f(b4.z); b3 += bf2f(b4.w);
    }
    p[4*rq+0] = exp2f(sac[4*rq+0] + b0);
    p[4*rq+1] = exp2f(sac[4*rq+1] + b1);
    p[4*rq+2] = exp2f(sac[4*rq+2] + b2);
    p[4*rq+3] = exp2f(sac[4*rq+3] + b3);
    lsum += (p[4*rq+0] + p[4*rq+1]) + (p[4*rq+2] + p[4*rq+3]);
  }
  unsigned u0 = cvt_pk(p[0],  p[1]),  u1 = cvt_pk(p[2],  p[3]);
  unsigned u2 = cvt_pk(p[4],  p[5]),  u3 = cvt_pk(p[6],  p[7]);
  unsigned u4 = cvt_pk(p[8],  p[9]),  u5 = cvt_pk(p[10], p[11]);
  unsigned u6 = cvt_pk(p[12], p[13]), u7 = cvt_pk(p[14], p[15]);
  pl32swap(u0, u2); pl32swap(u1, u3);
  pl32swap(u4, u6); pl32swap(u5, u7);
  pf0 = mk_frag(u0, u1, u2, u3);
  pf1 = mk_frag(u4, u5, u6, u7);
}

// ---------------- MFMA attention, 32x32, in-register P, MT=2 tiles/wave, K-prefetch ----
// QKVG: [b-panel rows][1024] bf16, Q +0, K +256, V +512, G +768 (Q pre-scaled qs*log2e).
// HPB heads per block; 8/HPB waves per head; each wave owns 2 q-tiles (64 q).
template<int NKEY, int HPB, bool ROWMODE>
__global__ __launch_bounds__(512, 2) void attn_mfma(
    const u16* __restrict__ QKVG, const u16* __restrict__ bias,
    const float* __restrict__ mask, u16* __restrict__ og)
{
  __shared__ __align__(16) u16 Vt[HPB][32][NKEY + 8];
  __shared__ float lmb[NKEY];
  constexpr int NKV = NKEY / 32;
  constexpr int WPH = 8 / HPB;
  int b = blockIdx.y;
  int t = threadIdx.x, lane = t & 63, w = t >> 6;
  int c31 = lane & 31, hi = lane >> 5;
  int lh = w / WPH, wtile = w % WPH;
  int hh = blockIdx.x * HPB + lh;

  size_t bigbase = (size_t)b * NKEY * 1024;
  const u16* Qp = QKVG + bigbase + (size_t)hh*32;
  const u16* Kp = Qp + 256;
  const u16* Gp = Qp + 768;

  // ---- stage V transposed (all HPB heads) ----
  for (int i = t; i < HPB*NKEY*4; i += 512) {
    int c0 = (i & 3) * 8;
    int key = (i >> 2) & (NKEY - 1);
    int sh = (i >> 2) / NKEY;
    const u16* Vs = QKVG + bigbase + (size_t)(blockIdx.x*HPB + sh)*32 + 512;
    bf16x8 v8 = *(const bf16x8*)(Vs + (size_t)key*1024 + c0);
    #pragma unroll
    for (int j = 0; j < 8; ++j) Vt[sh][c0+j][key] = (u16)v8[j];
  }
  for (int i = t; i < NKEY; i += 512)
    lmb[i] = 1.4426950e9f * ((ROWMODE ? mask[b*R + i] : mask[i*R + b]) - 1.0f);
  __syncthreads();

  int qA = wtile*64 + c31, qB = qA + 32;
  bf16x8 qfA0 = *(const bf16x8*)(Qp + (size_t)qA*1024 + hi*8);
  bf16x8 qfA1 = *(const bf16x8*)(Qp + (size_t)qA*1024 + 16 + hi*8);
  bf16x8 qfB0 = *(const bf16x8*)(Qp + (size_t)qB*1024 + hi*8);
  bf16x8 qfB1 = *(const bf16x8*)(Qp + (size_t)qB*1024 + 16 + hi*8);

  f32x16 oA = (f32x16)(0.0f), oB = (f32x16)(0.0f);
  float lsA = 0.f, lsB = 0.f;
  const u16* biasA = bias + (size_t)hh*NPAIR + (size_t)qA*R;
  const u16* biasB = biasA + (size_t)32*R;

  // prefetch group 0's K fragments
  const u16* kr0 = Kp + (size_t)c31*1024 + hi*8;
  bf16x8 nk0 = *(const bf16x8*)kr0;
  bf16x8 nk1 = *(const bf16x8*)(kr0 + 16);

  for (int g = 0; g < NKV; ++g) {
    int kb = g * 32;
    bf16x8 k0 = nk0, k1 = nk1;
    if (g + 1 < NKV) {
      const u16* kr = Kp + (size_t)(kb + 32 + c31)*1024 + hi*8;
      nk0 = *(const bf16x8*)kr;
      nk1 = *(const bf16x8*)(kr + 16);
    }
    __builtin_amdgcn_s_setprio(1);
    f32x16 sacA = __builtin_amdgcn_mfma_f32_32x32x16_bf16(k0, qfA0, (f32x16)(0.0f), 0, 0, 0);
    sacA = __builtin_amdgcn_mfma_f32_32x32x16_bf16(k1, qfA1, sacA, 0, 0, 0);
    f32x16 sacB = __builtin_amdgcn_mfma_f32_32x32x16_bf16(k0, qfB0, (f32x16)(0.0f), 0, 0, 0);
    sacB = __builtin_amdgcn_mfma_f32_32x32x16_bf16(k1, qfB1, sacB, 0, 0, 0);
    __builtin_amdgcn_s_setprio(0);
    bf16x8 va0 = *(const bf16x8*)&Vt[lh][c31][kb + hi*8];
    bf16x8 va1 = *(const bf16x8*)&Vt[lh][c31][kb + 16 + hi*8];
    bf16x8 pfA0, pfA1, pfB0, pfB1;
    softmax_pack<ROWMODE>(sacA, lmb, biasA, kb, hi, lsA, pfA0, pfA1);
    softmax_pack<ROWMODE>(sacB, lmb, biasB, kb, hi, lsB, pfB0, pfB1);
    __builtin_amdgcn_s_setprio(1);
    oA = __builtin_amdgcn_mfma_f32_32x32x16_bf16(va0, pfA0, oA, 0, 0, 0);
    oA = __builtin_amdgcn_mfma_f32_32x32x16_bf16(va1, pfA1, oA, 0, 0, 0);
    oB = __builtin_amdgcn_mfma_f32_32x32x16_bf16(va0, pfB0, oB, 0, 0, 0);
    oB = __builtin_amdgcn_mfma_f32_32x32x16_bf16(va1, pfB1, oB, 0, 0, 0);
    __builtin_amdgcn_s_setprio(0);
  }
  lsA += __shfl_xor(lsA, 32);
  lsB += __shfl_xor(lsB, 32);
  float invA = 1.0f / lsA, invB = 1.0f / lsB;

  size_t baseO = (size_t)b * NKEY * 256 + (size_t)hh * 32;
  #pragma unroll
  for (int tile = 0; tile < 2; ++tile) {
    int q = (tile == 0) ? qA : qB;
    float inv = (tile == 0) ? invA : invB;
    const f32x16 &oo = (tile == 0) ? oA : oB;
    u16* op = og + baseO + (size_t)q * 256;
    const u16* gp = Gp + (size_t)q * 1024;
    #pragma unroll
    for (int rq = 0; rq < 4; ++rq) {
      int c0 = 8*rq + 4*hi;
      ushort4 g4 = *(const ushort4*)(gp + c0);
      float f0 = oo[4*rq+0] * inv * bf2f(g4.x);
      float f1 = oo[4*rq+1] * inv * bf2f(g4.y);
      float f2 = oo[4*rq+2] * inv * bf2f(g4.z);
      float f3 = oo[4*rq+3] * inv * bf2f(g4.w);
      uint2 o2; o2.x = cvt_pk(f0, f1); o2.y = cvt_pk(f2, f3);
      *(uint2*)(op + c0) = o2;
    }
  }
}

extern "C" void kernel_launch(void* const* d_in, const int* in_sizes, int n_in,
                              void* d_out, int out_size, void* d_ws, size_t ws_size,
                              hipStream_t stream)
{
  const float* node         = (const float*)d_in[0];
  const float* pair         = (const float*)d_in[1];
  const float* node_mask    = (const float*)d_in[2];
  const float* row_ln_m_g   = (const float*)d_in[3];
  const float* row_ln_m_b   = (const float*)d_in[4];
  const float* row_ln_z_g   = (const float*)d_in[5];
  const float* row_ln_z_b   = (const float*)d_in[6];
  const float* row_b_w      = (const float*)d_in[7];
  const float* row_wq       = (const float*)d_in[8];
  const float* row_wk       = (const float*)d_in[9];
  const float* row_wv       = (const float*)d_in[10];
  const float* row_wg       = (const float*)d_in[11];
  const float* row_bg       = (const float*)d_in[12];
  const float* row_wo       = (const float*)d_in[13];
  const float* row_out_bias = (const float*)d_in[14];
  const float* col_ln_g     = (const float*)d_in[15];
  const float* col_ln_b     = (const float*)d_in[16];
  const float* col_wq       = (const float*)d_in[17];
  const float* col_wk       = (const float*)d_in[18];
  const float* col_wv       = (const float*)d_in[19];
  const float* col_wg       = (const float*)d_in[20];
  const float* col_bg       = (const float*)d_in[21];
  const float* col_wo       = (const float*)d_in[22];
  const float* col_bo       = (const float*)d_in[23];
  const float* tr_ln_g      = (const float*)d_in[24];
  const float* tr_ln_b      = (const float*)d_in[25];
  const float* tr_w1        = (const float*)d_in[26];
  const float* tr_b1        = (const float*)d_in[27];
  const float* tr_w2        = (const float*)d_in[28];
  const float* tr_b2        = (const float*)d_in[29];

  float* out = (float*)d_out;
  char* ws8 = (char*)d_ws;
  const size_t MB = 1ull << 20;
  u16*   A     = (u16*)(ws8);               // 16 MB  LN out [32768][256] bf16
  u16*   QKVG  = (u16*)(ws8 + 16*MB);       // 64 MB  [32768][1024] bf16 (also T1)
  u16*   Ob    = (u16*)(ws8 + 80*MB);       // 16 MB  gated attn out bf16
  u16*   Dbias = (u16*)(ws8 + 96*MB);       // 1 MB   [H][R][R] bf16 (log2e-scaled)
  u16*   Wb    = (u16*)(ws8 + 100*MB);      // bf16 weight arena
  u16*   T1    = QKVG;

  const float qs = 0.17677669529663687f;    // 1/sqrt(32)

  u16* Wrqkvg = Wb + 0;
  u16* Wro    = Wb + 262144;
  u16* Wcqkvg = Wb + 327680;
  u16* Wco    = Wb + 589824;
  u16* W1     = Wb + 655360;
  u16* W2     = Wb + 917504;

  CvtArgs ca;
  const float* srcs[12] = {row_wq,row_wk,row_wv,row_wg,row_wo,
                           col_wq,col_wk,col_wv,col_wg,col_wo,tr_w1,tr_w2};
  int offs[12] = {0,65536,131072,196608,262144,327680,393216,458752,524288,589824,655360,917504};
  int ns[12]   = {65536,65536,65536,65536,65536,65536,65536,65536,65536,65536,262144,262144};
  for (int i = 0; i < 12; ++i) {
    ca.src[i] = srcs[i]; ca.off[i] = offs[i]; ca.n[i] = ns[i];
    ca.scale[i] = (i == 0 || i == 5) ? qs * LOG2E : 1.0f;
  }
  cvt_w_kernel<<<dim3(256,12), 256, 0, stream>>>(ca, Wb);

  dim3 gq(4, 128);     // AM=2: 256x256 tiles, N=1024
  dim3 go(1, 256);     // AM=1: 128x256 tiles, N=256 (full-GPU grid)

  // --- row attention ---
  ln256_kernel<<<8192, 256, 0, stream>>>(node, A, row_ln_m_g, row_ln_m_b, 0);
  pair_bias_kernel<<<16384, 256, 0, stream>>>(pair, row_ln_z_g, row_ln_z_b, row_b_w, Dbias);
  gemm_8ph<2><<<gq, 512, 0, stream>>>(A, Wrqkvg, QKVG, 1024, 256, 6, row_bg, nullptr);
  attn_mfma<256,2,true><<<dim3(4,128), 512, 0, stream>>>(QKVG, Dbias, node_mask, Ob);
  gemm_8ph<1><<<go, 512, 0, stream>>>(Ob, Wro, out, 256, 256, 4, row_out_bias, node);

  // --- column attention (in [r,s,d] layout) ---
  ln256_kernel<<<8192, 256, 0, stream>>>(out, A, col_ln_g, col_ln_b, 1);
  gemm_8ph<2><<<gq, 512, 0, stream>>>(A, Wcqkvg, QKVG, 1024, 256, 6, col_bg, nullptr);
  attn_mfma<128,4,false><<<dim3(2,256), 512, 0, stream>>>(QKVG, Dbias, node_mask, Ob);
  gemm_8ph<1><<<go, 512, 0, stream>>>(Ob, Wco, out, 256, 256, 5, col_bo, out);

  // --- transition ---
  ln256_kernel<<<8192, 256, 0, stream>>>(out, A, tr_ln_g, tr_ln_b, 0);
  gemm_8ph<2><<<gq, 512, 0, stream>>>(A, W1, T1, 1024, 256, 3, tr_b1, nullptr);
  gemm_8ph<1><<<go, 512, 0, stream>>>(T1, W2, out, 256, 1024, 4, tr_b2, out);
}

// Round 11
// 367.442 us; speedup vs baseline: 4.5070x; 1.0016x over previous
//
#include <hip/hip_runtime.h>
#include <math.h>

#define S 128
#define R 256
#define DMODEL 256
#define H 8
#define CDIM 32
#define HC 256
#define DFF 1024
#define NROWS (S*R)     // 32768
#define NPAIR (R*R)     // 65536
#define LN_EPS 1e-5f
#define LOG2E 1.4426950408889634f
#define M32 ((size_t)NROWS * 32)

typedef unsigned short u16;
typedef __attribute__((ext_vector_type(8))) short bf16x8;
typedef __attribute__((ext_vector_type(4))) float f32x4;
typedef __attribute__((ext_vector_type(16))) float f32x16;

__device__ __forceinline__ u16 f2bf(float x) {
  unsigned u = __float_as_uint(x);
  u = (u + 0x7fffu + ((u >> 16) & 1u)) >> 16;
  return (u16)u;
}
__device__ __forceinline__ float bf2f(u16 x) {
  return __uint_as_float(((unsigned)x) << 16);
}
// pack 2 f32 -> 2 bf16 in one u32 (lo = a, hi = b), RNE
__device__ __forceinline__ unsigned cvt_pk(float a, float b) {
  unsigned r;
  asm("v_cvt_pk_bf16_f32 %0, %1, %2" : "=v"(r) : "v"(a), "v"(b));
  return r;
}
// swap a[32:63] <-> b[0:31]
__device__ __forceinline__ void pl32swap(unsigned &a, unsigned &b) {
  asm("v_permlane32_swap_b32 %0, %1" : "+v"(a), "+v"(b));
}
__device__ __forceinline__ bf16x8 mk_frag(unsigned a, unsigned b, unsigned c, unsigned d) {
  uint4 t = make_uint4(a, b, c, d);
  return __builtin_bit_cast(bf16x8, t);
}

__device__ __forceinline__ void gload_lds16(const u16* g, u16* l) {
  __builtin_amdgcn_global_load_lds(
      (const __attribute__((address_space(1))) unsigned int*)g,
      (__attribute__((address_space(3))) unsigned int*)l, 16, 0, 0);
}

// ---------------- weight f32 -> bf16 conversion (12 segments) ----------------
struct CvtArgs {
  const float* src[12];
  int off[12];
  int n[12];
  float scale[12];
};

__global__ __launch_bounds__(256) void cvt_w_kernel(CvtArgs a, u16* __restrict__ dst) {
  int sg = blockIdx.y;
  int i = (blockIdx.x * 256 + threadIdx.x) * 4;
  if (i >= a.n[sg]) return;
  float4 v = *(const float4*)(a.src[sg] + i);
  float sc = a.scale[sg];
  uint2 o;
  o.x = cvt_pk(v.x * sc, v.y * sc);
  o.y = cvt_pk(v.z * sc, v.w * sc);
  *(uint2*)(dst + a.off[sg] + i) = o;
}

// ---------------- LayerNorm over 256, one row per wave, bf16 out ----------------
__global__ __launch_bounds__(256) void ln256_kernel(
    const float* __restrict__ in, u16* __restrict__ out,
    const float* __restrict__ gamma, const float* __restrict__ beta,
    int tmode)
{
  int wid = threadIdx.x >> 6, lane = threadIdx.x & 63;
  int m = blockIdx.x * 4 + wid;
  int inrow = m;
  if (tmode) { int r = m >> 7, s = m & 127; inrow = s * R + r; }
  float4 x = *(const float4*)(in + (size_t)inrow * DMODEL + lane * 4);
  float sum = x.x + x.y + x.z + x.w;
  float sq  = x.x*x.x + x.y*x.y + x.z*x.z + x.w*x.w;
  #pragma unroll
  for (int off = 32; off; off >>= 1) {
    sum += __shfl_xor(sum, off);
    sq  += __shfl_xor(sq, off);
  }
  float mean = sum * (1.0f/256.0f);
  float var  = sq  * (1.0f/256.0f) - mean*mean;
  float rstd = rsqrtf(var + LN_EPS);
  float4 g = *(const float4*)(gamma + lane*4);
  float4 b = *(const float4*)(beta  + lane*4);
  uint2 o;
  o.x = cvt_pk((x.x-mean)*rstd*g.x + b.x, (x.y-mean)*rstd*g.y + b.y);
  o.y = cvt_pk((x.z-mean)*rstd*g.z + b.z, (x.w-mean)*rstd*g.w + b.w);
  *(uint2*)(out + (size_t)m * DMODEL + lane*4) = o;
}

// -- pair LN (over 128) + bias projection -> TRANSPOSED bias[h][k][q] (bf16, *log2e) --
__global__ __launch_bounds__(256) void pair_bias_kernel(
    const float* __restrict__ pair, const float* __restrict__ gamma,
    const float* __restrict__ beta, const float* __restrict__ bw,
    u16* __restrict__ bias)
{
  int wid = threadIdx.x >> 6, lane = threadIdx.x & 63;
  int p = blockIdx.x * 4 + wid;     // p = q*256 + k
  float2 x = *(const float2*)(pair + (size_t)p * 128 + lane*2);
  float sum = x.x + x.y, sq = x.x*x.x + x.y*x.y;
  #pragma unroll
  for (int off = 32; off; off >>= 1) {
    sum += __shfl_xor(sum, off);
    sq  += __shfl_xor(sq, off);
  }
  float mean = sum * (1.0f/128.0f);
  float rstd = rsqrtf(sq*(1.0f/128.0f) - mean*mean + LN_EPS);
  float z0 = (x.x-mean)*rstd*gamma[lane*2]   + beta[lane*2];
  float z1 = (x.y-mean)*rstd*gamma[lane*2+1] + beta[lane*2+1];
  float a0 = z0*bw[0*128+lane*2] + z1*bw[0*128+lane*2+1];
  float a1 = z0*bw[1*128+lane*2] + z1*bw[1*128+lane*2+1];
  float a2 = z0*bw[2*128+lane*2] + z1*bw[2*128+lane*2+1];
  float a3 = z0*bw[3*128+lane*2] + z1*bw[3*128+lane*2+1];
  float a4 = z0*bw[4*128+lane*2] + z1*bw[4*128+lane*2+1];
  float a5 = z0*bw[5*128+lane*2] + z1*bw[5*128+lane*2+1];
  float a6 = z0*bw[6*128+lane*2] + z1*bw[6*128+lane*2+1];
  float a7 = z0*bw[7*128+lane*2] + z1*bw[7*128+lane*2+1];
  #pragma unroll
  for (int off = 32; off; off >>= 1) {
    a0 += __shfl_xor(a0, off); a1 += __shfl_xor(a1, off);
    a2 += __shfl_xor(a2, off); a3 += __shfl_xor(a3, off);
    a4 += __shfl_xor(a4, off); a5 += __shfl_xor(a5, off);
    a6 += __shfl_xor(a6, off); a7 += __shfl_xor(a7, off);
  }
  float v = a0;
  v = (lane==1)?a1:v; v = (lane==2)?a2:v; v = (lane==3)?a3:v;
  v = (lane==4)?a4:v; v = (lane==5)?a5:v; v = (lane==6)?a6:v; v = (lane==7)?a7:v;
  if (lane < 8) {
    int q = p >> 8, k = p & 255;
    bias[(size_t)lane*NPAIR + (size_t)k*R + q] = f2bf(v * LOG2E);
  }
}

// ---------------- bf16 MFMA NT GEMM, (AM*128)x256 tile, BK=64, counted-vmcnt ----------------
// C[M,N] = A[M,K] * W[N,K]^T.  512 threads = 8 waves (2M x 4N).
// AM = A half-tiles (2 -> BM=256, 1 -> BM=128).
// modes: 1: bf16  2: bf16 sigmoid(x+bias)  3: bf16 relu(x+bias)
//        4: f32 x+res+bias   5: f32 transposed idx
//        6: HEAD-MAJOR QKVG store: [col>>5][row][col&31], cols>=768 sigmoid(+bias)
template<int AM>
__global__ __launch_bounds__(512, 2) void gemm_8ph(
    const u16* __restrict__ A, const u16* __restrict__ W,
    void* __restrict__ Cout, int N, int K,
    int mode, const float* __restrict__ bias, const float* __restrict__ res)
{
  __shared__ u16 lds[2][AM+2][128*64];
  int t = threadIdx.x, lane = t & 63, wv = t >> 6;
  int g16 = (lane >> 4) & 3, l16 = lane & 15;
  int wm = wv >> 2, wn = wv & 3;
  int lrow = lane >> 3, lchunk = lane & 7;

  // bijective XCD swizzle (nwg % 8 == 0 for all our grids)
  int gx = gridDim.x;
  int nwg = gx * gridDim.y;
  int p = blockIdx.y * gx + blockIdx.x;
  int cpx = nwg >> 3;
  int lg = (p & 7) * cpx + (p >> 3);
  int bn = (lg % gx) * 256;
  int bm = (lg / gx) * (AM * 128);

  int srcc = (lchunk ^ lrow) << 3;          // pre-swizzled global k-chunk
  int ch0  = (g16 ^ (l16 & 7)) << 3;        // swizzled LDS read chunk (k32=0)
  int rdoff = l16 * 64 + ch0;               // k32=1 -> rdoff ^ 32
  const int wnh = AM + (wn >> 1);
  const int wnr = (wn & 1) * 4096;

  f32x4 acc[AM*4][4];
  #pragma unroll
  for (int i = 0; i < AM*4; ++i)
    #pragma unroll
    for (int j = 0; j < 4; ++j) acc[i][j] = (f32x4){0.f,0.f,0.f,0.f};

  const int nkt = K >> 6;

#define STG_HALF(buf_, h_, base_, row0_, kc_) do { \
    gload_lds16(base_ + (size_t)((row0_) + (wv*2+0)*8 + lrow) * K + (kc_) + srcc, \
                &lds[buf_][h_][(wv*2+0)*512 + lane*8]); \
    gload_lds16(base_ + (size_t)((row0_) + (wv*2+1)*8 + lrow) * K + (kc_) + srcc, \
                &lds[buf_][h_][(wv*2+1)*512 + lane*8]); \
  } while(0)
#define STG_A(buf_, kc_) do { STG_HALF(buf_,0,A,bm,kc_); \
    if (AM==2) STG_HALF(buf_,1,A,bm+128,kc_); } while(0)
#define STG_B(buf_, kc_) do { STG_HALF(buf_,AM,W,bn,kc_); STG_HALF(buf_,AM+1,W,bn+128,kc_); } while(0)

  int buf = 0;
  STG_A(0, 0); STG_B(0, 0);
  for (int kt = 0; kt < nkt; ++kt) {
    int kc = kt << 6;
    if (kt + 1 < nkt) {
      STG_A(buf^1, kc + 64);                // issue-early next A
      if (AM == 2) asm volatile("s_waitcnt vmcnt(4)" ::: "memory");
      else         asm volatile("s_waitcnt vmcnt(2)" ::: "memory");
    } else {
      asm volatile("s_waitcnt vmcnt(0)" ::: "memory");
    }
    __builtin_amdgcn_s_barrier();
    asm volatile("" ::: "memory");
    if (kt + 1 < nkt) STG_B(buf^1, kc + 64);

    const u16* Abase = (AM==2) ? &lds[buf][wm][0] : &lds[buf][0][wm*4096];
    const u16* Wbase = &lds[buf][wnh][wnr];
    bf16x8 wf[4][2];
    #pragma unroll
    for (int nf = 0; nf < 4; ++nf) {
      wf[nf][0] = *(const bf16x8*)(Wbase + nf*1024 + rdoff);
      wf[nf][1] = *(const bf16x8*)(Wbase + nf*1024 + (rdoff ^ 32));
    }
    __builtin_amdgcn_s_setprio(1);
    #pragma unroll
    for (int mf = 0; mf < AM*4; ++mf) {
      bf16x8 a0 = *(const bf16x8*)(Abase + mf*1024 + rdoff);
      bf16x8 a1 = *(const bf16x8*)(Abase + mf*1024 + (rdoff ^ 32));
      #pragma unroll
      for (int nf = 0; nf < 4; ++nf) {
        acc[mf][nf] = __builtin_amdgcn_mfma_f32_16x16x32_bf16(wf[nf][0], a0, acc[mf][nf], 0, 0, 0);
        acc[mf][nf] = __builtin_amdgcn_mfma_f32_16x16x32_bf16(wf[nf][1], a1, acc[mf][nf], 0, 0, 0);
      }
    }
    __builtin_amdgcn_s_setprio(0);
    asm volatile("" ::: "memory");
    __builtin_amdgcn_s_barrier();
    buf ^= 1;
  }
#undef STG_A
#undef STG_B
#undef STG_HALF

  int rowb = bm + wm*(AM*64) + l16;
  int colb = bn + wn*64 + (g16 << 2);
  #pragma unroll
  for (int mf = 0; mf < AM*4; ++mf) {
    int row = rowb + mf*16;
    #pragma unroll
    for (int nf = 0; nf < 4; ++nf) {
      int col0 = colb + nf*16;
      f32x4 v = acc[mf][nf];
      if (mode == 6) {
        if (col0 >= 768) {
          float4 b4 = *(const float4*)(bias + col0 - 768);
          v[0] = 1.0f/(1.0f+__expf(-(v[0]+b4.x)));
          v[1] = 1.0f/(1.0f+__expf(-(v[1]+b4.y)));
          v[2] = 1.0f/(1.0f+__expf(-(v[2]+b4.z)));
          v[3] = 1.0f/(1.0f+__expf(-(v[3]+b4.w)));
        }
        uint2 o; o.x = cvt_pk(v[0], v[1]); o.y = cvt_pk(v[2], v[3]);
        size_t i2 = (size_t)(col0 >> 5) * M32 + (size_t)row*32 + (col0 & 31);
        *(uint2*)((u16*)Cout + i2) = o;
      } else if (mode == 3) {
        float4 b4 = *(const float4*)(bias + col0);
        uint2 o;
        o.x = cvt_pk(fmaxf(v[0]+b4.x, 0.f), fmaxf(v[1]+b4.y, 0.f));
        o.y = cvt_pk(fmaxf(v[2]+b4.z, 0.f), fmaxf(v[3]+b4.w, 0.f));
        *(uint2*)((u16*)Cout + (size_t)row*N + col0) = o;
      } else if (mode == 4) {
        size_t i2 = (size_t)row*N + col0;
        float4 r4 = *(const float4*)(res + i2);
        float4 b4 = *(const float4*)(bias + col0);
        float4 o = make_float4(v[0]+r4.x+b4.x, v[1]+r4.y+b4.y,
                               v[2]+r4.z+b4.z, v[3]+r4.w+b4.w);
        *(float4*)((float*)Cout + i2) = o;
      } else if (mode == 5) {
        int rr = row >> 7, ss = row & 127;
        size_t i2 = ((size_t)ss*R + rr)*(size_t)N + col0;
        float4 r4 = *(const float4*)(res + i2);
        float4 b4 = *(const float4*)(bias + col0);
        float4 o = make_float4(v[0]+r4.x+b4.x, v[1]+r4.y+b4.y,
                               v[2]+r4.z+b4.z, v[3]+r4.w+b4.w);
        *(float4*)((float*)Cout + i2) = o;
      } else if (mode == 2) {
        float4 b4 = *(const float4*)(bias + col0);
        uint2 o;
        o.x = cvt_pk(1.0f/(1.0f+__expf(-(v[0]+b4.x))),
                     1.0f/(1.0f+__expf(-(v[1]+b4.y))));
        o.y = cvt_pk(1.0f/(1.0f+__expf(-(v[2]+b4.z))),
                     1.0f/(1.0f+__expf(-(v[3]+b4.w))));
        *(uint2*)((u16*)Cout + (size_t)row*N + col0) = o;
      } else {
        uint2 o; o.x = cvt_pk(v[0], v[1]); o.y = cvt_pk(v[2], v[3]);
        *(uint2*)((u16*)Cout + (size_t)row*N + col0) = o;
      }
    }
  }
}

// ---- softmax + pack one 32-key group's P (one 32-q tile) into PV B-frags ----
// bias_tq = bias + h*NPAIR + q   (transposed layout [h][k][q]; loads coalesced over q)
template<bool RM>
__device__ __forceinline__ void softmax_pack(
    const f32x16 &sac, const float* __restrict__ lmbp,
    const u16* __restrict__ bias_tq, int kb, int hi,
    float &lsum, bf16x8 &pf0, bf16x8 &pf1)
{
  float p[16];
  #pragma unroll
  for (int rq = 0; rq < 4; ++rq) {
    int k0 = kb + 8*rq + 4*hi;
    float4 lm4 = *(const float4*)&lmbp[k0];
    float b0 = lm4.x, b1 = lm4.y, b2 = lm4.z, b3 = lm4.w;
    if (RM) {
      b0 += bf2f(bias_tq[(size_t)(k0+0)*R]);
      b1 += bf2f(bias_tq[(size_t)(k0+1)*R]);
      b2 += bf2f(bias_tq[(size_t)(k0+2)*R]);
      b3 += bf2f(bias_tq[(size_t)(k0+3)*R]);
    }
    p[4*rq+0] = exp2f(sac[4*rq+0] + b0);
    p[4*rq+1] = exp2f(sac[4*rq+1] + b1);
    p[4*rq+2] = exp2f(sac[4*rq+2] + b2);
    p[4*rq+3] = exp2f(sac[4*rq+3] + b3);
    lsum += (p[4*rq+0] + p[4*rq+1]) + (p[4*rq+2] + p[4*rq+3]);
  }
  unsigned u0 = cvt_pk(p[0],  p[1]),  u1 = cvt_pk(p[2],  p[3]);
  unsigned u2 = cvt_pk(p[4],  p[5]),  u3 = cvt_pk(p[6],  p[7]);
  unsigned u4 = cvt_pk(p[8],  p[9]),  u5 = cvt_pk(p[10], p[11]);
  unsigned u6 = cvt_pk(p[12], p[13]), u7 = cvt_pk(p[14], p[15]);
  pl32swap(u0, u2); pl32swap(u1, u3);
  pl32swap(u4, u6); pl32swap(u5, u7);
  pf0 = mk_frag(u0, u1, u2, u3);
  pf1 = mk_frag(u4, u5, u6, u7);
}

// ---------------- MFMA attention, 32x32, head-major QKVG, in-register P ----
// QKVG head-major: seg*8+head blocks of [NROWS][32]; Q=0..7, K=8..15, V=16..23, G=24..31.
// HPB heads per block; 8/HPB waves per head; each wave owns 2 q-tiles (64 q).
template<int NKEY, int HPB, bool ROWMODE>
__global__ __launch_bounds__(512, 2) void attn_mfma(
    const u16* __restrict__ QKVG, const u16* __restrict__ bias,
    const float* __restrict__ mask, u16* __restrict__ og)
{
  __shared__ __align__(16) u16 Vt[HPB][32][NKEY + 8];
  __shared__ float lmb[NKEY];
  constexpr int NKV = NKEY / 32;
  constexpr int WPH = 8 / HPB;
  int b = blockIdx.y;
  int t = threadIdx.x, lane = t & 63, w = t >> 6;
  int c31 = lane & 31, hi = lane >> 5;
  int lh = w / WPH, wtile = w % WPH;
  int hh = blockIdx.x * HPB + lh;

  size_t rbase = (size_t)b * NKEY * 32;
  const u16* Qp = QKVG + (size_t)hh * M32 + rbase;
  const u16* Kp = QKVG + (size_t)(8 + hh) * M32 + rbase;
  const u16* Gp = QKVG + (size_t)(24 + hh) * M32 + rbase;

  // ---- stage V transposed (contiguous reads) ----
  for (int i = t; i < HPB*NKEY*4; i += 512) {
    int c0 = (i & 3) * 8;
    int key = (i >> 2) & (NKEY - 1);
    int sh = (i >> 2) / NKEY;
    const u16* Vs = QKVG + (size_t)(16 + blockIdx.x*HPB + sh) * M32 + rbase;
    bf16x8 v8 = *(const bf16x8*)(Vs + (size_t)key*32 + c0);
    #pragma unroll
    for (int j = 0; j < 8; ++j) Vt[sh][c0+j][key] = (u16)v8[j];
  }
  for (int i = t; i < NKEY; i += 512)
    lmb[i] = 1.4426950e9f * ((ROWMODE ? mask[b*R + i] : mask[i*R + b]) - 1.0f);
  __syncthreads();

  int qA = wtile*64 + c31, qB = qA + 32;
  bf16x8 qfA0 = *(const bf16x8*)(Qp + (size_t)qA*32 + hi*8);
  bf16x8 qfA1 = *(const bf16x8*)(Qp + (size_t)qA*32 + 16 + hi*8);
  bf16x8 qfB0 = *(const bf16x8*)(Qp + (size_t)qB*32 + hi*8);
  bf16x8 qfB1 = *(const bf16x8*)(Qp + (size_t)qB*32 + 16 + hi*8);

  f32x16 oA = (f32x16)(0.0f), oB = (f32x16)(0.0f);
  float lsA = 0.f, lsB = 0.f;
  const u16* biasA = bias + (size_t)hh*NPAIR + qA;   // transposed [k][q], +q
  const u16* biasB = biasA + 32;

  // prefetch group 0's K fragments (contiguous: wave covers 2KB)
  const u16* kr0 = Kp + (size_t)c31*32 + hi*8;
  bf16x8 nk0 = *(const bf16x8*)kr0;
  bf16x8 nk1 = *(const bf16x8*)(kr0 + 16);

  for (int g = 0; g < NKV; ++g) {
    int kb = g * 32;
    bf16x8 k0 = nk0, k1 = nk1;
    if (g + 1 < NKV) {
      const u16* kr = Kp + (size_t)(kb + 32 + c31)*32 + hi*8;
      nk0 = *(const bf16x8*)kr;
      nk1 = *(const bf16x8*)(kr + 16);
    }
    __builtin_amdgcn_s_setprio(1);
    f32x16 sacA = __builtin_amdgcn_mfma_f32_32x32x16_bf16(k0, qfA0, (f32x16)(0.0f), 0, 0, 0);
    sacA = __builtin_amdgcn_mfma_f32_32x32x16_bf16(k1, qfA1, sacA, 0, 0, 0);
    f32x16 sacB = __builtin_amdgcn_mfma_f32_32x32x16_bf16(k0, qfB0, (f32x16)(0.0f), 0, 0, 0);
    sacB = __builtin_amdgcn_mfma_f32_32x32x16_bf16(k1, qfB1, sacB, 0, 0, 0);
    __builtin_amdgcn_s_setprio(0);
    bf16x8 va0 = *(const bf16x8*)&Vt[lh][c31][kb + hi*8];
    bf16x8 va1 = *(const bf16x8*)&Vt[lh][c31][kb + 16 + hi*8];
    bf16x8 pfA0, pfA1, pfB0, pfB1;
    softmax_pack<ROWMODE>(sacA, lmb, biasA, kb, hi, lsA, pfA0, pfA1);
    softmax_pack<ROWMODE>(sacB, lmb, biasB, kb, hi, lsB, pfB0, pfB1);
    __builtin_amdgcn_s_setprio(1);
    oA = __builtin_amdgcn_mfma_f32_32x32x16_bf16(va0, pfA0, oA, 0, 0, 0);
    oA = __builtin_amdgcn_mfma_f32_32x32x16_bf16(va1, pfA1, oA, 0, 0, 0);
    oB = __builtin_amdgcn_mfma_f32_32x32x16_bf16(va0, pfB0, oB, 0, 0, 0);
    oB = __builtin_amdgcn_mfma_f32_32x32x16_bf16(va1, pfB1, oB, 0, 0, 0);
    __builtin_amdgcn_s_setprio(0);
  }
  lsA += __shfl_xor(lsA, 32);
  lsB += __shfl_xor(lsB, 32);
  float invA = 1.0f / lsA, invB = 1.0f / lsB;

  size_t baseO = (size_t)b * NKEY * 256 + (size_t)hh * 32;
  #pragma unroll
  for (int tile = 0; tile < 2; ++tile) {
    int q = (tile == 0) ? qA : qB;
    float inv = (tile == 0) ? invA : invB;
    const f32x16 &oo = (tile == 0) ? oA : oB;
    u16* op = og + baseO + (size_t)q * 256;
    const u16* gp = Gp + (size_t)q * 32;
    #pragma unroll
    for (int rq = 0; rq < 4; ++rq) {
      int c0 = 8*rq + 4*hi;
      ushort4 g4 = *(const ushort4*)(gp + c0);
      float f0 = oo[4*rq+0] * inv * bf2f(g4.x);
      float f1 = oo[4*rq+1] * inv * bf2f(g4.y);
      float f2 = oo[4*rq+2] * inv * bf2f(g4.z);
      float f3 = oo[4*rq+3] * inv * bf2f(g4.w);
      uint2 o2; o2.x = cvt_pk(f0, f1); o2.y = cvt_pk(f2, f3);
      *(uint2*)(op + c0) = o2;
    }
  }
}

extern "C" void kernel_launch(void* const* d_in, const int* in_sizes, int n_in,
                              void* d_out, int out_size, void* d_ws, size_t ws_size,
                              hipStream_t stream)
{
  const float* node         = (const float*)d_in[0];
  const float* pair         = (const float*)d_in[1];
  const float* node_mask    = (const float*)d_in[2];
  const float* row_ln_m_g   = (const float*)d_in[3];
  const float* row_ln_m_b   = (const float*)d_in[4];
  const float* row_ln_z_g   = (const float*)d_in[5];
  const float* row_ln_z_b   = (const float*)d_in[6];
  const float* row_b_w      = (const float*)d_in[7];
  const float* row_wq       = (const float*)d_in[8];
  const float* row_wk       = (const float*)d_in[9];
  const float* row_wv       = (const float*)d_in[10];
  const float* row_wg       = (const float*)d_in[11];
  const float* row_bg       = (const float*)d_in[12];
  const float* row_wo       = (const float*)d_in[13];
  const float* row_out_bias = (const float*)d_in[14];
  const float* col_ln_g     = (const float*)d_in[15];
  const float* col_ln_b     = (const float*)d_in[16];
  const float* col_wq       = (const float*)d_in[17];
  const float* col_wk       = (const float*)d_in[18];
  const float* col_wv       = (const float*)d_in[19];
  const float* col_wg       = (const float*)d_in[20];
  const float* col_bg       = (const float*)d_in[21];
  const float* col_wo       = (const float*)d_in[22];
  const float* col_bo       = (const float*)d_in[23];
  const float* tr_ln_g      = (const float*)d_in[24];
  const float* tr_ln_b      = (const float*)d_in[25];
  const float* tr_w1        = (const float*)d_in[26];
  const float* tr_b1        = (const float*)d_in[27];
  const float* tr_w2        = (const float*)d_in[28];
  const float* tr_b2        = (const float*)d_in[29];

  float* out = (float*)d_out;
  char* ws8 = (char*)d_ws;
  const size_t MB = 1ull << 20;
  u16*   A     = (u16*)(ws8);               // 16 MB  LN out [32768][256] bf16
  u16*   QKVG  = (u16*)(ws8 + 16*MB);       // 64 MB  head-major 32 x [32768][32] (also T1)
  u16*   Ob    = (u16*)(ws8 + 80*MB);       // 16 MB  gated attn out bf16 [row][256]
  u16*   Dbias = (u16*)(ws8 + 96*MB);       // 1 MB   [H][k][q] bf16 (log2e-scaled)
  u16*   Wb    = (u16*)(ws8 + 100*MB);      // bf16 weight arena
  u16*   T1    = QKVG;

  const float qs = 0.17677669529663687f;    // 1/sqrt(32)

  u16* Wrqkvg = Wb + 0;
  u16* Wro    = Wb + 262144;
  u16* Wcqkvg = Wb + 327680;
  u16* Wco    = Wb + 589824;
  u16* W1     = Wb + 655360;
  u16* W2     = Wb + 917504;

  CvtArgs ca;
  const float* srcs[12] = {row_wq,row_wk,row_wv,row_wg,row_wo,
                           col_wq,col_wk,col_wv,col_wg,col_wo,tr_w1,tr_w2};
  int offs[12] = {0,65536,131072,196608,262144,327680,393216,458752,524288,589824,655360,917504};
  int ns[12]   = {65536,65536,65536,65536,65536,65536,65536,65536,65536,65536,262144,262144};
  for (int i = 0; i < 12; ++i) {
    ca.src[i] = srcs[i]; ca.off[i] = offs[i]; ca.n[i] = ns[i];
    ca.scale[i] = (i == 0 || i == 5) ? qs * LOG2E : 1.0f;
  }
  cvt_w_kernel<<<dim3(256,12), 256, 0, stream>>>(ca, Wb);

  dim3 gq(4, 128);     // AM=2: 256x256 tiles, N=1024
  dim3 go(1, 256);     // AM=1: 128x256 tiles, N=256 (full-GPU grid)

  // --- row attention ---
  ln256_kernel<<<8192, 256, 0, stream>>>(node, A, row_ln_m_g, row_ln_m_b, 0);
  pair_bias_kernel<<<16384, 256, 0, stream>>>(pair, row_ln_z_g, row_ln_z_b, row_b_w, Dbias);
  gemm_8ph<2><<<gq, 512, 0, stream>>>(A, Wrqkvg, QKVG, 1024, 256, 6, row_bg, nullptr);
  attn_mfma<256,2,true><<<dim3(4,128), 512, 0, stream>>>(QKVG, Dbias, node_mask, Ob);
  gemm_8ph<1><<<go, 512, 0, stream>>>(Ob, Wro, out, 256, 256, 4, row_out_bias, node);

  // --- column attention (in [r,s,d] layout) ---
  ln256_kernel<<<8192, 256, 0, stream>>>(out, A, col_ln_g, col_ln_b, 1);
  gemm_8ph<2><<<gq, 512, 0, stream>>>(A, Wcqkvg, QKVG, 1024, 256, 6, col_bg, nullptr);
  attn_mfma<128,4,false><<<dim3(2,256), 512, 0, stream>>>(QKVG, Dbias, node_mask, Ob);
  gemm_8ph<1><<<go, 512, 0, stream>>>(Ob, Wco, out, 256, 256, 5, col_bo, out);

  // --- transition ---
  ln256_kernel<<<8192, 256, 0, stream>>>(out, A, tr_ln_g, tr_ln_b, 0);
  gemm_8ph<2><<<gq, 512, 0, stream>>>(A, W1, T1, 1024, 256, 3, tr_b1, nullptr);
  gemm_8ph<1><<<go, 512, 0, stream>>>(T1, W2, out, 256, 1024, 4, tr_b2, out);
}

// Round 12
// 345.846 us; speedup vs baseline: 4.7885x; 1.0624x over previous
//
#include <hip/hip_runtime.h>
#include <math.h>

#define S 128
#define R 256
#define DMODEL 256
#define H 8
#define CDIM 32
#define HC 256
#define DFF 1024
#define NROWS (S*R)     // 32768
#define NPAIR (R*R)     // 65536
#define LN_EPS 1e-5f
#define LOG2E 1.4426950408889634f
#define M32 ((size_t)NROWS * 32)

typedef unsigned short u16;
typedef __attribute__((ext_vector_type(8))) short bf16x8;
typedef __attribute__((ext_vector_type(4))) float f32x4;
typedef __attribute__((ext_vector_type(16))) float f32x16;

__device__ __forceinline__ u16 f2bf(float x) {
  unsigned u = __float_as_uint(x);
  u = (u + 0x7fffu + ((u >> 16) & 1u)) >> 16;
  return (u16)u;
}
__device__ __forceinline__ float bf2f(u16 x) {
  return __uint_as_float(((unsigned)x) << 16);
}
__device__ __forceinline__ unsigned cvt_pk(float a, float b) {
  unsigned r;
  asm("v_cvt_pk_bf16_f32 %0, %1, %2" : "=v"(r) : "v"(a), "v"(b));
  return r;
}
__device__ __forceinline__ void pl32swap(unsigned &a, unsigned &b) {
  asm("v_permlane32_swap_b32 %0, %1" : "+v"(a), "+v"(b));
}
__device__ __forceinline__ bf16x8 mk_frag(unsigned a, unsigned b, unsigned c, unsigned d) {
  uint4 t = make_uint4(a, b, c, d);
  return __builtin_bit_cast(bf16x8, t);
}

__device__ __forceinline__ void gload_lds16(const u16* g, u16* l) {
  __builtin_amdgcn_global_load_lds(
      (const __attribute__((address_space(1))) unsigned int*)g,
      (__attribute__((address_space(3))) unsigned int*)l, 16, 0, 0);
}

// ---------------- weight f32 -> bf16 conversion (12 segments) ----------------
struct CvtArgs {
  const float* src[12];
  int off[12];
  int n[12];
  float scale[12];
};

__global__ __launch_bounds__(256) void cvt_w_kernel(CvtArgs a, u16* __restrict__ dst) {
  int sg = blockIdx.y;
  int i = (blockIdx.x * 256 + threadIdx.x) * 4;
  if (i >= a.n[sg]) return;
  float4 v = *(const float4*)(a.src[sg] + i);
  float sc = a.scale[sg];
  uint2 o;
  o.x = cvt_pk(v.x * sc, v.y * sc);
  o.y = cvt_pk(v.z * sc, v.w * sc);
  *(uint2*)(dst + a.off[sg] + i) = o;
}

// ---------------- LayerNorm over 256, one row per wave, bf16 out ----------------
// inbf: input is bf16 (u16) instead of f32
__global__ __launch_bounds__(256) void ln256_kernel(
    const void* __restrict__ in, u16* __restrict__ out,
    const float* __restrict__ gamma, const float* __restrict__ beta,
    int tmode, int inbf)
{
  int wid = threadIdx.x >> 6, lane = threadIdx.x & 63;
  int m = blockIdx.x * 4 + wid;
  int inrow = m;
  if (tmode) { int r = m >> 7, s = m & 127; inrow = s * R + r; }
  float4 x;
  if (inbf) {
    ushort4 u = *(const ushort4*)((const u16*)in + (size_t)inrow * DMODEL + lane * 4);
    x.x = bf2f(u.x); x.y = bf2f(u.y); x.z = bf2f(u.z); x.w = bf2f(u.w);
  } else {
    x = *(const float4*)((const float*)in + (size_t)inrow * DMODEL + lane * 4);
  }
  float sum = x.x + x.y + x.z + x.w;
  float sq  = x.x*x.x + x.y*x.y + x.z*x.z + x.w*x.w;
  #pragma unroll
  for (int off = 32; off; off >>= 1) {
    sum += __shfl_xor(sum, off);
    sq  += __shfl_xor(sq, off);
  }
  float mean = sum * (1.0f/256.0f);
  float var  = sq  * (1.0f/256.0f) - mean*mean;
  float rstd = rsqrtf(var + LN_EPS);
  float4 g = *(const float4*)(gamma + lane*4);
  float4 b = *(const float4*)(beta  + lane*4);
  uint2 o;
  o.x = cvt_pk((x.x-mean)*rstd*g.x + b.x, (x.y-mean)*rstd*g.y + b.y);
  o.y = cvt_pk((x.z-mean)*rstd*g.z + b.z, (x.w-mean)*rstd*g.w + b.w);
  *(uint2*)(out + (size_t)m * DMODEL + lane*4) = o;
}

// -- pair LN (over 128) + bias projection -> FRAGMENT layout bias (bf16, *log2e) --
// layout: [h][kt=k>>5][qt=q>>5][hi=(k>>2)&1][c31=q&31][j=16]  (j = (k&3)|(((k>>3)&3)<<2))
__global__ __launch_bounds__(256) void pair_bias_kernel(
    const float* __restrict__ pair, const float* __restrict__ gamma,
    const float* __restrict__ beta, const float* __restrict__ bw,
    u16* __restrict__ bias)
{
  int wid = threadIdx.x >> 6, lane = threadIdx.x & 63;
  int p = blockIdx.x * 4 + wid;     // p = q*256 + k
  float2 x = *(const float2*)(pair + (size_t)p * 128 + lane*2);
  float sum = x.x + x.y, sq = x.x*x.x + x.y*x.y;
  #pragma unroll
  for (int off = 32; off; off >>= 1) {
    sum += __shfl_xor(sum, off);
    sq  += __shfl_xor(sq, off);
  }
  float mean = sum * (1.0f/128.0f);
  float rstd = rsqrtf(sq*(1.0f/128.0f) - mean*mean + LN_EPS);
  float z0 = (x.x-mean)*rstd*gamma[lane*2]   + beta[lane*2];
  float z1 = (x.y-mean)*rstd*gamma[lane*2+1] + beta[lane*2+1];
  float a0 = z0*bw[0*128+lane*2] + z1*bw[0*128+lane*2+1];
  float a1 = z0*bw[1*128+lane*2] + z1*bw[1*128+lane*2+1];
  float a2 = z0*bw[2*128+lane*2] + z1*bw[2*128+lane*2+1];
  float a3 = z0*bw[3*128+lane*2] + z1*bw[3*128+lane*2+1];
  float a4 = z0*bw[4*128+lane*2] + z1*bw[4*128+lane*2+1];
  float a5 = z0*bw[5*128+lane*2] + z1*bw[5*128+lane*2+1];
  float a6 = z0*bw[6*128+lane*2] + z1*bw[6*128+lane*2+1];
  float a7 = z0*bw[7*128+lane*2] + z1*bw[7*128+lane*2+1];
  #pragma unroll
  for (int off = 32; off; off >>= 1) {
    a0 += __shfl_xor(a0, off); a1 += __shfl_xor(a1, off);
    a2 += __shfl_xor(a2, off); a3 += __shfl_xor(a3, off);
    a4 += __shfl_xor(a4, off); a5 += __shfl_xor(a5, off);
    a6 += __shfl_xor(a6, off); a7 += __shfl_xor(a7, off);
  }
  float v = a0;
  v = (lane==1)?a1:v; v = (lane==2)?a2:v; v = (lane==3)?a3:v;
  v = (lane==4)?a4:v; v = (lane==5)?a5:v; v = (lane==6)?a6:v; v = (lane==7)?a7:v;
  if (lane < 8) {
    int q = p >> 8, k = p & 255;
    int kt = k >> 5, qt = q >> 5, c31 = q & 31;
    int kk = k & 31;
    int hi2 = (kk >> 2) & 1;
    int j = (kk & 3) | ((kk >> 3) << 2);
    size_t addr = ((((size_t)lane*8 + kt)*8 + qt)*2 + hi2)*512 + (size_t)c31*16 + j;
    bias[addr] = f2bf(v * LOG2E);
  }
}

// ---------------- bf16 MFMA NT GEMM, (AM*128)x256 tile, BK=64, counted-vmcnt ----------------
// modes: 1: bf16  2: bf16 sigmoid(x+bias)  3: bf16 relu(x+bias)
//        4: f32 x+res_f32+bias   5: f32 transposed x+res_f32+bias
//        6: head-major QKVG store, cols>=768 sigmoid(+bias)
//        7: bf16 x+res_f32+bias   8: bf16 transposed x+res_bf16+bias
//        9: f32 x+res_bf16+bias
template<int AM>
__global__ __launch_bounds__(512, 2) void gemm_8ph(
    const u16* __restrict__ A, const u16* __restrict__ W,
    void* __restrict__ Cout, int N, int K,
    int mode, const float* __restrict__ bias, const float* __restrict__ res)
{
  __shared__ u16 lds[2][AM+2][128*64];
  int t = threadIdx.x, lane = t & 63, wv = t >> 6;
  int g16 = (lane >> 4) & 3, l16 = lane & 15;
  int wm = wv >> 2, wn = wv & 3;
  int lrow = lane >> 3, lchunk = lane & 7;

  int gx = gridDim.x;
  int nwg = gx * gridDim.y;
  int p = blockIdx.y * gx + blockIdx.x;
  int cpx = nwg >> 3;
  int lg = (p & 7) * cpx + (p >> 3);
  int bn = (lg % gx) * 256;
  int bm = (lg / gx) * (AM * 128);

  int srcc = (lchunk ^ lrow) << 3;
  int ch0  = (g16 ^ (l16 & 7)) << 3;
  int rdoff = l16 * 64 + ch0;
  const int wnh = AM + (wn >> 1);
  const int wnr = (wn & 1) * 4096;

  f32x4 acc[AM*4][4];
  #pragma unroll
  for (int i = 0; i < AM*4; ++i)
    #pragma unroll
    for (int j = 0; j < 4; ++j) acc[i][j] = (f32x4){0.f,0.f,0.f,0.f};

  const int nkt = K >> 6;

#define STG_HALF(buf_, h_, base_, row0_, kc_) do { \
    gload_lds16(base_ + (size_t)((row0_) + (wv*2+0)*8 + lrow) * K + (kc_) + srcc, \
                &lds[buf_][h_][(wv*2+0)*512 + lane*8]); \
    gload_lds16(base_ + (size_t)((row0_) + (wv*2+1)*8 + lrow) * K + (kc_) + srcc, \
                &lds[buf_][h_][(wv*2+1)*512 + lane*8]); \
  } while(0)
#define STG_A(buf_, kc_) do { STG_HALF(buf_,0,A,bm,kc_); \
    if (AM==2) STG_HALF(buf_,1,A,bm+128,kc_); } while(0)
#define STG_B(buf_, kc_) do { STG_HALF(buf_,AM,W,bn,kc_); STG_HALF(buf_,AM+1,W,bn+128,kc_); } while(0)

  int buf = 0;
  STG_A(0, 0); STG_B(0, 0);
  for (int kt = 0; kt < nkt; ++kt) {
    int kc = kt << 6;
    if (kt + 1 < nkt) {
      STG_A(buf^1, kc + 64);
      if (AM == 2) asm volatile("s_waitcnt vmcnt(4)" ::: "memory");
      else         asm volatile("s_waitcnt vmcnt(2)" ::: "memory");
    } else {
      asm volatile("s_waitcnt vmcnt(0)" ::: "memory");
    }
    __builtin_amdgcn_s_barrier();
    asm volatile("" ::: "memory");
    if (kt + 1 < nkt) STG_B(buf^1, kc + 64);

    const u16* Abase = (AM==2) ? &lds[buf][wm][0] : &lds[buf][0][wm*4096];
    const u16* Wbase = &lds[buf][wnh][wnr];
    bf16x8 wf[4][2];
    #pragma unroll
    for (int nf = 0; nf < 4; ++nf) {
      wf[nf][0] = *(const bf16x8*)(Wbase + nf*1024 + rdoff);
      wf[nf][1] = *(const bf16x8*)(Wbase + nf*1024 + (rdoff ^ 32));
    }
    __builtin_amdgcn_s_setprio(1);
    #pragma unroll
    for (int mf = 0; mf < AM*4; ++mf) {
      bf16x8 a0 = *(const bf16x8*)(Abase + mf*1024 + rdoff);
      bf16x8 a1 = *(const bf16x8*)(Abase + mf*1024 + (rdoff ^ 32));
      #pragma unroll
      for (int nf = 0; nf < 4; ++nf) {
        acc[mf][nf] = __builtin_amdgcn_mfma_f32_16x16x32_bf16(wf[nf][0], a0, acc[mf][nf], 0, 0, 0);
        acc[mf][nf] = __builtin_amdgcn_mfma_f32_16x16x32_bf16(wf[nf][1], a1, acc[mf][nf], 0, 0, 0);
      }
    }
    __builtin_amdgcn_s_setprio(0);
    asm volatile("" ::: "memory");
    __builtin_amdgcn_s_barrier();
    buf ^= 1;
  }
#undef STG_A
#undef STG_B
#undef STG_HALF

  const u16* resb = (const u16*)res;
  int rowb = bm + wm*(AM*64) + l16;
  int colb = bn + wn*64 + (g16 << 2);
  #pragma unroll
  for (int mf = 0; mf < AM*4; ++mf) {
    int row = rowb + mf*16;
    #pragma unroll
    for (int nf = 0; nf < 4; ++nf) {
      int col0 = colb + nf*16;
      f32x4 v = acc[mf][nf];
      if (mode == 6) {
        if (col0 >= 768) {
          float4 b4 = *(const float4*)(bias + col0 - 768);
          v[0] = 1.0f/(1.0f+__expf(-(v[0]+b4.x)));
          v[1] = 1.0f/(1.0f+__expf(-(v[1]+b4.y)));
          v[2] = 1.0f/(1.0f+__expf(-(v[2]+b4.z)));
          v[3] = 1.0f/(1.0f+__expf(-(v[3]+b4.w)));
        }
        uint2 o; o.x = cvt_pk(v[0], v[1]); o.y = cvt_pk(v[2], v[3]);
        size_t i2 = (size_t)(col0 >> 5) * M32 + (size_t)row*32 + (col0 & 31);
        *(uint2*)((u16*)Cout + i2) = o;
      } else if (mode == 3) {
        float4 b4 = *(const float4*)(bias + col0);
        uint2 o;
        o.x = cvt_pk(fmaxf(v[0]+b4.x, 0.f), fmaxf(v[1]+b4.y, 0.f));
        o.y = cvt_pk(fmaxf(v[2]+b4.z, 0.f), fmaxf(v[3]+b4.w, 0.f));
        *(uint2*)((u16*)Cout + (size_t)row*N + col0) = o;
      } else if (mode == 4) {
        size_t i2 = (size_t)row*N + col0;
        float4 r4 = *(const float4*)(res + i2);
        float4 b4 = *(const float4*)(bias + col0);
        float4 o = make_float4(v[0]+r4.x+b4.x, v[1]+r4.y+b4.y,
                               v[2]+r4.z+b4.z, v[3]+r4.w+b4.w);
        *(float4*)((float*)Cout + i2) = o;
      } else if (mode == 5) {
        int rr = row >> 7, ss = row & 127;
        size_t i2 = ((size_t)ss*R + rr)*(size_t)N + col0;
        float4 r4 = *(const float4*)(res + i2);
        float4 b4 = *(const float4*)(bias + col0);
        float4 o = make_float4(v[0]+r4.x+b4.x, v[1]+r4.y+b4.y,
                               v[2]+r4.z+b4.z, v[3]+r4.w+b4.w);
        *(float4*)((float*)Cout + i2) = o;
      } else if (mode == 7) {
        size_t i2 = (size_t)row*N + col0;
        float4 r4 = *(const float4*)(res + i2);
        float4 b4 = *(const float4*)(bias + col0);
        uint2 o;
        o.x = cvt_pk(v[0]+r4.x+b4.x, v[1]+r4.y+b4.y);
        o.y = cvt_pk(v[2]+r4.z+b4.z, v[3]+r4.w+b4.w);
        *(uint2*)((u16*)Cout + i2) = o;
      } else if (mode == 8) {
        int rr = row >> 7, ss = row & 127;
        size_t i2 = ((size_t)ss*R + rr)*(size_t)N + col0;
        ushort4 r4 = *(const ushort4*)(resb + i2);
        float4 b4 = *(const float4*)(bias + col0);
        uint2 o;
        o.x = cvt_pk(v[0]+bf2f(r4.x)+b4.x, v[1]+bf2f(r4.y)+b4.y);
        o.y = cvt_pk(v[2]+bf2f(r4.z)+b4.z, v[3]+bf2f(r4.w)+b4.w);
        *(uint2*)((u16*)Cout + i2) = o;
      } else if (mode == 9) {
        size_t i2 = (size_t)row*N + col0;
        ushort4 r4 = *(const ushort4*)(resb + i2);
        float4 b4 = *(const float4*)(bias + col0);
        float4 o = make_float4(v[0]+bf2f(r4.x)+b4.x, v[1]+bf2f(r4.y)+b4.y,
                               v[2]+bf2f(r4.z)+b4.z, v[3]+bf2f(r4.w)+b4.w);
        *(float4*)((float*)Cout + i2) = o;
      } else if (mode == 2) {
        float4 b4 = *(const float4*)(bias + col0);
        uint2 o;
        o.x = cvt_pk(1.0f/(1.0f+__expf(-(v[0]+b4.x))),
                     1.0f/(1.0f+__expf(-(v[1]+b4.y))));
        o.y = cvt_pk(1.0f/(1.0f+__expf(-(v[2]+b4.z))),
                     1.0f/(1.0f+__expf(-(v[3]+b4.w))));
        *(uint2*)((u16*)Cout + (size_t)row*N + col0) = o;
      } else {
        uint2 o; o.x = cvt_pk(v[0], v[1]); o.y = cvt_pk(v[2], v[3]);
        *(uint2*)((u16*)Cout + (size_t)row*N + col0) = o;
      }
    }
  }
}

// ---- softmax + pack: bias comes pre-packed in fragment order (2x bf16x8) ----
template<bool RM>
__device__ __forceinline__ void softmax_pack(
    const f32x16 &sac, const float* __restrict__ lmbp,
    bf16x8 bf0, bf16x8 bf1, int kb, int hi,
    float &lsum, bf16x8 &pf0, bf16x8 &pf1)
{
  float p[16];
  #pragma unroll
  for (int rq = 0; rq < 4; ++rq) {
    int k0 = kb + 8*rq + 4*hi;
    float4 lm4 = *(const float4*)&lmbp[k0];
    float b0 = lm4.x, b1 = lm4.y, b2 = lm4.z, b3 = lm4.w;
    if (RM) {
      if (rq < 2) {
        b0 += bf2f((u16)bf0[4*rq+0]); b1 += bf2f((u16)bf0[4*rq+1]);
        b2 += bf2f((u16)bf0[4*rq+2]); b3 += bf2f((u16)bf0[4*rq+3]);
      } else {
        b0 += bf2f((u16)bf1[4*rq-8+0]); b1 += bf2f((u16)bf1[4*rq-8+1]);
        b2 += bf2f((u16)bf1[4*rq-8+2]); b3 += bf2f((u16)bf1[4*rq-8+3]);
      }
    }
    p[4*rq+0] = exp2f(sac[4*rq+0] + b0);
    p[4*rq+1] = exp2f(sac[4*rq+1] + b1);
    p[4*rq+2] = exp2f(sac[4*rq+2] + b2);
    p[4*rq+3] = exp2f(sac[4*rq+3] + b3);
    lsum += (p[4*rq+0] + p[4*rq+1]) + (p[4*rq+2] + p[4*rq+3]);
  }
  unsigned u0 = cvt_pk(p[0],  p[1]),  u1 = cvt_pk(p[2],  p[3]);
  unsigned u2 = cvt_pk(p[4],  p[5]),  u3 = cvt_pk(p[6],  p[7]);
  unsigned u4 = cvt_pk(p[8],  p[9]),  u5 = cvt_pk(p[10], p[11]);
  unsigned u6 = cvt_pk(p[12], p[13]), u7 = cvt_pk(p[14], p[15]);
  pl32swap(u0, u2); pl32swap(u1, u3);
  pl32swap(u4, u6); pl32swap(u5, u7);
  pf0 = mk_frag(u0, u1, u2, u3);
  pf1 = mk_frag(u4, u5, u6, u7);
}

// ---------------- MFMA attention, 32x32, head-major QKVG, deep prefetch ----
// QKVG head-major: 32 blocks of [NROWS][32]; Q=0..7, K=8..15, V=16..23, G=24..31.
// HPB heads per block; 8/HPB waves per head; each wave owns 2 q-tiles (64 q).
// K prefetched 2 groups deep (even/odd named register sets); bias as fragments.
template<int NKEY, int HPB, bool ROWMODE>
__global__ __launch_bounds__(512, 2) void attn_mfma(
    const u16* __restrict__ QKVG, const u16* __restrict__ biasF,
    const float* __restrict__ mask, u16* __restrict__ og)
{
  __shared__ __align__(16) u16 Vt[HPB][32][NKEY + 8];
  __shared__ float lmb[NKEY];
  constexpr int NKV = NKEY / 32;
  constexpr int WPH = 8 / HPB;
  int b = blockIdx.y;
  int t = threadIdx.x, lane = t & 63, w = t >> 6;
  int c31 = lane & 31, hi = lane >> 5;
  int lh = w / WPH, wtile = w % WPH;
  int hh = blockIdx.x * HPB + lh;

  size_t rbase = (size_t)b * NKEY * 32;
  const u16* Qp = QKVG + (size_t)hh * M32 + rbase;
  const u16* Kp = QKVG + (size_t)(8 + hh) * M32 + rbase;
  const u16* Gp = QKVG + (size_t)(24 + hh) * M32 + rbase;

  for (int i = t; i < HPB*NKEY*4; i += 512) {
    int c0 = (i & 3) * 8;
    int key = (i >> 2) & (NKEY - 1);
    int sh = (i >> 2) / NKEY;
    const u16* Vs = QKVG + (size_t)(16 + blockIdx.x*HPB + sh) * M32 + rbase;
    bf16x8 v8 = *(const bf16x8*)(Vs + (size_t)key*32 + c0);
    #pragma unroll
    for (int j = 0; j < 8; ++j) Vt[sh][c0+j][key] = (u16)v8[j];
  }
  for (int i = t; i < NKEY; i += 512)
    lmb[i] = 1.4426950e9f * ((ROWMODE ? mask[b*R + i] : mask[i*R + b]) - 1.0f);
  __syncthreads();

  int qA = wtile*64 + c31, qB = qA + 32;
  int qtA = wtile*2, qtB = wtile*2 + 1;
  bf16x8 qfA0 = *(const bf16x8*)(Qp + (size_t)qA*32 + hi*8);
  bf16x8 qfA1 = *(const bf16x8*)(Qp + (size_t)qA*32 + 16 + hi*8);
  bf16x8 qfB0 = *(const bf16x8*)(Qp + (size_t)qB*32 + hi*8);
  bf16x8 qfB1 = *(const bf16x8*)(Qp + (size_t)qB*32 + 16 + hi*8);

  f32x16 oA = (f32x16)(0.0f), oB = (f32x16)(0.0f);
  float lsA = 0.f, lsB = 0.f;

#define LOADK(d0_, d1_, g_) do { \
    const u16* kr_ = Kp + ((size_t)((g_)*32) + c31)*32 + hi*8; \
    d0_ = *(const bf16x8*)kr_; d1_ = *(const bf16x8*)(kr_ + 16); \
  } while(0)

#define GROUP_BODY(g_, k0_, k1_) do { \
    int kb_ = (g_) * 32; \
    bf16x8 bA0{}, bA1{}, bB0{}, bB1{}; \
    if (ROWMODE) { \
      const u16* bpA_ = biasF + ((((size_t)hh*8 + (g_))*8 + qtA)*2 + hi)*512 + (size_t)c31*16; \
      bA0 = *(const bf16x8*)bpA_; bA1 = *(const bf16x8*)(bpA_ + 8); \
    } \
    __builtin_amdgcn_s_setprio(1); \
    f32x16 sacA_ = __builtin_amdgcn_mfma_f32_32x32x16_bf16(k0_, qfA0, (f32x16)(0.0f), 0, 0, 0); \
    sacA_ = __builtin_amdgcn_mfma_f32_32x32x16_bf16(k1_, qfA1, sacA_, 0, 0, 0); \
    __builtin_amdgcn_s_setprio(0); \
    bf16x8 va0_ = *(const bf16x8*)&Vt[lh][c31][kb_ + hi*8]; \
    bf16x8 va1_ = *(const bf16x8*)&Vt[lh][c31][kb_ + 16 + hi*8]; \
    bf16x8 pf0_, pf1_; \
    softmax_pack<ROWMODE>(sacA_, lmb, bA0, bA1, kb_, hi, lsA, pf0_, pf1_); \
    __builtin_amdgcn_s_setprio(1); \
    oA = __builtin_amdgcn_mfma_f32_32x32x16_bf16(va0_, pf0_, oA, 0, 0, 0); \
    oA = __builtin_amdgcn_mfma_f32_32x32x16_bf16(va1_, pf1_, oA, 0, 0, 0); \
    __builtin_amdgcn_s_setprio(0); \
    if (ROWMODE) { \
      const u16* bpB_ = biasF + ((((size_t)hh*8 + (g_))*8 + qtB)*2 + hi)*512 + (size_t)c31*16; \
      bB0 = *(const bf16x8*)bpB_; bB1 = *(const bf16x8*)(bpB_ + 8); \
    } \
    __builtin_amdgcn_s_setprio(1); \
    f32x16 sacB_ = __builtin_amdgcn_mfma_f32_32x32x16_bf16(k0_, qfB0, (f32x16)(0.0f), 0, 0, 0); \
    sacB_ = __builtin_amdgcn_mfma_f32_32x32x16_bf16(k1_, qfB1, sacB_, 0, 0, 0); \
    __builtin_amdgcn_s_setprio(0); \
    softmax_pack<ROWMODE>(sacB_, lmb, bB0, bB1, kb_, hi, lsB, pf0_, pf1_); \
    __builtin_amdgcn_s_setprio(1); \
    oB = __builtin_amdgcn_mfma_f32_32x32x16_bf16(va0_, pf0_, oB, 0, 0, 0); \
    oB = __builtin_amdgcn_mfma_f32_32x32x16_bf16(va1_, pf1_, oB, 0, 0, 0); \
    __builtin_amdgcn_s_setprio(0); \
  } while(0)

  bf16x8 ke0{}, ke1{}, ko0{}, ko1{};
  LOADK(ke0, ke1, 0);
  LOADK(ko0, ko1, 1);
  for (int g = 0; g < NKV; g += 2) {
    bf16x8 c0 = ke0, c1 = ke1;
    if (g + 2 < NKV) LOADK(ke0, ke1, g + 2);
    GROUP_BODY(g, c0, c1);
    bf16x8 d0 = ko0, d1 = ko1;
    if (g + 3 < NKV) LOADK(ko0, ko1, g + 3);
    GROUP_BODY(g + 1, d0, d1);
  }
#undef GROUP_BODY
#undef LOADK

  lsA += __shfl_xor(lsA, 32);
  lsB += __shfl_xor(lsB, 32);
  float invA = 1.0f / lsA, invB = 1.0f / lsB;

  size_t baseO = (size_t)b * NKEY * 256 + (size_t)hh * 32;
  #pragma unroll
  for (int tile = 0; tile < 2; ++tile) {
    int q = (tile == 0) ? qA : qB;
    float inv = (tile == 0) ? invA : invB;
    const f32x16 &oo = (tile == 0) ? oA : oB;
    u16* op = og + baseO + (size_t)q * 256;
    const u16* gp = Gp + (size_t)q * 32;
    #pragma unroll
    for (int rq = 0; rq < 4; ++rq) {
      int c0 = 8*rq + 4*hi;
      ushort4 g4 = *(const ushort4*)(gp + c0);
      float f0 = oo[4*rq+0] * inv * bf2f(g4.x);
      float f1 = oo[4*rq+1] * inv * bf2f(g4.y);
      float f2 = oo[4*rq+2] * inv * bf2f(g4.z);
      float f3 = oo[4*rq+3] * inv * bf2f(g4.w);
      uint2 o2; o2.x = cvt_pk(f0, f1); o2.y = cvt_pk(f2, f3);
      *(uint2*)(op + c0) = o2;
    }
  }
}

extern "C" void kernel_launch(void* const* d_in, const int* in_sizes, int n_in,
                              void* d_out, int out_size, void* d_ws, size_t ws_size,
                              hipStream_t stream)
{
  const float* node         = (const float*)d_in[0];
  const float* pair         = (const float*)d_in[1];
  const float* node_mask    = (const float*)d_in[2];
  const float* row_ln_m_g   = (const float*)d_in[3];
  const float* row_ln_m_b   = (const float*)d_in[4];
  const float* row_ln_z_g   = (const float*)d_in[5];
  const float* row_ln_z_b   = (const float*)d_in[6];
  const float* row_b_w      = (const float*)d_in[7];
  const float* row_wq       = (const float*)d_in[8];
  const float* row_wk       = (const float*)d_in[9];
  const float* row_wv       = (const float*)d_in[10];
  const float* row_wg       = (const float*)d_in[11];
  const float* row_bg       = (const float*)d_in[12];
  const float* row_wo       = (const float*)d_in[13];
  const float* row_out_bias = (const float*)d_in[14];
  const float* col_ln_g     = (const float*)d_in[15];
  const float* col_ln_b     = (const float*)d_in[16];
  const float* col_wq       = (const float*)d_in[17];
  const float* col_wk       = (const float*)d_in[18];
  const float* col_wv       = (const float*)d_in[19];
  const float* col_wg       = (const float*)d_in[20];
  const float* col_bg       = (const float*)d_in[21];
  const float* col_wo       = (const float*)d_in[22];
  const float* col_bo       = (const float*)d_in[23];
  const float* tr_ln_g      = (const float*)d_in[24];
  const float* tr_ln_b      = (const float*)d_in[25];
  const float* tr_w1        = (const float*)d_in[26];
  const float* tr_b1        = (const float*)d_in[27];
  const float* tr_w2        = (const float*)d_in[28];
  const float* tr_b2        = (const float*)d_in[29];

  float* out = (float*)d_out;
  char* ws8 = (char*)d_ws;
  const size_t MB = 1ull << 20;
  u16*   A     = (u16*)(ws8);               // 16 MB  LN out [32768][256] bf16
  u16*   QKVG  = (u16*)(ws8 + 16*MB);       // 64 MB  head-major 32 x [32768][32] (also T1)
  u16*   Ob    = (u16*)(ws8 + 80*MB);       // 16 MB  gated attn out bf16 [row][256]
  u16*   DbF   = (u16*)(ws8 + 96*MB);       // 4 MB   bias fragments
  u16*   N1    = (u16*)(ws8 + 100*MB);      // 16 MB  node1 bf16 [s][r][256]
  u16*   N2    = (u16*)(ws8 + 116*MB);      // 16 MB  node2 bf16 [s][r][256]
  u16*   Wb    = (u16*)(ws8 + 132*MB);      // bf16 weight arena
  u16*   T1    = QKVG;

  const float qs = 0.17677669529663687f;    // 1/sqrt(32)

  u16* Wrqkvg = Wb + 0;
  u16* Wro    = Wb + 262144;
  u16* Wcqkvg = Wb + 327680;
  u16* Wco    = Wb + 589824;
  u16* W1w    = Wb + 655360;
  u16* W2w    = Wb + 917504;

  CvtArgs ca;
  const float* srcs[12] = {row_wq,row_wk,row_wv,row_wg,row_wo,
                           col_wq,col_wk,col_wv,col_wg,col_wo,tr_w1,tr_w2};
  int offs[12] = {0,65536,131072,196608,262144,327680,393216,458752,524288,589824,655360,917504};
  int ns[12]   = {65536,65536,65536,65536,65536,65536,65536,65536,65536,65536,262144,262144};
  for (int i = 0; i < 12; ++i) {
    ca.src[i] = srcs[i]; ca.off[i] = offs[i]; ca.n[i] = ns[i];
    ca.scale[i] = (i == 0 || i == 5) ? qs * LOG2E : 1.0f;
  }
  cvt_w_kernel<<<dim3(256,12), 256, 0, stream>>>(ca, Wb);

  dim3 gq(4, 128);     // AM=2: 256x256 tiles, N=1024
  dim3 go(1, 256);     // AM=1: 128x256 tiles, N=256

  // --- row attention ---
  ln256_kernel<<<8192, 256, 0, stream>>>(node, A, row_ln_m_g, row_ln_m_b, 0, 0);
  pair_bias_kernel<<<16384, 256, 0, stream>>>(pair, row_ln_z_g, row_ln_z_b, row_b_w, DbF);
  gemm_8ph<2><<<gq, 512, 0, stream>>>(A, Wrqkvg, QKVG, 1024, 256, 6, row_bg, nullptr);
  attn_mfma<256,2,true><<<dim3(4,128), 512, 0, stream>>>(QKVG, DbF, node_mask, Ob);
  gemm_8ph<1><<<go, 512, 0, stream>>>(Ob, Wro, N1, 256, 256, 7, row_out_bias, node);

  // --- column attention (in [r,s,d] layout) ---
  ln256_kernel<<<8192, 256, 0, stream>>>(N1, A, col_ln_g, col_ln_b, 1, 1);
  gemm_8ph<2><<<gq, 512, 0, stream>>>(A, Wcqkvg, QKVG, 1024, 256, 6, col_bg, nullptr);
  attn_mfma<128,4,false><<<dim3(2,256), 512, 0, stream>>>(QKVG, nullptr, node_mask, Ob);
  gemm_8ph<1><<<go, 512, 0, stream>>>(Ob, Wco, N2, 256, 256, 8, col_bo, (const float*)N1);

  // --- transition ---
  ln256_kernel<<<8192, 256, 0, stream>>>(N2, A, tr_ln_g, tr_ln_b, 0, 1);
  gemm_8ph<2><<<gq, 512, 0, stream>>>(A, W1w, T1, 1024, 256, 3, tr_b1, nullptr);
  gemm_8ph<1><<<go, 512, 0, stream>>>(T1, W2w, out, 256, 1024, 9, tr_b2, (const float*)N2);
}